// Round 6
// baseline (435.011 us; speedup 1.0000x reference)
//
#include <hip/hip_runtime.h>

typedef unsigned short u16;
typedef unsigned int u32;

#define B_ 4
#define N_ 256
#define T_ 36
#define C_ 64
#define H_ 4
#define D_ 16
#define CH_ 128
#define E_ 4096
#define G_ (B_*T_)
#define TOK_ (B_*N_*T_)

// workspace layout (float offsets)
#define DS_OFF  0
#define XG_OFF  (DS_OFF + N_*C_)
#define HA_OFF  (XG_OFF + TOK_*C_)          // bf16 h buffer A (conv outs) ; aliased by o_ws later
#define HB_OFF  (HA_OFF + G_*N_*CH_/2)      // bf16 buffer B (h1 / jk input)
#define HS_OFF  (HB_OFF + G_*N_*CH_/2)
#define HD_OFF  (HS_OFF + G_*N_)
#define INT_OFF (HD_OFF + G_*N_)

__device__ __forceinline__ float bf2f(u16 u){
  u32 x = ((u32)u) << 16;
  return __builtin_bit_cast(float, x);
}
__device__ __forceinline__ u16 f2bf(float f){
  u32 x = __builtin_bit_cast(u32, f);
  x += 0x7fffu + ((x >> 16) & 1u);
  return (u16)(x >> 16);
}
__device__ __forceinline__ void unpack8(uint4 u, float* f){
  f[0]=bf2f((u16)(u.x & 0xffffu)); f[1]=bf2f((u16)(u.x >> 16));
  f[2]=bf2f((u16)(u.y & 0xffffu)); f[3]=bf2f((u16)(u.y >> 16));
  f[4]=bf2f((u16)(u.z & 0xffffu)); f[5]=bf2f((u16)(u.z >> 16));
  f[6]=bf2f((u16)(u.w & 0xffffu)); f[7]=bf2f((u16)(u.w >> 16));
}
__device__ __forceinline__ uint4 pack8f(const float* f){
  uint4 u;
  u.x = (u32)f2bf(f[0]) | ((u32)f2bf(f[1]) << 16);
  u.y = (u32)f2bf(f[2]) | ((u32)f2bf(f[3]) << 16);
  u.z = (u32)f2bf(f[4]) | ((u32)f2bf(f[5]) << 16);
  u.w = (u32)f2bf(f[6]) | ((u32)f2bf(f[7]) << 16);
  return u;
}
__device__ __forceinline__ int rfl(int v){ return __builtin_amdgcn_readfirstlane(v); }

// ---------------- deterministic CSR: bucket by dst (atomic), stable-sort by edge id ----------------
__global__ void k_csr(const int* __restrict__ ei, int* __restrict__ indptr, int* __restrict__ srcs)
{
  __shared__ int srcL[E_];
  __shared__ int dstL[E_];
  __shared__ int tmp[E_];
  __shared__ int cnt[N_];
  __shared__ int base[N_+1];
  const int tid = threadIdx.x;   // 256
  for (int e = tid; e < E_; e += 256){ srcL[e] = ei[e]; dstL[e] = ei[E_ + e]; }
  cnt[tid] = 0;
  __syncthreads();
  for (int e = tid; e < E_; e += 256) atomicAdd(&cnt[dstL[e]], 1);
  __syncthreads();
  if (tid == 0){
    int run = 0;
    for (int i = 0; i < N_; i++){ base[i] = run; run += cnt[i]; }
    base[N_] = run;
  }
  __syncthreads();
  cnt[tid] = 0;
  __syncthreads();
  for (int e = tid; e < E_; e += 256){
    int d = dstL[e];
    int p = atomicAdd(&cnt[d], 1);
    tmp[base[d] + p] = e;
  }
  __syncthreads();
  {
    const int p0 = base[tid], p1 = base[tid] + cnt[tid];
    for (int i = p0 + 1; i < p1; i++){      // insertion sort by edge id -> stable/deterministic
      int v = tmp[i]; int j = i - 1;
      while (j >= p0 && tmp[j] > v){ tmp[j+1] = tmp[j]; j--; }
      tmp[j+1] = v;
    }
    for (int j = p0; j < p1; j++) srcs[j] = srcL[tmp[j]];
  }
  indptr[tid] = base[tid];
  if (tid == 0) indptr[N_] = base[N_];
}

// ---------------- ds = D_S @ W_emb + b_emb ----------------
__global__ void k_ds(const float* __restrict__ DSm, const float* __restrict__ Wemb,
                     const float* __restrict__ bemb, float* __restrict__ dsb)
{
  const int n = blockIdx.x, c = threadIdx.x;
  float acc = bemb[c];
  for (int m = 0; m < N_; m++) acc += DSm[n*N_ + m] * Wemb[m*C_ + c];
  dsb[n*C_ + c] = acc;
}

// ---------------- GAT conv1 linear: h = bf16(x @ W1), fused hs/hd ----------------
__global__ __launch_bounds__(256)
void k_lin1(const float* __restrict__ query, const float* __restrict__ W1,
            const float* __restrict__ as1, const float* __restrict__ ad1,
            u16* __restrict__ h, float* __restrict__ hs_ws, float* __restrict__ hd_ws)
{
  __shared__ float xs[64][65];
  __shared__ float red[2][4][64];
  const int bid = blockIdx.x;
  const int g = bid >> 2, n0 = (bid & 3) * 64;
  const int b = g / T_, t = g % T_;
  const int tid = threadIdx.x;

  {
    const size_t gb = (((size_t)b*N_ + n0)*T_ + t)*C_;
    #pragma unroll
    for (int it = 0; it < 4; it++){
      int idx = tid + 256*it;
      int row = idx >> 4, c4 = (idx & 15) * 4;
      float4 v = *(const float4*)(query + gb + (size_t)row*(T_*C_) + c4);
      xs[row][c4+0] = v.x; xs[row][c4+1] = v.y; xs[row][c4+2] = v.z; xs[row][c4+3] = v.w;
    }
  }
  __syncthreads();

  const int r = tid & 63;
  const int cb = rfl(tid >> 6);
  const int ch0 = cb * 32;

  float acc[32];
  #pragma unroll
  for (int j = 0; j < 32; j++) acc[j] = 0.f;
  for (int k = 0; k < 64; k++){
    float xv = xs[r][k];
    const float* wrow = W1 + k*CH_ + ch0;   // scalar (uniform) loads
    #pragma unroll
    for (int j = 0; j < 32; j++) acc[j] += xv * wrow[j];
  }
  float hs = 0.f, hd = 0.f;
  #pragma unroll
  for (int j = 0; j < 32; j++){ hs += acc[j]*as1[ch0+j]; hd += acc[j]*ad1[ch0+j]; }
  red[0][cb][r] = hs; red[1][cb][r] = hd;

  u16* hp = h + ((size_t)(g*N_ + n0 + r))*CH_ + ch0;
  #pragma unroll
  for (int j8 = 0; j8 < 32; j8 += 8)
    *(uint4*)(hp + j8) = pack8f(&acc[j8]);

  __syncthreads();
  if (tid < 64){
    float a = red[0][0][tid]+red[0][1][tid]+red[0][2][tid]+red[0][3][tid];
    float d = red[1][0][tid]+red[1][1][tid]+red[1][2][tid]+red[1][3][tid];
    hs_ws[g*N_ + n0 + tid] = a;
    hd_ws[g*N_ + n0 + tid] = d;
  }
}

// ---------------- GAT conv2 linear: h2 = bf16(h1 @ W2), fused hs2/hd2 ----------------
__global__ __launch_bounds__(256)
void k_lin2(const u16* __restrict__ h1, const float* __restrict__ W2,
            const float* __restrict__ as2, const float* __restrict__ ad2,
            u16* __restrict__ h2, float* __restrict__ hs_ws, float* __restrict__ hd_ws)
{
  __shared__ float xs[64][129];
  __shared__ float red[2][4][64];
  const int bid = blockIdx.x;
  const int g = bid >> 2, n0 = (bid & 3) * 64;
  const int tid = threadIdx.x;

  {
    #pragma unroll
    for (int it = 0; it < 4; it++){
      int idx = tid + 256*it;
      int row = idx >> 4, c8 = (idx & 15) * 8;
      uint4 u = *(const uint4*)(h1 + ((size_t)(g*N_ + n0 + row))*CH_ + c8);
      float v[8]; unpack8(u, v);
      #pragma unroll
      for (int i = 0; i < 8; i++) xs[row][c8+i] = v[i];
    }
  }
  __syncthreads();

  const int r = tid & 63;
  const int cb = rfl(tid >> 6);
  const int ch0 = cb * 32;

  float acc[32];
  #pragma unroll
  for (int j = 0; j < 32; j++) acc[j] = 0.f;
  for (int k = 0; k < 128; k++){
    float xv = xs[r][k];
    const float* wrow = W2 + k*CH_ + ch0;
    #pragma unroll
    for (int j = 0; j < 32; j++) acc[j] += xv * wrow[j];
  }
  float hs = 0.f, hd = 0.f;
  #pragma unroll
  for (int j = 0; j < 32; j++){ hs += acc[j]*as2[ch0+j]; hd += acc[j]*ad2[ch0+j]; }
  red[0][cb][r] = hs; red[1][cb][r] = hd;

  u16* hp = h2 + ((size_t)(g*N_ + n0 + r))*CH_ + ch0;
  #pragma unroll
  for (int j8 = 0; j8 < 32; j8 += 8)
    *(uint4*)(hp + j8) = pack8f(&acc[j8]);

  __syncthreads();
  if (tid < 64){
    float a = red[0][0][tid]+red[0][1][tid]+red[0][2][tid]+red[0][3][tid];
    float d = red[1][0][tid]+red[1][1][tid]+red[1][2][tid]+red[1][3][tid];
    hs_ws[g*N_ + n0 + tid] = a;
    hd_ws[g*N_ + n0 + tid] = d;
  }
}

// ---------------- GAT aggregation (+softmax in-block). layer2: jk max fused ----------------
__global__ __launch_bounds__(256)
void k_agg(const u16* __restrict__ hin, const float* __restrict__ hs_ws, const float* __restrict__ hd_ws,
           const int* __restrict__ indptr, const int* __restrict__ srcs,
           const float* __restrict__ bias, u16* __restrict__ hout, int layer2)
{
  __shared__ int   srcs_l[E_];
  __shared__ float alpha_l[E_];
  __shared__ float hs_l[N_];
  const int bid = blockIdx.x;
  const int g = bid >> 2, n0 = (bid & 3) * 64;
  const int tid = threadIdx.x;

  const int p00 = indptr[n0];
  const int pend = indptr[n0 + 64];
  const int cntE = pend - p00;
  for (int i = tid; i < cntE; i += 256) srcs_l[i] = srcs[p00 + i];
  hs_l[tid] = hs_ws[g*N_ + tid];
  __syncthreads();

  if (tid < 64){
    const int dst = n0 + tid;
    const int p0 = indptr[dst] - p00, p1 = indptr[dst+1] - p00;
    const float hdn = hd_ws[g*N_ + dst];
    for (int j = p0; j < p1; j++){
      float e = hs_l[srcs_l[j]] + hdn;
      alpha_l[j] = e > 0.f ? e : 0.2f * e;
    }
    float m = -1e30f;
    for (int j = p0; j < p1; j++) m = fmaxf(m, alpha_l[j]);
    float s = 0.f;
    for (int j = p0; j < p1; j++){
      float w = __expf(alpha_l[j] - m);
      alpha_l[j] = w; s += w;
    }
    float inv = 1.f / (s + 1e-16f);
    for (int j = p0; j < p1; j++) alpha_l[j] *= inv;
  }
  __syncthreads();

  const int r = tid & 63;
  const int cb = rfl(tid >> 6);
  const int ch0 = cb * 32;
  const int dst = n0 + r;
  const int p0 = indptr[dst] - p00, p1 = indptr[dst+1] - p00;

  float acc[32];
  #pragma unroll
  for (int j = 0; j < 32; j++) acc[j] = 0.f;
  for (int j = p0; j < p1; j++){
    float a = alpha_l[j];
    int s = srcs_l[j];
    const uint4* hp = (const uint4*)(hin + ((size_t)(g*N_ + s))*CH_ + ch0);
    #pragma unroll
    for (int q = 0; q < 4; q++){
      float hv[8]; unpack8(hp[q], hv);
      #pragma unroll
      for (int i = 0; i < 8; i++) acc[q*8+i] += a * hv[i];
    }
  }
  float o[32];
  #pragma unroll
  for (int j = 0; j < 32; j++){
    float v = acc[j] + bias[ch0+j];
    o[j] = v > 0.f ? v : 0.f;
  }
  u16* op = hout + ((size_t)(g*N_ + dst))*CH_ + ch0;
  if (layer2){
    #pragma unroll
    for (int j8 = 0; j8 < 32; j8 += 8){
      float h1v[8]; unpack8(*(const uint4*)(op + j8), h1v);
      #pragma unroll
      for (int i = 0; i < 8; i++) o[j8+i] = fmaxf(h1v[i], o[j8+i]);
    }
  }
  #pragma unroll
  for (int j8 = 0; j8 < 32; j8 += 8)
    *(uint4*)(op + j8) = pack8f(&o[j8]);
}

// ---------------- jk linear: xg(time-reversed) = jk @ jkW + jkb ----------------
__global__ __launch_bounds__(256)
void k_jk(const u16* __restrict__ jkin, const float* __restrict__ jkW, const float* __restrict__ jkb,
          float* __restrict__ xg)
{
  __shared__ float xs[64][129];
  const int bid = blockIdx.x;
  const int g = bid >> 2, n0 = (bid & 3) * 64;
  const int b = g / T_, t = g % T_;
  const int tid = threadIdx.x;

  {
    #pragma unroll
    for (int it = 0; it < 4; it++){
      int idx = tid + 256*it;
      int row = idx >> 4, c8 = (idx & 15) * 8;
      uint4 u = *(const uint4*)(jkin + ((size_t)(g*N_ + n0 + row))*CH_ + c8);
      float v[8]; unpack8(u, v);
      #pragma unroll
      for (int i = 0; i < 8; i++) xs[row][c8+i] = v[i];
    }
  }
  __syncthreads();

  const int r = tid & 63;
  const int cb = rfl(tid >> 6);
  const int o0 = cb * 16;

  float acc[16];
  #pragma unroll
  for (int j = 0; j < 16; j++) acc[j] = 0.f;
  for (int k = 0; k < 128; k++){
    float xv = xs[r][k];
    const float* wrow = jkW + k*C_ + o0;
    #pragma unroll
    for (int j = 0; j < 16; j++) acc[j] += xv * wrow[j];
  }
  float* op = xg + ((((size_t)b*N_ + n0 + r)*T_) + (T_-1-t))*C_ + o0;
  #pragma unroll
  for (int j4 = 0; j4 < 16; j4 += 4){
    float4 v = make_float4(acc[j4]+jkb[o0+j4], acc[j4+1]+jkb[o0+j4+1],
                           acc[j4+2]+jkb[o0+j4+2], acc[j4+3]+jkb[o0+j4+3]);
    *(float4*)(op + j4) = v;
  }
}

// ---------------- attention v3: 512 thr, projections de-duplicated, frag reads from LDS ----------------
#define QP_ 20   // 80B rows: 16B-aligned -> float4 LDS reads
__global__ __launch_bounds__(512)
void k_attn(const float* __restrict__ query, const float* __restrict__ key, const float* __restrict__ value,
            const float* __restrict__ Wq, const float* __restrict__ Wk, const float* __restrict__ Wv,
            const float* __restrict__ dsb, float* __restrict__ o_ws)
{
  __shared__ float qh[N_][QP_];       // q-proj; reused as partial-o [256][16] in combine
  __shared__ float kh[N_][QP_];
  __shared__ u16   vh[N_][16];        // bf16 V
  __shared__ float mArr[N_];
  __shared__ float invArr[N_];
  __shared__ float pm[2][N_];
  __shared__ float ps[2][N_];
  __shared__ float wq[16][16], wk[16][16], wv[16][16];

  const int bx = blockIdx.x;
  const int b = bx / (T_*H_);
  const int rr = bx % (T_*H_);
  const int t = rr / H_;
  const int h = rr % H_;
  const int tid = threadIdx.x;
  const int n = tid & (N_-1);
  const int half = tid >> 8;           // 0/1 (wave-uniform)

  if (tid < 256){
    wq[tid>>4][tid&15] = Wq[tid];
    wk[tid>>4][tid&15] = Wk[tid];
    wv[tid>>4][tid&15] = Wv[tid];
  }
  __syncthreads();   // weights staged

  const size_t base = ((((size_t)b*N_ + n)*T_) + t)*C_ + h*D_;
  const float* dsp = dsb + n*C_ + h*D_;

  // de-duplicated projections: half0 -> Q then V; half1 -> K. One 16x16 live at a time.
  if (half == 0){
    float x[16], r0[16];
    #pragma unroll
    for (int j4 = 0; j4 < 16; j4 += 4){
      float4 a = *(const float4*)(query + base + j4);
      x[j4]=a.x; x[j4+1]=a.y; x[j4+2]=a.z; x[j4+3]=a.w;
    }
    #pragma unroll
    for (int j = 0; j < 16; j++) x[j] += dsp[j];
    #pragma unroll
    for (int j = 0; j < 16; j++){
      float a = 0.f;
      #pragma unroll
      for (int i = 0; i < 16; i++) a += x[i] * wq[i][j];
      r0[j] = a;
    }
    #pragma unroll
    for (int j = 0; j < 16; j++) qh[n][j] = r0[j];

    #pragma unroll
    for (int j4 = 0; j4 < 16; j4 += 4){
      float4 a = *(const float4*)(value + base + j4);
      x[j4]=a.x; x[j4+1]=a.y; x[j4+2]=a.z; x[j4+3]=a.w;
    }
    #pragma unroll
    for (int j = 0; j < 16; j++) x[j] += dsp[j];
    #pragma unroll
    for (int j = 0; j < 16; j++){
      float a = 0.f;
      #pragma unroll
      for (int i = 0; i < 16; i++) a += x[i] * wv[i][j];
      r0[j] = a;
    }
    *(uint4*)&vh[n][0] = pack8f(&r0[0]);
    *(uint4*)&vh[n][8] = pack8f(&r0[8]);
  } else {
    float x[16], r0[16];
    #pragma unroll
    for (int j4 = 0; j4 < 16; j4 += 4){
      float4 a = *(const float4*)(key + base + j4);
      x[j4]=a.x; x[j4+1]=a.y; x[j4+2]=a.z; x[j4+3]=a.w;
    }
    #pragma unroll
    for (int j = 0; j < 16; j++) x[j] += dsp[j];
    #pragma unroll
    for (int j = 0; j < 16; j++){
      float a = 0.f;
      #pragma unroll
      for (int i = 0; i < 16; i++) a += x[i] * wk[i][j];
      r0[j] = a;
    }
    #pragma unroll
    for (int j = 0; j < 16; j++) kh[n][j] = r0[j];
  }
  __syncthreads();

  // pass 1: thread = (column n, q-half); khr from LDS; 4 independent online chains over 128 q's
  {
    float khr[16];
    #pragma unroll
    for (int j4 = 0; j4 < 16; j4 += 4){
      float4 a = *(const float4*)&kh[n][j4];
      khr[j4]=a.x; khr[j4+1]=a.y; khr[j4+2]=a.z; khr[j4+3]=a.w;
    }
    const int q0 = half * 128;
    float m[4], s[4];
    #pragma unroll
    for (int c = 0; c < 4; c++){ m[c] = -1e30f; s[c] = 0.f; }
    for (int qq = 0; qq < 128; qq += 4){
      #pragma unroll
      for (int c = 0; c < 4; c++){
        const float* qrow = &qh[q0 + qq + c][0];
        float4 a0 = *(const float4*)(qrow);
        float4 a1 = *(const float4*)(qrow+4);
        float4 a2 = *(const float4*)(qrow+8);
        float4 a3 = *(const float4*)(qrow+12);
        float d = a0.x*khr[0]+a0.y*khr[1]+a0.z*khr[2]+a0.w*khr[3]
                + a1.x*khr[4]+a1.y*khr[5]+a1.z*khr[6]+a1.w*khr[7]
                + a2.x*khr[8]+a2.y*khr[9]+a2.z*khr[10]+a2.w*khr[11]
                + a3.x*khr[12]+a3.y*khr[13]+a3.z*khr[14]+a3.w*khr[15];
        d *= 0.125f;
        float mn = fmaxf(m[c], d);
        s[c] = s[c]*__expf(m[c]-mn) + __expf(d-mn);
        m[c] = mn;
      }
    }
    float M = fmaxf(fmaxf(m[0],m[1]), fmaxf(m[2],m[3]));
    float S = s[0]*__expf(m[0]-M) + s[1]*__expf(m[1]-M)
            + s[2]*__expf(m[2]-M) + s[3]*__expf(m[3]-M);
    pm[half][n] = M; ps[half][n] = S;
  }
  __syncthreads();
  if (tid < 256){
    float m0 = pm[0][n], m1 = pm[1][n];
    float M = fmaxf(m0, m1);
    float S = ps[0][n]*__expf(m0-M) + ps[1][n]*__expf(m1-M);
    mArr[n] = M;
    invArr[n] = 1.f / S;
  }
  __syncthreads();

  // pass 2: thread = (row n, k-half); qhr from LDS; o partial over 128 k
  float qhr[16];
  #pragma unroll
  for (int j4 = 0; j4 < 16; j4 += 4){
    float4 a = *(const float4*)&qh[n][j4];
    qhr[j4]=a.x; qhr[j4+1]=a.y; qhr[j4+2]=a.z; qhr[j4+3]=a.w;
  }
  __syncthreads();   // all qh reads done before the partial-o region reuse

  float o[16];
  #pragma unroll
  for (int j = 0; j < 16; j++) o[j] = 0.f;
  {
    const int k0 = half * 128;
    for (int k = k0; k < k0 + 128; k++){
      const float* krow = &kh[k][0];
      float4 a0 = *(const float4*)(krow);
      float4 a1 = *(const float4*)(krow+4);
      float4 a2 = *(const float4*)(krow+8);
      float4 a3 = *(const float4*)(krow+12);
      float d = a0.x*qhr[0]+a0.y*qhr[1]+a0.z*qhr[2]+a0.w*qhr[3]
              + a1.x*qhr[4]+a1.y*qhr[5]+a1.z*qhr[6]+a1.w*qhr[7]
              + a2.x*qhr[8]+a2.y*qhr[9]+a2.z*qhr[10]+a2.w*qhr[11]
              + a3.x*qhr[12]+a3.y*qhr[13]+a3.z*qhr[14]+a3.w*qhr[15];
      float p = __expf(d*0.125f - mArr[k]) * invArr[k];
      uint4 v0 = *(const uint4*)&vh[k][0];
      uint4 v1 = *(const uint4*)&vh[k][8];
      float vv2[16]; unpack8(v0, vv2); unpack8(v1, vv2+8);
      #pragma unroll
      for (int j = 0; j < 16; j++) o[j] += p * vv2[j];
    }
  }
  // combine halves: half1 -> LDS (reuse qh), half0 adds + writes out
  float* po = &qh[0][0];   // [256][16] region
  if (half == 1){
    #pragma unroll
    for (int j4 = 0; j4 < 16; j4 += 4)
      *(float4*)(po + n*16 + j4) = make_float4(o[j4], o[j4+1], o[j4+2], o[j4+3]);
  }
  __syncthreads();
  if (half == 0){
    float* op = o_ws + base;
    #pragma unroll
    for (int j4 = 0; j4 < 16; j4 += 4){
      float4 pv = *(const float4*)(po + n*16 + j4);
      *(float4*)(op + j4) = make_float4(o[j4]+pv.x, o[j4+1]+pv.y, o[j4+2]+pv.z, o[j4+3]+pv.w);
    }
  }
}

// ---------------- fused epilogue, transposed: lane=token, wave=16-ch quarter ----------------
// 64 tokens/block, 256 threads (4 waves). Weights wave-uniform scalar loads. No big per-thread arrays.
__global__ __launch_bounds__(256)
void k_final(const float* __restrict__ query, const float* __restrict__ dsb,
             const float* __restrict__ o_ws, const float* __restrict__ xg_ws,
             const float* __restrict__ Wfc, const float* __restrict__ bfc,
             const float* __restrict__ ln1g, const float* __restrict__ ln1b,
             const float* __restrict__ ln2g, const float* __restrict__ ln2b,
             const float* __restrict__ Wff1, const float* __restrict__ bff1,
             const float* __restrict__ Wff2, const float* __restrict__ bff2,
             const float* __restrict__ Wfs, const float* __restrict__ bfs,
             const float* __restrict__ Wfg, const float* __restrict__ bfg,
             float* __restrict__ out)
{
  __shared__ float smA[64*66];    // o_t -> us_t
  __shared__ float smB[64*66];    // qd_t -> ms_t -> out_t
  __shared__ float smH[128*66];   // ff1 hidden chunks -> xg_t
  __shared__ float lnxA[4][64];
  __shared__ float lnxB[4][64];

  const int tid = threadIdx.x;
  const int token0 = blockIdx.x * 64;
  const int w = rfl(tid >> 6);         // wave id (wave-uniform)
  const int tok = tid & 63;
  const int c0 = w * 16;               // output channel quarter

  #pragma unroll
  for (int it = 0; it < 4; it++){
    int idx = tid + 256*it;             // 0..1023
    int tk = idx >> 4, c4 = (idx & 15) * 4;
    int gtok = token0 + tk;
    int n = (gtok / T_) & (N_-1);
    float4 ov = *(const float4*)(o_ws + (size_t)gtok*C_ + c4);
    float4 qv = *(const float4*)(query + (size_t)gtok*C_ + c4);
    float4 dv = *(const float4*)(dsb + n*C_ + c4);
    smA[(c4+0)*66+tk] = ov.x; smA[(c4+1)*66+tk] = ov.y; smA[(c4+2)*66+tk] = ov.z; smA[(c4+3)*66+tk] = ov.w;
    smB[(c4+0)*66+tk] = qv.x+dv.x; smB[(c4+1)*66+tk] = qv.y+dv.y; smB[(c4+2)*66+tk] = qv.z+dv.z; smB[(c4+3)*66+tk] = qv.w+dv.w;
  }
  __syncthreads();

  // fc: x1 = o @ Wfc + bfc + (q+ds), this wave's 16 channels
  float x1[16];
  #pragma unroll
  for (int j = 0; j < 16; j++) x1[j] = 0.f;
  for (int i = 0; i < C_; i++){
    float ov = smA[i*66 + tok];
    const float* wrow = Wfc + i*C_ + c0;
    #pragma unroll
    for (int j = 0; j < 16; j++) x1[j] += ov * wrow[j];
  }
  #pragma unroll
  for (int j = 0; j < 16; j++) x1[j] += bfc[c0+j] + smB[(c0+j)*66 + tok];

  // LN1 (cross-wave via lnxA/lnxB)
  float s1 = 0.f;
  #pragma unroll
  for (int j = 0; j < 16; j++) s1 += x1[j];
  lnxA[w][tok] = s1;
  __syncthreads();
  float mu = (lnxA[0][tok]+lnxA[1][tok]+lnxA[2][tok]+lnxA[3][tok]) * (1.f/64.f);
  float v1 = 0.f;
  #pragma unroll
  for (int j = 0; j < 16; j++){ float d = x1[j]-mu; v1 += d*d; }
  lnxB[w][tok] = v1;
  __syncthreads();
  float var = (lnxB[0][tok]+lnxB[1][tok]+lnxB[2][tok]+lnxB[3][tok]) * (1.f/64.f);
  float rstd = rsqrtf(var + 1e-5f);
  float ms[16];
  #pragma unroll
  for (int j = 0; j < 16; j++) ms[j] = (x1[j]-mu)*rstd*ln1g[c0+j] + ln1b[c0+j];
  __syncthreads();
  #pragma unroll
  for (int j = 0; j < 16; j++) smB[(c0+j)*66 + tok] = ms[j];
  __syncthreads();

  // FFN: wave w owns hidden [w*64, w*64+64) in two 32-chunks via smH; part[16] only
  float part[16];
  #pragma unroll
  for (int j = 0; j < 16; j++) part[j] = 0.f;
  #pragma unroll
  for (int ch = 0; ch < 2; ch++){
    float fch[32];
    #pragma unroll
    for (int kk = 0; kk < 32; kk++) fch[kk] = 0.f;
    const int kbase = w*64 + ch*32;
    for (int i = 0; i < C_; i++){
      float msv = smB[i*66 + tok];
      const float* wrow = Wff1 + i*(4*C_) + kbase;
      #pragma unroll
      for (int kk = 0; kk < 32; kk++) fch[kk] += msv * wrow[kk];
    }
    #pragma unroll
    for (int kk = 0; kk < 32; kk++){
      float v = fch[kk] + bff1[kbase+kk];
      fch[kk] = v > 0.f ? v : 0.f;
    }
    if (ch) __syncthreads();
    #pragma unroll
    for (int kk = 0; kk < 32; kk++) smH[(w*32+kk)*66 + tok] = fch[kk];
    __syncthreads();
    #pragma unroll
    for (int wq = 0; wq < 4; wq++){
      #pragma unroll 8
      for (int kk = 0; kk < 32; kk++){
        int k = wq*64 + ch*32 + kk;
        float hv = smH[(wq*32+kk)*66 + tok];
        const float* wrow = Wff2 + k*C_ + c0;
        #pragma unroll
        for (int j = 0; j < 16; j++) part[j] += hv * wrow[j];
      }
    }
  }
  float x2[16];
  #pragma unroll
  for (int j = 0; j < 16; j++) x2[j] = part[j] + bff2[c0+j] + ms[j];

  // LN2
  float s2 = 0.f;
  #pragma unroll
  for (int j = 0; j < 16; j++) s2 += x2[j];
  __syncthreads();
  lnxA[w][tok] = s2;
  __syncthreads();
  float mu2 = (lnxA[0][tok]+lnxA[1][tok]+lnxA[2][tok]+lnxA[3][tok]) * (1.f/64.f);
  float v2 = 0.f;
  #pragma unroll
  for (int j = 0; j < 16; j++){ float d = x2[j]-mu2; v2 += d*d; }
  lnxB[w][tok] = v2;
  __syncthreads();
  float var2 = (lnxB[0][tok]+lnxB[1][tok]+lnxB[2][tok]+lnxB[3][tok]) * (1.f/64.f);
  float rstd2 = rsqrtf(var2 + 1e-5f);
  float us[16];
  #pragma unroll
  for (int j = 0; j < 16; j++) us[j] = (x2[j]-mu2)*rstd2*ln2g[c0+j] + ln2b[c0+j];

  #pragma unroll
  for (int j = 0; j < 16; j++) smA[(c0+j)*66 + tok] = us[j];
  #pragma unroll
  for (int it = 0; it < 4; it++){
    int idx = tid + 256*it;
    int tk = idx >> 4, c4 = (idx & 15) * 4;
    int gtok = token0 + tk;
    float4 xv = *(const float4*)(xg_ws + (size_t)gtok*C_ + c4);
    smH[(c4+0)*66+tk] = xv.x; smH[(c4+1)*66+tk] = xv.y; smH[(c4+2)*66+tk] = xv.z; smH[(c4+3)*66+tk] = xv.w;
  }
  __syncthreads();

  // gate
  float ga[16];
  #pragma unroll
  for (int j = 0; j < 16; j++) ga[j] = 0.f;
  for (int i = 0; i < C_; i++){
    float uv = smA[i*66 + tok];
    float xv = smH[i*66 + tok];
    const float* wsr = Wfs + i*C_ + c0;
    const float* wgr = Wfg + i*C_ + c0;
    #pragma unroll
    for (int j = 0; j < 16; j++) ga[j] += uv*wsr[j] + xv*wgr[j];
  }
  float res[16];
  #pragma unroll
  for (int j = 0; j < 16; j++){
    float a = ga[j] + bfs[c0+j] + bfg[c0+j];
    float gg = 1.f / (1.f + __expf(-a));
    float xgv = smH[(c0+j)*66 + tok];
    res[j] = gg*us[j] + (1.f-gg)*xgv;
  }
  __syncthreads();
  #pragma unroll
  for (int j = 0; j < 16; j++) smB[(c0+j)*66 + tok] = res[j];
  __syncthreads();
  #pragma unroll
  for (int it = 0; it < 4; it++){
    int idx = tid + 256*it;
    int tk = idx >> 4, c4 = (idx & 15) * 4;
    int gtok = token0 + tk;
    float4 v = make_float4(smB[(c4+0)*66+tk], smB[(c4+1)*66+tk],
                           smB[(c4+2)*66+tk], smB[(c4+3)*66+tk]);
    *(float4*)(out + (size_t)gtok*C_ + c4) = v;
  }
}

extern "C" void kernel_launch(void* const* d_in, const int* in_sizes, int n_in,
                              void* d_out, int out_size, void* d_ws, size_t ws_size,
                              hipStream_t stream)
{
  (void)in_sizes; (void)n_in; (void)out_size; (void)ws_size;
  const float* query = (const float*)d_in[0];
  const float* key   = (const float*)d_in[1];
  const float* value = (const float*)d_in[2];
  const float* DSm   = (const float*)d_in[4];
  const float* Wemb  = (const float*)d_in[5];
  const float* bemb  = (const float*)d_in[6];
  const float* Wq    = (const float*)d_in[7];
  const float* Wk    = (const float*)d_in[8];
  const float* Wv    = (const float*)d_in[9];
  const float* Wfc   = (const float*)d_in[10];
  const float* bfc   = (const float*)d_in[11];
  const float* ln1g  = (const float*)d_in[12];
  const float* ln1b  = (const float*)d_in[13];
  const float* ln2g  = (const float*)d_in[14];
  const float* ln2b  = (const float*)d_in[15];
  const float* Wff1  = (const float*)d_in[16];
  const float* bff1  = (const float*)d_in[17];
  const float* Wff2  = (const float*)d_in[18];
  const float* bff2  = (const float*)d_in[19];
  const float* g1W   = (const float*)d_in[20];
  const float* g1as  = (const float*)d_in[21];
  const float* g1ad  = (const float*)d_in[22];
  const float* g1b   = (const float*)d_in[23];
  const float* g2W   = (const float*)d_in[24];
  const float* g2as  = (const float*)d_in[25];
  const float* g2ad  = (const float*)d_in[26];
  const float* g2b   = (const float*)d_in[27];
  const float* jkW   = (const float*)d_in[28];
  const float* jkb   = (const float*)d_in[29];
  const float* Wfs   = (const float*)d_in[30];
  const float* bfs   = (const float*)d_in[31];
  const float* Wfg   = (const float*)d_in[32];
  const float* bfg   = (const float*)d_in[33];
  const int* ei      = (const int*)d_in[34];
  float* out = (float*)d_out;

  float* wf     = (float*)d_ws;
  float* dsb    = wf + DS_OFF;
  float* xg_ws  = wf + XG_OFF;
  u16*   hA     = (u16*)(wf + HA_OFF);
  u16*   hB     = (u16*)(wf + HB_OFF);
  float* o_ws   = wf + HA_OFF;             // aliases hA (dead before k_attn)
  float* hs_ws  = wf + HS_OFF;
  float* hd_ws  = wf + HD_OFF;
  int*   indptr = (int*)(wf + INT_OFF);
  int*   srcs   = indptr + 260;

  k_csr<<<dim3(1), dim3(256), 0, stream>>>(ei, indptr, srcs);
  k_ds<<<dim3(N_), dim3(C_), 0, stream>>>(DSm, Wemb, bemb, dsb);
  k_lin1<<<dim3(G_*4), dim3(256), 0, stream>>>(query, g1W, g1as, g1ad, hA, hs_ws, hd_ws);
  k_agg <<<dim3(G_*4), dim3(256), 0, stream>>>(hA, hs_ws, hd_ws, indptr, srcs, g1b, hB, 0);
  k_lin2<<<dim3(G_*4), dim3(256), 0, stream>>>(hB, g2W, g2as, g2ad, hA, hs_ws, hd_ws);
  k_agg <<<dim3(G_*4), dim3(256), 0, stream>>>(hA, hs_ws, hd_ws, indptr, srcs, g2b, hB, 1);
  k_jk  <<<dim3(G_*4), dim3(256), 0, stream>>>(hB, jkW, jkb, xg_ws);
  k_attn<<<dim3(B_*T_*H_), dim3(512), 0, stream>>>(query, key, value, Wq, Wk, Wv, dsb, o_ws);
  k_final<<<dim3(TOK_/64), dim3(256), 0, stream>>>(query, dsb, o_ws, xg_ws,
      Wfc, bfc, ln1g, ln1b, ln2g, ln2b,
      Wff1, bff1, Wff2, bff2,
      Wfs, bfs, Wfg, bfg, out);
}

// Round 7
// 410.923 us; speedup vs baseline: 1.0586x; 1.0586x over previous
//
#include <hip/hip_runtime.h>

typedef unsigned short u16;
typedef unsigned int u32;

#define B_ 4
#define N_ 256
#define T_ 36
#define C_ 64
#define H_ 4
#define D_ 16
#define CH_ 128
#define E_ 4096
#define G_ (B_*T_)
#define TOK_ (B_*N_*T_)

// workspace layout (float offsets)
#define DS_OFF  0
#define XG_OFF  (DS_OFF + N_*C_)
#define HA_OFF  (XG_OFF + TOK_*C_)          // bf16 h buffer A (conv outs) ; aliased by o_ws later
#define HB_OFF  (HA_OFF + G_*N_*CH_/2)      // bf16 buffer B (h1 / jk input)
#define HS_OFF  (HB_OFF + G_*N_*CH_/2)
#define HD_OFF  (HS_OFF + G_*N_)
#define INT_OFF (HD_OFF + G_*N_)
#define MS_OFF  (INT_OFF + 4608)            // (m, 1/S) pairs: 576 * 512 floats

__device__ __forceinline__ float bf2f(u16 u){
  u32 x = ((u32)u) << 16;
  return __builtin_bit_cast(float, x);
}
__device__ __forceinline__ u16 f2bf(float f){
  u32 x = __builtin_bit_cast(u32, f);
  x += 0x7fffu + ((x >> 16) & 1u);
  return (u16)(x >> 16);
}
__device__ __forceinline__ void unpack8(uint4 u, float* f){
  f[0]=bf2f((u16)(u.x & 0xffffu)); f[1]=bf2f((u16)(u.x >> 16));
  f[2]=bf2f((u16)(u.y & 0xffffu)); f[3]=bf2f((u16)(u.y >> 16));
  f[4]=bf2f((u16)(u.z & 0xffffu)); f[5]=bf2f((u16)(u.z >> 16));
  f[6]=bf2f((u16)(u.w & 0xffffu)); f[7]=bf2f((u16)(u.w >> 16));
}
__device__ __forceinline__ uint4 pack8f(const float* f){
  uint4 u;
  u.x = (u32)f2bf(f[0]) | ((u32)f2bf(f[1]) << 16);
  u.y = (u32)f2bf(f[2]) | ((u32)f2bf(f[3]) << 16);
  u.z = (u32)f2bf(f[4]) | ((u32)f2bf(f[5]) << 16);
  u.w = (u32)f2bf(f[6]) | ((u32)f2bf(f[7]) << 16);
  return u;
}
__device__ __forceinline__ int rfl(int v){ return __builtin_amdgcn_readfirstlane(v); }

// ---------------- deterministic CSR: bucket by dst (atomic), stable-sort by edge id ----------------
__global__ void k_csr(const int* __restrict__ ei, int* __restrict__ indptr, int* __restrict__ srcs)
{
  __shared__ int srcL[E_];
  __shared__ int dstL[E_];
  __shared__ int tmp[E_];
  __shared__ int cnt[N_];
  __shared__ int base[N_+1];
  const int tid = threadIdx.x;   // 256
  for (int e = tid; e < E_; e += 256){ srcL[e] = ei[e]; dstL[e] = ei[E_ + e]; }
  cnt[tid] = 0;
  __syncthreads();
  for (int e = tid; e < E_; e += 256) atomicAdd(&cnt[dstL[e]], 1);
  __syncthreads();
  if (tid == 0){
    int run = 0;
    for (int i = 0; i < N_; i++){ base[i] = run; run += cnt[i]; }
    base[N_] = run;
  }
  __syncthreads();
  cnt[tid] = 0;
  __syncthreads();
  for (int e = tid; e < E_; e += 256){
    int d = dstL[e];
    int p = atomicAdd(&cnt[d], 1);
    tmp[base[d] + p] = e;
  }
  __syncthreads();
  {
    const int p0 = base[tid], p1 = base[tid] + cnt[tid];
    for (int i = p0 + 1; i < p1; i++){      // insertion sort by edge id -> stable/deterministic
      int v = tmp[i]; int j = i - 1;
      while (j >= p0 && tmp[j] > v){ tmp[j+1] = tmp[j]; j--; }
      tmp[j+1] = v;
    }
    for (int j = p0; j < p1; j++) srcs[j] = srcL[tmp[j]];
  }
  indptr[tid] = base[tid];
  if (tid == 0) indptr[N_] = base[N_];
}

// ---------------- ds = D_S @ W_emb + b_emb ----------------
__global__ void k_ds(const float* __restrict__ DSm, const float* __restrict__ Wemb,
                     const float* __restrict__ bemb, float* __restrict__ dsb)
{
  const int n = blockIdx.x, c = threadIdx.x;
  float acc = bemb[c];
  for (int m = 0; m < N_; m++) acc += DSm[n*N_ + m] * Wemb[m*C_ + c];
  dsb[n*C_ + c] = acc;
}

// ---------------- GAT conv1 linear: h = bf16(x @ W1), fused hs/hd ----------------
__global__ __launch_bounds__(256)
void k_lin1(const float* __restrict__ query, const float* __restrict__ W1,
            const float* __restrict__ as1, const float* __restrict__ ad1,
            u16* __restrict__ h, float* __restrict__ hs_ws, float* __restrict__ hd_ws)
{
  __shared__ float xs[64][65];
  __shared__ float red[2][4][64];
  const int bid = blockIdx.x;
  const int g = bid >> 2, n0 = (bid & 3) * 64;
  const int b = g / T_, t = g % T_;
  const int tid = threadIdx.x;

  {
    const size_t gb = (((size_t)b*N_ + n0)*T_ + t)*C_;
    #pragma unroll
    for (int it = 0; it < 4; it++){
      int idx = tid + 256*it;
      int row = idx >> 4, c4 = (idx & 15) * 4;
      float4 v = *(const float4*)(query + gb + (size_t)row*(T_*C_) + c4);
      xs[row][c4+0] = v.x; xs[row][c4+1] = v.y; xs[row][c4+2] = v.z; xs[row][c4+3] = v.w;
    }
  }
  __syncthreads();

  const int r = tid & 63;
  const int cb = rfl(tid >> 6);
  const int ch0 = cb * 32;

  float acc[32];
  #pragma unroll
  for (int j = 0; j < 32; j++) acc[j] = 0.f;
  for (int k = 0; k < 64; k++){
    float xv = xs[r][k];
    const float* wrow = W1 + k*CH_ + ch0;   // scalar (uniform) loads
    #pragma unroll
    for (int j = 0; j < 32; j++) acc[j] += xv * wrow[j];
  }
  float hs = 0.f, hd = 0.f;
  #pragma unroll
  for (int j = 0; j < 32; j++){ hs += acc[j]*as1[ch0+j]; hd += acc[j]*ad1[ch0+j]; }
  red[0][cb][r] = hs; red[1][cb][r] = hd;

  u16* hp = h + ((size_t)(g*N_ + n0 + r))*CH_ + ch0;
  #pragma unroll
  for (int j8 = 0; j8 < 32; j8 += 8)
    *(uint4*)(hp + j8) = pack8f(&acc[j8]);

  __syncthreads();
  if (tid < 64){
    float a = red[0][0][tid]+red[0][1][tid]+red[0][2][tid]+red[0][3][tid];
    float d = red[1][0][tid]+red[1][1][tid]+red[1][2][tid]+red[1][3][tid];
    hs_ws[g*N_ + n0 + tid] = a;
    hd_ws[g*N_ + n0 + tid] = d;
  }
}

// ---------------- GAT conv2 linear: h2 = bf16(h1 @ W2), fused hs2/hd2 ----------------
__global__ __launch_bounds__(256)
void k_lin2(const u16* __restrict__ h1, const float* __restrict__ W2,
            const float* __restrict__ as2, const float* __restrict__ ad2,
            u16* __restrict__ h2, float* __restrict__ hs_ws, float* __restrict__ hd_ws)
{
  __shared__ float xs[64][129];
  __shared__ float red[2][4][64];
  const int bid = blockIdx.x;
  const int g = bid >> 2, n0 = (bid & 3) * 64;
  const int tid = threadIdx.x;

  {
    #pragma unroll
    for (int it = 0; it < 4; it++){
      int idx = tid + 256*it;
      int row = idx >> 4, c8 = (idx & 15) * 8;
      uint4 u = *(const uint4*)(h1 + ((size_t)(g*N_ + n0 + row))*CH_ + c8);
      float v[8]; unpack8(u, v);
      #pragma unroll
      for (int i = 0; i < 8; i++) xs[row][c8+i] = v[i];
    }
  }
  __syncthreads();

  const int r = tid & 63;
  const int cb = rfl(tid >> 6);
  const int ch0 = cb * 32;

  float acc[32];
  #pragma unroll
  for (int j = 0; j < 32; j++) acc[j] = 0.f;
  for (int k = 0; k < 128; k++){
    float xv = xs[r][k];
    const float* wrow = W2 + k*CH_ + ch0;
    #pragma unroll
    for (int j = 0; j < 32; j++) acc[j] += xv * wrow[j];
  }
  float hs = 0.f, hd = 0.f;
  #pragma unroll
  for (int j = 0; j < 32; j++){ hs += acc[j]*as2[ch0+j]; hd += acc[j]*ad2[ch0+j]; }
  red[0][cb][r] = hs; red[1][cb][r] = hd;

  u16* hp = h2 + ((size_t)(g*N_ + n0 + r))*CH_ + ch0;
  #pragma unroll
  for (int j8 = 0; j8 < 32; j8 += 8)
    *(uint4*)(hp + j8) = pack8f(&acc[j8]);

  __syncthreads();
  if (tid < 64){
    float a = red[0][0][tid]+red[0][1][tid]+red[0][2][tid]+red[0][3][tid];
    float d = red[1][0][tid]+red[1][1][tid]+red[1][2][tid]+red[1][3][tid];
    hs_ws[g*N_ + n0 + tid] = a;
    hd_ws[g*N_ + n0 + tid] = d;
  }
}

// ---------------- GAT aggregation (+softmax in-block). layer2: jk max fused ----------------
__global__ __launch_bounds__(256)
void k_agg(const u16* __restrict__ hin, const float* __restrict__ hs_ws, const float* __restrict__ hd_ws,
           const int* __restrict__ indptr, const int* __restrict__ srcs,
           const float* __restrict__ bias, u16* __restrict__ hout, int layer2)
{
  __shared__ int   srcs_l[E_];
  __shared__ float alpha_l[E_];
  __shared__ float hs_l[N_];
  const int bid = blockIdx.x;
  const int g = bid >> 2, n0 = (bid & 3) * 64;
  const int tid = threadIdx.x;

  const int p00 = indptr[n0];
  const int pend = indptr[n0 + 64];
  const int cntE = pend - p00;
  for (int i = tid; i < cntE; i += 256) srcs_l[i] = srcs[p00 + i];
  hs_l[tid] = hs_ws[g*N_ + tid];
  __syncthreads();

  if (tid < 64){
    const int dst = n0 + tid;
    const int p0 = indptr[dst] - p00, p1 = indptr[dst+1] - p00;
    const float hdn = hd_ws[g*N_ + dst];
    for (int j = p0; j < p1; j++){
      float e = hs_l[srcs_l[j]] + hdn;
      alpha_l[j] = e > 0.f ? e : 0.2f * e;
    }
    float m = -1e30f;
    for (int j = p0; j < p1; j++) m = fmaxf(m, alpha_l[j]);
    float s = 0.f;
    for (int j = p0; j < p1; j++){
      float w = __expf(alpha_l[j] - m);
      alpha_l[j] = w; s += w;
    }
    float inv = 1.f / (s + 1e-16f);
    for (int j = p0; j < p1; j++) alpha_l[j] *= inv;
  }
  __syncthreads();

  const int r = tid & 63;
  const int cb = rfl(tid >> 6);
  const int ch0 = cb * 32;
  const int dst = n0 + r;
  const int p0 = indptr[dst] - p00, p1 = indptr[dst+1] - p00;

  float acc[32];
  #pragma unroll
  for (int j = 0; j < 32; j++) acc[j] = 0.f;
  for (int j = p0; j < p1; j++){
    float a = alpha_l[j];
    int s = srcs_l[j];
    const uint4* hp = (const uint4*)(hin + ((size_t)(g*N_ + s))*CH_ + ch0);
    #pragma unroll
    for (int q = 0; q < 4; q++){
      float hv[8]; unpack8(hp[q], hv);
      #pragma unroll
      for (int i = 0; i < 8; i++) acc[q*8+i] += a * hv[i];
    }
  }
  float o[32];
  #pragma unroll
  for (int j = 0; j < 32; j++){
    float v = acc[j] + bias[ch0+j];
    o[j] = v > 0.f ? v : 0.f;
  }
  u16* op = hout + ((size_t)(g*N_ + dst))*CH_ + ch0;
  if (layer2){
    #pragma unroll
    for (int j8 = 0; j8 < 32; j8 += 8){
      float h1v[8]; unpack8(*(const uint4*)(op + j8), h1v);
      #pragma unroll
      for (int i = 0; i < 8; i++) o[j8+i] = fmaxf(h1v[i], o[j8+i]);
    }
  }
  #pragma unroll
  for (int j8 = 0; j8 < 32; j8 += 8)
    *(uint4*)(op + j8) = pack8f(&o[j8]);
}

// ---------------- jk linear: xg(time-reversed) = jk @ jkW + jkb ----------------
__global__ __launch_bounds__(256)
void k_jk(const u16* __restrict__ jkin, const float* __restrict__ jkW, const float* __restrict__ jkb,
          float* __restrict__ xg)
{
  __shared__ float xs[64][129];
  const int bid = blockIdx.x;
  const int g = bid >> 2, n0 = (bid & 3) * 64;
  const int b = g / T_, t = g % T_;
  const int tid = threadIdx.x;

  {
    #pragma unroll
    for (int it = 0; it < 4; it++){
      int idx = tid + 256*it;
      int row = idx >> 4, c8 = (idx & 15) * 8;
      uint4 u = *(const uint4*)(jkin + ((size_t)(g*N_ + n0 + row))*CH_ + c8);
      float v[8]; unpack8(u, v);
      #pragma unroll
      for (int i = 0; i < 8; i++) xs[row][c8+i] = v[i];
    }
  }
  __syncthreads();

  const int r = tid & 63;
  const int cb = rfl(tid >> 6);
  const int o0 = cb * 16;

  float acc[16];
  #pragma unroll
  for (int j = 0; j < 16; j++) acc[j] = 0.f;
  for (int k = 0; k < 128; k++){
    float xv = xs[r][k];
    const float* wrow = jkW + k*C_ + o0;
    #pragma unroll
    for (int j = 0; j < 16; j++) acc[j] += xv * wrow[j];
  }
  float* op = xg + ((((size_t)b*N_ + n0 + r)*T_) + (T_-1-t))*C_ + o0;
  #pragma unroll
  for (int j4 = 0; j4 < 16; j4 += 4){
    float4 v = make_float4(acc[j4]+jkb[o0+j4], acc[j4+1]+jkb[o0+j4+1],
                           acc[j4+2]+jkb[o0+j4+2], acc[j4+3]+jkb[o0+j4+3]);
    *(float4*)(op + j4) = v;
  }
}

// ---------------- attention stats: per (b,t,h), thread = column k; (m, 1/S) over q axis ----------------
#define SP_ 20   // 80B rows, 16B-aligned; loop reads are uniform-row broadcasts (conflict-free)
__global__ __launch_bounds__(256)
void k_stat(const float* __restrict__ query, const float* __restrict__ key,
            const float* __restrict__ Wq, const float* __restrict__ Wk,
            const float* __restrict__ dsb, float* __restrict__ mS)
{
  __shared__ float qs[N_][SP_];
  __shared__ float wq[16][16], wk[16][16];

  const int bx = blockIdx.x;
  const int b = bx / (T_*H_);
  const int rem = bx % (T_*H_);
  const int t = rem / H_;
  const int h = rem % H_;
  const int n = threadIdx.x;

  wq[n>>4][n&15] = Wq[n];
  wk[n>>4][n&15] = Wk[n];

  const size_t base = ((((size_t)b*N_ + n)*T_) + t)*C_ + h*D_;
  const float* dsp = dsb + n*C_ + h*D_;

  float x[16];
  #pragma unroll
  for (int j4 = 0; j4 < 16; j4 += 4){
    float4 a = *(const float4*)(query + base + j4);
    float4 d = *(const float4*)(dsp + j4);
    x[j4]=a.x+d.x; x[j4+1]=a.y+d.y; x[j4+2]=a.z+d.z; x[j4+3]=a.w+d.w;
  }
  __syncthreads();   // weights staged
  #pragma unroll
  for (int j = 0; j < 16; j++){
    float a = 0.f;
    #pragma unroll
    for (int i = 0; i < 16; i++) a += x[i]*wq[i][j];
    qs[n][j] = a;
  }
  float khr[16];
  #pragma unroll
  for (int j4 = 0; j4 < 16; j4 += 4){
    float4 a = *(const float4*)(key + base + j4);
    float4 d = *(const float4*)(dsp + j4);
    x[j4]=a.x+d.x; x[j4+1]=a.y+d.y; x[j4+2]=a.z+d.z; x[j4+3]=a.w+d.w;
  }
  #pragma unroll
  for (int j = 0; j < 16; j++){
    float a = 0.f;
    #pragma unroll
    for (int i = 0; i < 16; i++) a += x[i]*wk[i][j];
    khr[j] = a;
  }
  __syncthreads();   // qs complete

  // 4 independent online chains over q (64 each)
  float m[4], s[4];
  #pragma unroll
  for (int c = 0; c < 4; c++){ m[c] = -1e30f; s[c] = 0.f; }
  for (int qq = 0; qq < 64; qq++){
    #pragma unroll
    for (int c = 0; c < 4; c++){
      const float* qrow = &qs[qq + 64*c][0];
      float4 a0 = *(const float4*)(qrow);
      float4 a1 = *(const float4*)(qrow+4);
      float4 a2 = *(const float4*)(qrow+8);
      float4 a3 = *(const float4*)(qrow+12);
      float d = a0.x*khr[0]+a0.y*khr[1]+a0.z*khr[2]+a0.w*khr[3]
              + a1.x*khr[4]+a1.y*khr[5]+a1.z*khr[6]+a1.w*khr[7]
              + a2.x*khr[8]+a2.y*khr[9]+a2.z*khr[10]+a2.w*khr[11]
              + a3.x*khr[12]+a3.y*khr[13]+a3.z*khr[14]+a3.w*khr[15];
      d *= 0.125f;
      float mn = fmaxf(m[c], d);
      s[c] = s[c]*__expf(m[c]-mn) + __expf(d-mn);
      m[c] = mn;
    }
  }
  float M = fmaxf(fmaxf(m[0],m[1]), fmaxf(m[2],m[3]));
  float S = s[0]*__expf(m[0]-M) + s[1]*__expf(m[1]-M)
          + s[2]*__expf(m[2]-M) + s[3]*__expf(m[3]-M);
  mS[(size_t)bx*512 + n*2]     = M;
  mS[(size_t)bx*512 + n*2 + 1] = 1.f / S;
}

// ---------------- attention AV: per (b,t,h), thread = row q; stats precomputed (no serial chain) ----------------
__global__ __launch_bounds__(256)
void k_av(const float* __restrict__ query, const float* __restrict__ key, const float* __restrict__ value,
          const float* __restrict__ Wq, const float* __restrict__ Wk, const float* __restrict__ Wv,
          const float* __restrict__ dsb, const float* __restrict__ mS, float* __restrict__ o_ws)
{
  __shared__ float ks[N_][SP_];
  __shared__ float vs[N_][SP_];
  __shared__ float2 msl[N_];
  __shared__ float wq[16][16], wk[16][16], wv[16][16];

  const int bx = blockIdx.x;
  const int b = bx / (T_*H_);
  const int rem = bx % (T_*H_);
  const int t = rem / H_;
  const int h = rem % H_;
  const int n = threadIdx.x;

  wq[n>>4][n&15] = Wq[n];
  wk[n>>4][n&15] = Wk[n];
  wv[n>>4][n&15] = Wv[n];
  msl[n] = *(const float2*)(mS + (size_t)bx*512 + n*2);

  const size_t base = ((((size_t)b*N_ + n)*T_) + t)*C_ + h*D_;
  const float* dsp = dsb + n*C_ + h*D_;

  float ds16[16];
  #pragma unroll
  for (int j4 = 0; j4 < 16; j4 += 4){
    float4 d = *(const float4*)(dsp + j4);
    ds16[j4]=d.x; ds16[j4+1]=d.y; ds16[j4+2]=d.z; ds16[j4+3]=d.w;
  }
  __syncthreads();   // weights staged

  float x[16];
  // kh -> LDS
  #pragma unroll
  for (int j4 = 0; j4 < 16; j4 += 4){
    float4 a = *(const float4*)(key + base + j4);
    x[j4]=a.x+ds16[j4]; x[j4+1]=a.y+ds16[j4+1]; x[j4+2]=a.z+ds16[j4+2]; x[j4+3]=a.w+ds16[j4+3];
  }
  #pragma unroll
  for (int j = 0; j < 16; j++){
    float a = 0.f;
    #pragma unroll
    for (int i = 0; i < 16; i++) a += x[i]*wk[i][j];
    ks[n][j] = a;
  }
  // vh -> LDS
  #pragma unroll
  for (int j4 = 0; j4 < 16; j4 += 4){
    float4 a = *(const float4*)(value + base + j4);
    x[j4]=a.x+ds16[j4]; x[j4+1]=a.y+ds16[j4+1]; x[j4+2]=a.z+ds16[j4+2]; x[j4+3]=a.w+ds16[j4+3];
  }
  #pragma unroll
  for (int j = 0; j < 16; j++){
    float a = 0.f;
    #pragma unroll
    for (int i = 0; i < 16; i++) a += x[i]*wv[i][j];
    vs[n][j] = a;
  }
  // qh -> registers
  float qhr[16];
  #pragma unroll
  for (int j4 = 0; j4 < 16; j4 += 4){
    float4 a = *(const float4*)(query + base + j4);
    x[j4]=a.x+ds16[j4]; x[j4+1]=a.y+ds16[j4+1]; x[j4+2]=a.z+ds16[j4+2]; x[j4+3]=a.w+ds16[j4+3];
  }
  #pragma unroll
  for (int j = 0; j < 16; j++){
    float a = 0.f;
    #pragma unroll
    for (int i = 0; i < 16; i++) a += x[i]*wq[i][j];
    qhr[j] = a;
  }
  __syncthreads();   // ks/vs/msl complete

  // o = sum_k exp(s-m[k])*inv[k] * vh[k]; unroll x2, two accumulators (no inter-k dependency)
  float o0[16], o1[16];
  #pragma unroll
  for (int j = 0; j < 16; j++){ o0[j] = 0.f; o1[j] = 0.f; }
  for (int k = 0; k < N_; k += 2){
    {
      const float* krow = &ks[k][0];
      float4 a0 = *(const float4*)(krow);
      float4 a1 = *(const float4*)(krow+4);
      float4 a2 = *(const float4*)(krow+8);
      float4 a3 = *(const float4*)(krow+12);
      float d = a0.x*qhr[0]+a0.y*qhr[1]+a0.z*qhr[2]+a0.w*qhr[3]
              + a1.x*qhr[4]+a1.y*qhr[5]+a1.z*qhr[6]+a1.w*qhr[7]
              + a2.x*qhr[8]+a2.y*qhr[9]+a2.z*qhr[10]+a2.w*qhr[11]
              + a3.x*qhr[12]+a3.y*qhr[13]+a3.z*qhr[14]+a3.w*qhr[15];
      float2 ms0 = msl[k];
      float p = __expf(d*0.125f - ms0.x) * ms0.y;
      const float* vrow = &vs[k][0];
      float4 v0 = *(const float4*)(vrow);
      float4 v1 = *(const float4*)(vrow+4);
      float4 v2 = *(const float4*)(vrow+8);
      float4 v3 = *(const float4*)(vrow+12);
      o0[0]+=p*v0.x; o0[1]+=p*v0.y; o0[2]+=p*v0.z; o0[3]+=p*v0.w;
      o0[4]+=p*v1.x; o0[5]+=p*v1.y; o0[6]+=p*v1.z; o0[7]+=p*v1.w;
      o0[8]+=p*v2.x; o0[9]+=p*v2.y; o0[10]+=p*v2.z; o0[11]+=p*v2.w;
      o0[12]+=p*v3.x; o0[13]+=p*v3.y; o0[14]+=p*v3.z; o0[15]+=p*v3.w;
    }
    {
      const float* krow = &ks[k+1][0];
      float4 a0 = *(const float4*)(krow);
      float4 a1 = *(const float4*)(krow+4);
      float4 a2 = *(const float4*)(krow+8);
      float4 a3 = *(const float4*)(krow+12);
      float d = a0.x*qhr[0]+a0.y*qhr[1]+a0.z*qhr[2]+a0.w*qhr[3]
              + a1.x*qhr[4]+a1.y*qhr[5]+a1.z*qhr[6]+a1.w*qhr[7]
              + a2.x*qhr[8]+a2.y*qhr[9]+a2.z*qhr[10]+a2.w*qhr[11]
              + a3.x*qhr[12]+a3.y*qhr[13]+a3.z*qhr[14]+a3.w*qhr[15];
      float2 ms1 = msl[k+1];
      float p = __expf(d*0.125f - ms1.x) * ms1.y;
      const float* vrow = &vs[k+1][0];
      float4 v0 = *(const float4*)(vrow);
      float4 v1 = *(const float4*)(vrow+4);
      float4 v2 = *(const float4*)(vrow+8);
      float4 v3 = *(const float4*)(vrow+12);
      o1[0]+=p*v0.x; o1[1]+=p*v0.y; o1[2]+=p*v0.z; o1[3]+=p*v0.w;
      o1[4]+=p*v1.x; o1[5]+=p*v1.y; o1[6]+=p*v1.z; o1[7]+=p*v1.w;
      o1[8]+=p*v2.x; o1[9]+=p*v2.y; o1[10]+=p*v2.z; o1[11]+=p*v2.w;
      o1[12]+=p*v3.x; o1[13]+=p*v3.y; o1[14]+=p*v3.z; o1[15]+=p*v3.w;
    }
  }
  float* op = o_ws + base;
  #pragma unroll
  for (int j4 = 0; j4 < 16; j4 += 4)
    *(float4*)(op + j4) = make_float4(o0[j4]+o1[j4], o0[j4+1]+o1[j4+1],
                                      o0[j4+2]+o1[j4+2], o0[j4+3]+o1[j4+3]);
}

// ---------------- fused epilogue, transposed: lane=token, wave=16-ch quarter ----------------
__global__ __launch_bounds__(256)
void k_final(const float* __restrict__ query, const float* __restrict__ dsb,
             const float* __restrict__ o_ws, const float* __restrict__ xg_ws,
             const float* __restrict__ Wfc, const float* __restrict__ bfc,
             const float* __restrict__ ln1g, const float* __restrict__ ln1b,
             const float* __restrict__ ln2g, const float* __restrict__ ln2b,
             const float* __restrict__ Wff1, const float* __restrict__ bff1,
             const float* __restrict__ Wff2, const float* __restrict__ bff2,
             const float* __restrict__ Wfs, const float* __restrict__ bfs,
             const float* __restrict__ Wfg, const float* __restrict__ bfg,
             float* __restrict__ out)
{
  __shared__ float smA[64*66];    // o_t -> us_t
  __shared__ float smB[64*66];    // qd_t -> ms_t -> out_t
  __shared__ float smH[128*66];   // ff1 hidden chunks -> xg_t
  __shared__ float lnxA[4][64];
  __shared__ float lnxB[4][64];

  const int tid = threadIdx.x;
  const int token0 = blockIdx.x * 64;
  const int w = rfl(tid >> 6);         // wave id (wave-uniform)
  const int tok = tid & 63;
  const int c0 = w * 16;               // output channel quarter

  #pragma unroll
  for (int it = 0; it < 4; it++){
    int idx = tid + 256*it;             // 0..1023
    int tk = idx >> 4, c4 = (idx & 15) * 4;
    int gtok = token0 + tk;
    int n = (gtok / T_) & (N_-1);
    float4 ov = *(const float4*)(o_ws + (size_t)gtok*C_ + c4);
    float4 qv = *(const float4*)(query + (size_t)gtok*C_ + c4);
    float4 dv = *(const float4*)(dsb + n*C_ + c4);
    smA[(c4+0)*66+tk] = ov.x; smA[(c4+1)*66+tk] = ov.y; smA[(c4+2)*66+tk] = ov.z; smA[(c4+3)*66+tk] = ov.w;
    smB[(c4+0)*66+tk] = qv.x+dv.x; smB[(c4+1)*66+tk] = qv.y+dv.y; smB[(c4+2)*66+tk] = qv.z+dv.z; smB[(c4+3)*66+tk] = qv.w+dv.w;
  }
  __syncthreads();

  // fc: x1 = o @ Wfc + bfc + (q+ds), this wave's 16 channels
  float x1[16];
  #pragma unroll
  for (int j = 0; j < 16; j++) x1[j] = 0.f;
  for (int i = 0; i < C_; i++){
    float ov = smA[i*66 + tok];
    const float* wrow = Wfc + i*C_ + c0;
    #pragma unroll
    for (int j = 0; j < 16; j++) x1[j] += ov * wrow[j];
  }
  #pragma unroll
  for (int j = 0; j < 16; j++) x1[j] += bfc[c0+j] + smB[(c0+j)*66 + tok];

  // LN1 (cross-wave via lnxA/lnxB)
  float s1 = 0.f;
  #pragma unroll
  for (int j = 0; j < 16; j++) s1 += x1[j];
  lnxA[w][tok] = s1;
  __syncthreads();
  float mu = (lnxA[0][tok]+lnxA[1][tok]+lnxA[2][tok]+lnxA[3][tok]) * (1.f/64.f);
  float v1 = 0.f;
  #pragma unroll
  for (int j = 0; j < 16; j++){ float d = x1[j]-mu; v1 += d*d; }
  lnxB[w][tok] = v1;
  __syncthreads();
  float var = (lnxB[0][tok]+lnxB[1][tok]+lnxB[2][tok]+lnxB[3][tok]) * (1.f/64.f);
  float rstd = rsqrtf(var + 1e-5f);
  float ms[16];
  #pragma unroll
  for (int j = 0; j < 16; j++) ms[j] = (x1[j]-mu)*rstd*ln1g[c0+j] + ln1b[c0+j];
  __syncthreads();
  #pragma unroll
  for (int j = 0; j < 16; j++) smB[(c0+j)*66 + tok] = ms[j];
  __syncthreads();

  // FFN: wave w owns hidden [w*64, w*64+64) in two 32-chunks via smH; part[16] only
  float part[16];
  #pragma unroll
  for (int j = 0; j < 16; j++) part[j] = 0.f;
  #pragma unroll
  for (int ch = 0; ch < 2; ch++){
    float fch[32];
    #pragma unroll
    for (int kk = 0; kk < 32; kk++) fch[kk] = 0.f;
    const int kbase = w*64 + ch*32;
    for (int i = 0; i < C_; i++){
      float msv = smB[i*66 + tok];
      const float* wrow = Wff1 + i*(4*C_) + kbase;
      #pragma unroll
      for (int kk = 0; kk < 32; kk++) fch[kk] += msv * wrow[kk];
    }
    #pragma unroll
    for (int kk = 0; kk < 32; kk++){
      float v = fch[kk] + bff1[kbase+kk];
      fch[kk] = v > 0.f ? v : 0.f;
    }
    if (ch) __syncthreads();
    #pragma unroll
    for (int kk = 0; kk < 32; kk++) smH[(w*32+kk)*66 + tok] = fch[kk];
    __syncthreads();
    #pragma unroll
    for (int wq = 0; wq < 4; wq++){
      #pragma unroll 8
      for (int kk = 0; kk < 32; kk++){
        int k = wq*64 + ch*32 + kk;
        float hv = smH[(wq*32+kk)*66 + tok];
        const float* wrow = Wff2 + k*C_ + c0;
        #pragma unroll
        for (int j = 0; j < 16; j++) part[j] += hv * wrow[j];
      }
    }
  }
  float x2[16];
  #pragma unroll
  for (int j = 0; j < 16; j++) x2[j] = part[j] + bff2[c0+j] + ms[j];

  // LN2
  float s2 = 0.f;
  #pragma unroll
  for (int j = 0; j < 16; j++) s2 += x2[j];
  __syncthreads();
  lnxA[w][tok] = s2;
  __syncthreads();
  float mu2 = (lnxA[0][tok]+lnxA[1][tok]+lnxA[2][tok]+lnxA[3][tok]) * (1.f/64.f);
  float v2 = 0.f;
  #pragma unroll
  for (int j = 0; j < 16; j++){ float d = x2[j]-mu2; v2 += d*d; }
  lnxB[w][tok] = v2;
  __syncthreads();
  float var2 = (lnxB[0][tok]+lnxB[1][tok]+lnxB[2][tok]+lnxB[3][tok]) * (1.f/64.f);
  float rstd2 = rsqrtf(var2 + 1e-5f);
  float us[16];
  #pragma unroll
  for (int j = 0; j < 16; j++) us[j] = (x2[j]-mu2)*rstd2*ln2g[c0+j] + ln2b[c0+j];

  #pragma unroll
  for (int j = 0; j < 16; j++) smA[(c0+j)*66 + tok] = us[j];
  #pragma unroll
  for (int it = 0; it < 4; it++){
    int idx = tid + 256*it;
    int tk = idx >> 4, c4 = (idx & 15) * 4;
    int gtok = token0 + tk;
    float4 xv = *(const float4*)(xg_ws + (size_t)gtok*C_ + c4);
    smH[(c4+0)*66+tk] = xv.x; smH[(c4+1)*66+tk] = xv.y; smH[(c4+2)*66+tk] = xv.z; smH[(c4+3)*66+tk] = xv.w;
  }
  __syncthreads();

  // gate
  float ga[16];
  #pragma unroll
  for (int j = 0; j < 16; j++) ga[j] = 0.f;
  for (int i = 0; i < C_; i++){
    float uv = smA[i*66 + tok];
    float xv = smH[i*66 + tok];
    const float* wsr = Wfs + i*C_ + c0;
    const float* wgr = Wfg + i*C_ + c0;
    #pragma unroll
    for (int j = 0; j < 16; j++) ga[j] += uv*wsr[j] + xv*wgr[j];
  }
  float res[16];
  #pragma unroll
  for (int j = 0; j < 16; j++){
    float a = ga[j] + bfs[c0+j] + bfg[c0+j];
    float gg = 1.f / (1.f + __expf(-a));
    float xgv = smH[(c0+j)*66 + tok];
    res[j] = gg*us[j] + (1.f-gg)*xgv;
  }
  __syncthreads();
  #pragma unroll
  for (int j = 0; j < 16; j++) smB[(c0+j)*66 + tok] = res[j];
  __syncthreads();
  #pragma unroll
  for (int it = 0; it < 4; it++){
    int idx = tid + 256*it;
    int tk = idx >> 4, c4 = (idx & 15) * 4;
    int gtok = token0 + tk;
    float4 v = make_float4(smB[(c4+0)*66+tk], smB[(c4+1)*66+tk],
                           smB[(c4+2)*66+tk], smB[(c4+3)*66+tk]);
    *(float4*)(out + (size_t)gtok*C_ + c4) = v;
  }
}

extern "C" void kernel_launch(void* const* d_in, const int* in_sizes, int n_in,
                              void* d_out, int out_size, void* d_ws, size_t ws_size,
                              hipStream_t stream)
{
  (void)in_sizes; (void)n_in; (void)out_size; (void)ws_size;
  const float* query = (const float*)d_in[0];
  const float* key   = (const float*)d_in[1];
  const float* value = (const float*)d_in[2];
  const float* DSm   = (const float*)d_in[4];
  const float* Wemb  = (const float*)d_in[5];
  const float* bemb  = (const float*)d_in[6];
  const float* Wq    = (const float*)d_in[7];
  const float* Wk    = (const float*)d_in[8];
  const float* Wv    = (const float*)d_in[9];
  const float* Wfc   = (const float*)d_in[10];
  const float* bfc   = (const float*)d_in[11];
  const float* ln1g  = (const float*)d_in[12];
  const float* ln1b  = (const float*)d_in[13];
  const float* ln2g  = (const float*)d_in[14];
  const float* ln2b  = (const float*)d_in[15];
  const float* Wff1  = (const float*)d_in[16];
  const float* bff1  = (const float*)d_in[17];
  const float* Wff2  = (const float*)d_in[18];
  const float* bff2  = (const float*)d_in[19];
  const float* g1W   = (const float*)d_in[20];
  const float* g1as  = (const float*)d_in[21];
  const float* g1ad  = (const float*)d_in[22];
  const float* g1b   = (const float*)d_in[23];
  const float* g2W   = (const float*)d_in[24];
  const float* g2as  = (const float*)d_in[25];
  const float* g2ad  = (const float*)d_in[26];
  const float* g2b   = (const float*)d_in[27];
  const float* jkW   = (const float*)d_in[28];
  const float* jkb   = (const float*)d_in[29];
  const float* Wfs   = (const float*)d_in[30];
  const float* bfs   = (const float*)d_in[31];
  const float* Wfg   = (const float*)d_in[32];
  const float* bfg   = (const float*)d_in[33];
  const int* ei      = (const int*)d_in[34];
  float* out = (float*)d_out;

  float* wf     = (float*)d_ws;
  float* dsb    = wf + DS_OFF;
  float* xg_ws  = wf + XG_OFF;
  u16*   hA     = (u16*)(wf + HA_OFF);
  u16*   hB     = (u16*)(wf + HB_OFF);
  float* o_ws   = wf + HA_OFF;             // aliases hA (dead before attention)
  float* hs_ws  = wf + HS_OFF;
  float* hd_ws  = wf + HD_OFF;
  int*   indptr = (int*)(wf + INT_OFF);
  int*   srcs   = indptr + 260;
  float* mS     = wf + MS_OFF;

  k_csr<<<dim3(1), dim3(256), 0, stream>>>(ei, indptr, srcs);
  k_ds<<<dim3(N_), dim3(C_), 0, stream>>>(DSm, Wemb, bemb, dsb);
  k_lin1<<<dim3(G_*4), dim3(256), 0, stream>>>(query, g1W, g1as, g1ad, hA, hs_ws, hd_ws);
  k_agg <<<dim3(G_*4), dim3(256), 0, stream>>>(hA, hs_ws, hd_ws, indptr, srcs, g1b, hB, 0);
  k_lin2<<<dim3(G_*4), dim3(256), 0, stream>>>(hB, g2W, g2as, g2ad, hA, hs_ws, hd_ws);
  k_agg <<<dim3(G_*4), dim3(256), 0, stream>>>(hA, hs_ws, hd_ws, indptr, srcs, g2b, hB, 1);
  k_jk  <<<dim3(G_*4), dim3(256), 0, stream>>>(hB, jkW, jkb, xg_ws);
  k_stat<<<dim3(B_*T_*H_), dim3(256), 0, stream>>>(query, key, Wq, Wk, dsb, mS);
  k_av  <<<dim3(B_*T_*H_), dim3(256), 0, stream>>>(query, key, value, Wq, Wk, Wv, dsb, mS, o_ws);
  k_final<<<dim3(TOK_/64), dim3(256), 0, stream>>>(query, dsb, o_ws, xg_ws,
      Wfc, bfc, ln1g, ln1b, ln2g, ln2b,
      Wff1, bff1, Wff2, bff2,
      Wfs, bfs, Wfg, bfg, out);
}

// Round 8
// 326.296 us; speedup vs baseline: 1.3332x; 1.2594x over previous
//
#include <hip/hip_runtime.h>

typedef unsigned short u16;
typedef unsigned int u32;

#define B_ 4
#define N_ 256
#define T_ 36
#define C_ 64
#define H_ 4
#define D_ 16
#define CH_ 128
#define E_ 4096
#define G_ (B_*T_)
#define TOK_ (B_*N_*T_)

// workspace layout (float offsets)
#define DS_OFF  0
#define XG_OFF  (DS_OFF + N_*C_)
#define HA_OFF  (XG_OFF + TOK_*C_)          // bf16 h buffer A (conv outs); aliased by o_ws later
#define HB_OFF  (HA_OFF + G_*N_*CH_/2)      // bf16 buffer B (h1)
#define HS_OFF  (HB_OFF + G_*N_*CH_/2)
#define HD_OFF  (HS_OFF + G_*N_)
#define INT_OFF (HD_OFF + G_*N_)
#define MS_OFF  (INT_OFF + 4608)            // (m, 1/S) pairs: 576 * 512 floats

__device__ __forceinline__ float bf2f(u16 u){
  u32 x = ((u32)u) << 16;
  return __builtin_bit_cast(float, x);
}
__device__ __forceinline__ u16 f2bf(float f){
  u32 x = __builtin_bit_cast(u32, f);
  x += 0x7fffu + ((x >> 16) & 1u);
  return (u16)(x >> 16);
}
__device__ __forceinline__ void unpack8(uint4 u, float* f){
  f[0]=bf2f((u16)(u.x & 0xffffu)); f[1]=bf2f((u16)(u.x >> 16));
  f[2]=bf2f((u16)(u.y & 0xffffu)); f[3]=bf2f((u16)(u.y >> 16));
  f[4]=bf2f((u16)(u.z & 0xffffu)); f[5]=bf2f((u16)(u.z >> 16));
  f[6]=bf2f((u16)(u.w & 0xffffu)); f[7]=bf2f((u16)(u.w >> 16));
}
__device__ __forceinline__ uint4 pack8f(const float* f){
  uint4 u;
  u.x = (u32)f2bf(f[0]) | ((u32)f2bf(f[1]) << 16);
  u.y = (u32)f2bf(f[2]) | ((u32)f2bf(f[3]) << 16);
  u.z = (u32)f2bf(f[4]) | ((u32)f2bf(f[5]) << 16);
  u.w = (u32)f2bf(f[6]) | ((u32)f2bf(f[7]) << 16);
  return u;
}
__device__ __forceinline__ int rfl(int v){ return __builtin_amdgcn_readfirstlane(v); }

#define SP_ 20   // f32 attn row pitch (80B, 16B-aligned)

// ---------------- fused pre: lin1 (576) + ds (64) + csr (1) ----------------
__global__ __launch_bounds__(256)
void k_pre(const float* __restrict__ query, const float* __restrict__ W1,
           const float* __restrict__ as1, const float* __restrict__ ad1,
           u16* __restrict__ h, float* __restrict__ hs_ws, float* __restrict__ hd_ws,
           const float* __restrict__ DSm, const float* __restrict__ Wemb,
           const float* __restrict__ bemb, float* __restrict__ dsb,
           const int* __restrict__ ei, int* __restrict__ indptr, int* __restrict__ srcs)
{
  __shared__ union UP {
    struct { float xs[64][65]; float red[2][4][64]; } lin;
    struct { int srcL[E_]; int dstL[E_]; int tmp[E_]; int cnt[N_]; int base[N_+1]; } c;
  } S;
  const int bid = blockIdx.x;
  const int tid = threadIdx.x;

  if (bid < 576){
    // ---- GAT conv1 linear: h = bf16(x @ W1), fused hs/hd ----
    const int g = bid >> 2, n0 = (bid & 3) * 64;
    const int b = g / T_, t = g % T_;
    {
      const size_t gb = (((size_t)b*N_ + n0)*T_ + t)*C_;
      #pragma unroll
      for (int it = 0; it < 4; it++){
        int idx = tid + 256*it;
        int row = idx >> 4, c4 = (idx & 15) * 4;
        float4 v = *(const float4*)(query + gb + (size_t)row*(T_*C_) + c4);
        S.lin.xs[row][c4+0] = v.x; S.lin.xs[row][c4+1] = v.y;
        S.lin.xs[row][c4+2] = v.z; S.lin.xs[row][c4+3] = v.w;
      }
    }
    __syncthreads();

    const int r = tid & 63;
    const int cb = rfl(tid >> 6);
    const int ch0 = cb * 32;

    float acc[32];
    #pragma unroll
    for (int j = 0; j < 32; j++) acc[j] = 0.f;
    for (int k = 0; k < 64; k++){
      float xv = S.lin.xs[r][k];
      const float* wrow = W1 + k*CH_ + ch0;   // wave-uniform -> scalar loads
      #pragma unroll
      for (int j = 0; j < 32; j++) acc[j] += xv * wrow[j];
    }
    float hs = 0.f, hd = 0.f;
    #pragma unroll
    for (int j = 0; j < 32; j++){ hs += acc[j]*as1[ch0+j]; hd += acc[j]*ad1[ch0+j]; }
    S.lin.red[0][cb][r] = hs; S.lin.red[1][cb][r] = hd;

    u16* hp = h + ((size_t)(g*N_ + n0 + r))*CH_ + ch0;
    #pragma unroll
    for (int j8 = 0; j8 < 32; j8 += 8)
      *(uint4*)(hp + j8) = pack8f(&acc[j8]);

    __syncthreads();
    if (tid < 64){
      float a = S.lin.red[0][0][tid]+S.lin.red[0][1][tid]+S.lin.red[0][2][tid]+S.lin.red[0][3][tid];
      float d = S.lin.red[1][0][tid]+S.lin.red[1][1][tid]+S.lin.red[1][2][tid]+S.lin.red[1][3][tid];
      hs_ws[g*N_ + n0 + tid] = a;
      hd_ws[g*N_ + n0 + tid] = d;
    }
  } else if (bid < 640){
    // ---- ds = D_S @ W_emb + b_emb ; 4 rows per block ----
    const int n = (bid - 576) * 4 + (tid >> 6);   // wave-uniform
    const int c = tid & 63;
    float acc = bemb[c];
    for (int m = 0; m < N_; m++) acc += DSm[n*N_ + m] * Wemb[m*C_ + c];
    dsb[n*C_ + c] = acc;
  } else {
    // ---- deterministic CSR ----
    for (int e = tid; e < E_; e += 256){ S.c.srcL[e] = ei[e]; S.c.dstL[e] = ei[E_ + e]; }
    S.c.cnt[tid] = 0;
    __syncthreads();
    for (int e = tid; e < E_; e += 256) atomicAdd(&S.c.cnt[S.c.dstL[e]], 1);
    __syncthreads();
    if (tid == 0){
      int run = 0;
      for (int i = 0; i < N_; i++){ S.c.base[i] = run; run += S.c.cnt[i]; }
      S.c.base[N_] = run;
    }
    __syncthreads();
    S.c.cnt[tid] = 0;
    __syncthreads();
    for (int e = tid; e < E_; e += 256){
      int d = S.c.dstL[e];
      int p = atomicAdd(&S.c.cnt[d], 1);
      S.c.tmp[S.c.base[d] + p] = e;
    }
    __syncthreads();
    {
      const int p0 = S.c.base[tid], p1 = S.c.base[tid] + S.c.cnt[tid];
      for (int i = p0 + 1; i < p1; i++){      // insertion sort by edge id -> deterministic
        int v = S.c.tmp[i]; int j = i - 1;
        while (j >= p0 && S.c.tmp[j] > v){ S.c.tmp[j+1] = S.c.tmp[j]; j--; }
        S.c.tmp[j+1] = v;
      }
      for (int j = p0; j < p1; j++) srcs[j] = S.c.srcL[S.c.tmp[j]];
    }
    indptr[tid] = S.c.base[tid];
    if (tid == 0) indptr[N_] = S.c.base[N_];
  }
}

// ---------------- agg1: softmax + gather, h1 = relu(agg + b1) -> hB ----------------
__global__ __launch_bounds__(256)
void k_agg1(const u16* __restrict__ hin, const float* __restrict__ hs_ws, const float* __restrict__ hd_ws,
            const int* __restrict__ indptr, const int* __restrict__ srcs,
            const float* __restrict__ bias, u16* __restrict__ hout)
{
  __shared__ int   srcs_l[E_];
  __shared__ float alpha_l[E_];
  __shared__ float hs_l[N_];
  const int bid = blockIdx.x;
  const int g = bid >> 2, n0 = (bid & 3) * 64;
  const int tid = threadIdx.x;

  const int p00 = indptr[n0];
  const int pend = indptr[n0 + 64];
  const int cntE = pend - p00;
  for (int i = tid; i < cntE; i += 256) srcs_l[i] = srcs[p00 + i];
  hs_l[tid] = hs_ws[g*N_ + tid];
  __syncthreads();

  if (tid < 64){
    const int dst = n0 + tid;
    const int p0 = indptr[dst] - p00, p1 = indptr[dst+1] - p00;
    const float hdn = hd_ws[g*N_ + dst];
    for (int j = p0; j < p1; j++){
      float e = hs_l[srcs_l[j]] + hdn;
      alpha_l[j] = e > 0.f ? e : 0.2f * e;
    }
    float m = -1e30f;
    for (int j = p0; j < p1; j++) m = fmaxf(m, alpha_l[j]);
    float s = 0.f;
    for (int j = p0; j < p1; j++){
      float w = __expf(alpha_l[j] - m);
      alpha_l[j] = w; s += w;
    }
    float inv = 1.f / (s + 1e-16f);
    for (int j = p0; j < p1; j++) alpha_l[j] *= inv;
  }
  __syncthreads();

  const int r = tid & 63;
  const int cb = rfl(tid >> 6);
  const int ch0 = cb * 32;
  const int dst = n0 + r;
  const int p0 = indptr[dst] - p00, p1 = indptr[dst+1] - p00;

  float acc[32];
  #pragma unroll
  for (int j = 0; j < 32; j++) acc[j] = 0.f;
  for (int j = p0; j < p1; j++){
    float a = alpha_l[j];
    int s = srcs_l[j];
    const uint4* hp = (const uint4*)(hin + ((size_t)(g*N_ + s))*CH_ + ch0);
    #pragma unroll
    for (int q = 0; q < 4; q++){
      float hv[8]; unpack8(hp[q], hv);
      #pragma unroll
      for (int i = 0; i < 8; i++) acc[q*8+i] += a * hv[i];
    }
  }
  float o[32];
  #pragma unroll
  for (int j = 0; j < 32; j++){
    float v = acc[j] + bias[ch0+j];
    o[j] = v > 0.f ? v : 0.f;
  }
  u16* op = hout + ((size_t)(g*N_ + dst))*CH_ + ch0;
  #pragma unroll
  for (int j8 = 0; j8 < 32; j8 += 8)
    *(uint4*)(op + j8) = pack8f(&o[j8]);
}

// ---------------- lin2: h2 = bf16(h1 @ W2), fused hs2/hd2 ----------------
__global__ __launch_bounds__(256)
void k_lin2(const u16* __restrict__ h1, const float* __restrict__ W2,
            const float* __restrict__ as2, const float* __restrict__ ad2,
            u16* __restrict__ h2, float* __restrict__ hs_ws, float* __restrict__ hd_ws)
{
  __shared__ float xs[64][129];
  __shared__ float red[2][4][64];
  const int bid = blockIdx.x;
  const int g = bid >> 2, n0 = (bid & 3) * 64;
  const int tid = threadIdx.x;

  {
    #pragma unroll
    for (int it = 0; it < 4; it++){
      int idx = tid + 256*it;
      int row = idx >> 4, c8 = (idx & 15) * 8;
      uint4 u = *(const uint4*)(h1 + ((size_t)(g*N_ + n0 + row))*CH_ + c8);
      float v[8]; unpack8(u, v);
      #pragma unroll
      for (int i = 0; i < 8; i++) xs[row][c8+i] = v[i];
    }
  }
  __syncthreads();

  const int r = tid & 63;
  const int cb = rfl(tid >> 6);
  const int ch0 = cb * 32;

  float acc[32];
  #pragma unroll
  for (int j = 0; j < 32; j++) acc[j] = 0.f;
  for (int k = 0; k < 128; k++){
    float xv = xs[r][k];
    const float* wrow = W2 + k*CH_ + ch0;
    #pragma unroll
    for (int j = 0; j < 32; j++) acc[j] += xv * wrow[j];
  }
  float hs = 0.f, hd = 0.f;
  #pragma unroll
  for (int j = 0; j < 32; j++){ hs += acc[j]*as2[ch0+j]; hd += acc[j]*ad2[ch0+j]; }
  red[0][cb][r] = hs; red[1][cb][r] = hd;

  u16* hp = h2 + ((size_t)(g*N_ + n0 + r))*CH_ + ch0;
  #pragma unroll
  for (int j8 = 0; j8 < 32; j8 += 8)
    *(uint4*)(hp + j8) = pack8f(&acc[j8]);

  __syncthreads();
  if (tid < 64){
    float a = red[0][0][tid]+red[0][1][tid]+red[0][2][tid]+red[0][3][tid];
    float d = red[1][0][tid]+red[1][1][tid]+red[1][2][tid]+red[1][3][tid];
    hs_ws[g*N_ + n0 + tid] = a;
    hd_ws[g*N_ + n0 + tid] = d;
  }
}

// ---------------- fused: agg2 + jk-max + jk-linear (blocks 0..575) ; attn stats (576..1151) ----------------
__global__ __launch_bounds__(256)
void k_aggjk(const u16* __restrict__ h2, const float* __restrict__ hs_ws, const float* __restrict__ hd_ws,
             const int* __restrict__ indptr, const int* __restrict__ srcs,
             const float* __restrict__ b2, const u16* __restrict__ h1,
             const float* __restrict__ jkW, const float* __restrict__ jkb, float* __restrict__ xg,
             const float* __restrict__ query, const float* __restrict__ key,
             const float* __restrict__ Wq, const float* __restrict__ Wk,
             const float* __restrict__ dsb, float* __restrict__ mS)
{
  __shared__ union UJ {
    struct { int srcs_l[E_]; float alpha_l[E_]; float hs_l[N_]; } a;
    struct { float xs[64][129]; } l;
    struct { float qs[N_][SP_]; float wq[16][16]; float wk[16][16]; } s;
  } U;
  const int bid = blockIdx.x;
  const int tid = threadIdx.x;

  if (bid < 576){
    const int g = bid >> 2, n0 = (bid & 3) * 64;
    const int b = g / T_, t = g % T_;

    // ---- agg2 phase (output stays in regs) ----
    const int p00 = indptr[n0];
    const int pend = indptr[n0 + 64];
    const int cntE = pend - p00;
    for (int i = tid; i < cntE; i += 256) U.a.srcs_l[i] = srcs[p00 + i];
    U.a.hs_l[tid] = hs_ws[g*N_ + tid];
    __syncthreads();

    if (tid < 64){
      const int dst = n0 + tid;
      const int p0 = indptr[dst] - p00, p1 = indptr[dst+1] - p00;
      const float hdn = hd_ws[g*N_ + dst];
      for (int j = p0; j < p1; j++){
        float e = U.a.hs_l[U.a.srcs_l[j]] + hdn;
        U.a.alpha_l[j] = e > 0.f ? e : 0.2f * e;
      }
      float m = -1e30f;
      for (int j = p0; j < p1; j++) m = fmaxf(m, U.a.alpha_l[j]);
      float s = 0.f;
      for (int j = p0; j < p1; j++){
        float w = __expf(U.a.alpha_l[j] - m);
        U.a.alpha_l[j] = w; s += w;
      }
      float inv = 1.f / (s + 1e-16f);
      for (int j = p0; j < p1; j++) U.a.alpha_l[j] *= inv;
    }
    __syncthreads();

    const int r = tid & 63;
    const int cb = rfl(tid >> 6);
    const int ch0 = cb * 32;
    const int dst = n0 + r;
    const int p0 = indptr[dst] - p00, p1 = indptr[dst+1] - p00;

    float acc[32];
    #pragma unroll
    for (int j = 0; j < 32; j++) acc[j] = 0.f;
    for (int j = p0; j < p1; j++){
      float a = U.a.alpha_l[j];
      int s = U.a.srcs_l[j];
      const uint4* hp = (const uint4*)(h2 + ((size_t)(g*N_ + s))*CH_ + ch0);
      #pragma unroll
      for (int q = 0; q < 4; q++){
        float hv[8]; unpack8(hp[q], hv);
        #pragma unroll
        for (int i = 0; i < 8; i++) acc[q*8+i] += a * hv[i];
      }
    }
    float o[32];
    {
      const uint4* h1p = (const uint4*)(h1 + ((size_t)(g*N_ + dst))*CH_ + ch0);
      #pragma unroll
      for (int j8 = 0; j8 < 32; j8 += 8){
        float h1v[8]; unpack8(h1p[j8>>3], h1v);
        #pragma unroll
        for (int i = 0; i < 8; i++){
          float v = acc[j8+i] + b2[ch0+j8+i];
          v = v > 0.f ? v : 0.f;
          o[j8+i] = fmaxf(h1v[i], v);
        }
      }
    }
    __syncthreads();   // all agg reads of U.a done

    // ---- transition: regs -> xs (f32) ----
    #pragma unroll
    for (int j = 0; j < 32; j++) U.l.xs[r][ch0+j] = o[j];
    __syncthreads();

    // ---- jk linear: xg(time-reversed) = xs @ jkW + jkb ----
    const int o0 = cb * 16;
    float acc2[16];
    #pragma unroll
    for (int j = 0; j < 16; j++) acc2[j] = 0.f;
    for (int k = 0; k < 128; k++){
      float xv = U.l.xs[r][k];
      const float* wrow = jkW + k*C_ + o0;
      #pragma unroll
      for (int j = 0; j < 16; j++) acc2[j] += xv * wrow[j];
    }
    float* op = xg + ((((size_t)b*N_ + n0 + r)*T_) + (T_-1-t))*C_ + o0;
    #pragma unroll
    for (int j4 = 0; j4 < 16; j4 += 4){
      float4 v = make_float4(acc2[j4]+jkb[o0+j4], acc2[j4+1]+jkb[o0+j4+1],
                             acc2[j4+2]+jkb[o0+j4+2], acc2[j4+3]+jkb[o0+j4+3]);
      *(float4*)(op + j4) = v;
    }
  } else {
    // ---- attention stats: per (b,t,h), thread = column k; (m, 1/S) over q axis ----
    const int sb = bid - 576;
    const int b = sb / (T_*H_);
    const int rem = sb % (T_*H_);
    const int t = rem / H_;
    const int h = rem % H_;
    const int n = tid;

    U.s.wq[n>>4][n&15] = Wq[n];
    U.s.wk[n>>4][n&15] = Wk[n];

    const size_t base = ((((size_t)b*N_ + n)*T_) + t)*C_ + h*D_;
    const float* dsp = dsb + n*C_ + h*D_;

    float x[16];
    #pragma unroll
    for (int j4 = 0; j4 < 16; j4 += 4){
      float4 a = *(const float4*)(query + base + j4);
      float4 d = *(const float4*)(dsp + j4);
      x[j4]=a.x+d.x; x[j4+1]=a.y+d.y; x[j4+2]=a.z+d.z; x[j4+3]=a.w+d.w;
    }
    __syncthreads();   // weights staged
    #pragma unroll
    for (int j = 0; j < 16; j++){
      float a = 0.f;
      #pragma unroll
      for (int i = 0; i < 16; i++) a += x[i]*U.s.wq[i][j];
      U.s.qs[n][j] = a;
    }
    float khr[16];
    #pragma unroll
    for (int j4 = 0; j4 < 16; j4 += 4){
      float4 a = *(const float4*)(key + base + j4);
      float4 d = *(const float4*)(dsp + j4);
      x[j4]=a.x+d.x; x[j4+1]=a.y+d.y; x[j4+2]=a.z+d.z; x[j4+3]=a.w+d.w;
    }
    #pragma unroll
    for (int j = 0; j < 16; j++){
      float a = 0.f;
      #pragma unroll
      for (int i = 0; i < 16; i++) a += x[i]*U.s.wk[i][j];
      khr[j] = a;
    }
    __syncthreads();   // qs complete

    float m[4], s[4];
    #pragma unroll
    for (int c = 0; c < 4; c++){ m[c] = -1e30f; s[c] = 0.f; }
    for (int qq = 0; qq < 64; qq++){
      #pragma unroll
      for (int c = 0; c < 4; c++){
        const float* qrow = &U.s.qs[qq + 64*c][0];
        float4 a0 = *(const float4*)(qrow);
        float4 a1 = *(const float4*)(qrow+4);
        float4 a2 = *(const float4*)(qrow+8);
        float4 a3 = *(const float4*)(qrow+12);
        float d = a0.x*khr[0]+a0.y*khr[1]+a0.z*khr[2]+a0.w*khr[3]
                + a1.x*khr[4]+a1.y*khr[5]+a1.z*khr[6]+a1.w*khr[7]
                + a2.x*khr[8]+a2.y*khr[9]+a2.z*khr[10]+a2.w*khr[11]
                + a3.x*khr[12]+a3.y*khr[13]+a3.z*khr[14]+a3.w*khr[15];
        d *= 0.125f;
        float mn = fmaxf(m[c], d);
        s[c] = s[c]*__expf(m[c]-mn) + __expf(d-mn);
        m[c] = mn;
      }
    }
    float M = fmaxf(fmaxf(m[0],m[1]), fmaxf(m[2],m[3]));
    float S = s[0]*__expf(m[0]-M) + s[1]*__expf(m[1]-M)
            + s[2]*__expf(m[2]-M) + s[3]*__expf(m[3]-M);
    mS[(size_t)sb*512 + n*2]     = M;
    mS[(size_t)sb*512 + n*2 + 1] = 1.f / S;
  }
}

// ---------------- attention AV: per (b,t,h), thread = row q; stats precomputed ----------------
__global__ __launch_bounds__(256)
void k_av(const float* __restrict__ query, const float* __restrict__ key, const float* __restrict__ value,
          const float* __restrict__ Wq, const float* __restrict__ Wk, const float* __restrict__ Wv,
          const float* __restrict__ dsb, const float* __restrict__ mS, float* __restrict__ o_ws)
{
  __shared__ float ks[N_][SP_];
  __shared__ float vs[N_][SP_];
  __shared__ float2 msl[N_];
  __shared__ float wq[16][16], wk[16][16], wv[16][16];

  const int bx = blockIdx.x;
  const int b = bx / (T_*H_);
  const int rem = bx % (T_*H_);
  const int t = rem / H_;
  const int h = rem % H_;
  const int n = threadIdx.x;

  wq[n>>4][n&15] = Wq[n];
  wk[n>>4][n&15] = Wk[n];
  wv[n>>4][n&15] = Wv[n];
  msl[n] = *(const float2*)(mS + (size_t)bx*512 + n*2);

  const size_t base = ((((size_t)b*N_ + n)*T_) + t)*C_ + h*D_;
  const float* dsp = dsb + n*C_ + h*D_;

  float ds16[16];
  #pragma unroll
  for (int j4 = 0; j4 < 16; j4 += 4){
    float4 d = *(const float4*)(dsp + j4);
    ds16[j4]=d.x; ds16[j4+1]=d.y; ds16[j4+2]=d.z; ds16[j4+3]=d.w;
  }
  __syncthreads();   // weights staged

  float x[16];
  #pragma unroll
  for (int j4 = 0; j4 < 16; j4 += 4){
    float4 a = *(const float4*)(key + base + j4);
    x[j4]=a.x+ds16[j4]; x[j4+1]=a.y+ds16[j4+1]; x[j4+2]=a.z+ds16[j4+2]; x[j4+3]=a.w+ds16[j4+3];
  }
  #pragma unroll
  for (int j = 0; j < 16; j++){
    float a = 0.f;
    #pragma unroll
    for (int i = 0; i < 16; i++) a += x[i]*wk[i][j];
    ks[n][j] = a;
  }
  #pragma unroll
  for (int j4 = 0; j4 < 16; j4 += 4){
    float4 a = *(const float4*)(value + base + j4);
    x[j4]=a.x+ds16[j4]; x[j4+1]=a.y+ds16[j4+1]; x[j4+2]=a.z+ds16[j4+2]; x[j4+3]=a.w+ds16[j4+3];
  }
  #pragma unroll
  for (int j = 0; j < 16; j++){
    float a = 0.f;
    #pragma unroll
    for (int i = 0; i < 16; i++) a += x[i]*wv[i][j];
    vs[n][j] = a;
  }
  float qhr[16];
  #pragma unroll
  for (int j4 = 0; j4 < 16; j4 += 4){
    float4 a = *(const float4*)(query + base + j4);
    x[j4]=a.x+ds16[j4]; x[j4+1]=a.y+ds16[j4+1]; x[j4+2]=a.z+ds16[j4+2]; x[j4+3]=a.w+ds16[j4+3];
  }
  #pragma unroll
  for (int j = 0; j < 16; j++){
    float a = 0.f;
    #pragma unroll
    for (int i = 0; i < 16; i++) a += x[i]*wq[i][j];
    qhr[j] = a;
  }
  __syncthreads();   // ks/vs/msl complete

  float o0[16], o1[16];
  #pragma unroll
  for (int j = 0; j < 16; j++){ o0[j] = 0.f; o1[j] = 0.f; }
  for (int k = 0; k < N_; k += 2){
    {
      const float* krow = &ks[k][0];
      float4 a0 = *(const float4*)(krow);
      float4 a1 = *(const float4*)(krow+4);
      float4 a2 = *(const float4*)(krow+8);
      float4 a3 = *(const float4*)(krow+12);
      float d = a0.x*qhr[0]+a0.y*qhr[1]+a0.z*qhr[2]+a0.w*qhr[3]
              + a1.x*qhr[4]+a1.y*qhr[5]+a1.z*qhr[6]+a1.w*qhr[7]
              + a2.x*qhr[8]+a2.y*qhr[9]+a2.z*qhr[10]+a2.w*qhr[11]
              + a3.x*qhr[12]+a3.y*qhr[13]+a3.z*qhr[14]+a3.w*qhr[15];
      float2 ms0 = msl[k];
      float p = __expf(d*0.125f - ms0.x) * ms0.y;
      const float* vrow = &vs[k][0];
      float4 v0 = *(const float4*)(vrow);
      float4 v1 = *(const float4*)(vrow+4);
      float4 v2 = *(const float4*)(vrow+8);
      float4 v3 = *(const float4*)(vrow+12);
      o0[0]+=p*v0.x; o0[1]+=p*v0.y; o0[2]+=p*v0.z; o0[3]+=p*v0.w;
      o0[4]+=p*v1.x; o0[5]+=p*v1.y; o0[6]+=p*v1.z; o0[7]+=p*v1.w;
      o0[8]+=p*v2.x; o0[9]+=p*v2.y; o0[10]+=p*v2.z; o0[11]+=p*v2.w;
      o0[12]+=p*v3.x; o0[13]+=p*v3.y; o0[14]+=p*v3.z; o0[15]+=p*v3.w;
    }
    {
      const float* krow = &ks[k+1][0];
      float4 a0 = *(const float4*)(krow);
      float4 a1 = *(const float4*)(krow+4);
      float4 a2 = *(const float4*)(krow+8);
      float4 a3 = *(const float4*)(krow+12);
      float d = a0.x*qhr[0]+a0.y*qhr[1]+a0.z*qhr[2]+a0.w*qhr[3]
              + a1.x*qhr[4]+a1.y*qhr[5]+a1.z*qhr[6]+a1.w*qhr[7]
              + a2.x*qhr[8]+a2.y*qhr[9]+a2.z*qhr[10]+a2.w*qhr[11]
              + a3.x*qhr[12]+a3.y*qhr[13]+a3.z*qhr[14]+a3.w*qhr[15];
      float2 ms1 = msl[k+1];
      float p = __expf(d*0.125f - ms1.x) * ms1.y;
      const float* vrow = &vs[k+1][0];
      float4 v0 = *(const float4*)(vrow);
      float4 v1 = *(const float4*)(vrow+4);
      float4 v2 = *(const float4*)(vrow+8);
      float4 v3 = *(const float4*)(vrow+12);
      o1[0]+=p*v0.x; o1[1]+=p*v0.y; o1[2]+=p*v0.z; o1[3]+=p*v0.w;
      o1[4]+=p*v1.x; o1[5]+=p*v1.y; o1[6]+=p*v1.z; o1[7]+=p*v1.w;
      o1[8]+=p*v2.x; o1[9]+=p*v2.y; o1[10]+=p*v2.z; o1[11]+=p*v2.w;
      o1[12]+=p*v3.x; o1[13]+=p*v3.y; o1[14]+=p*v3.z; o1[15]+=p*v3.w;
    }
  }
  float* op = o_ws + base;
  #pragma unroll
  for (int j4 = 0; j4 < 16; j4 += 4)
    *(float4*)(op + j4) = make_float4(o0[j4]+o1[j4], o0[j4+1]+o1[j4+1],
                                      o0[j4+2]+o1[j4+2], o0[j4+3]+o1[j4+3]);
}

// ---------------- fused epilogue v3: bf16 LDS staging (35.8 KB -> 4 blocks/CU) ----------------
__global__ __launch_bounds__(256)
void k_final(const float* __restrict__ query, const float* __restrict__ dsb,
             const float* __restrict__ o_ws, const float* __restrict__ xg_ws,
             const float* __restrict__ Wfc, const float* __restrict__ bfc,
             const float* __restrict__ ln1g, const float* __restrict__ ln1b,
             const float* __restrict__ ln2g, const float* __restrict__ ln2b,
             const float* __restrict__ Wff1, const float* __restrict__ bff1,
             const float* __restrict__ Wff2, const float* __restrict__ bff2,
             const float* __restrict__ Wfs, const float* __restrict__ bfs,
             const float* __restrict__ Wfg, const float* __restrict__ bfg,
             float* __restrict__ out)
{
  __shared__ u16 smA[64*66];                       // o_t -> us_t (bf16)
  __shared__ u16 smB[64*66];                       // qd_t -> ms_t (bf16)
  __shared__ union UH { u16 h[128*66]; float o[64*66]; } HH;  // hidden/xg (bf16) -> out_t (f32)
  __shared__ float lnxA[4][64];
  __shared__ float lnxB[4][64];

  const int tid = threadIdx.x;
  const int token0 = blockIdx.x * 64;
  const int w = rfl(tid >> 6);
  const int tok = tid & 63;
  const int c0 = w * 16;

  #pragma unroll
  for (int it = 0; it < 4; it++){
    int idx = tid + 256*it;
    int tk = idx >> 4, c4 = (idx & 15) * 4;
    int gtok = token0 + tk;
    int n = (gtok / T_) & (N_-1);
    float4 ov = *(const float4*)(o_ws + (size_t)gtok*C_ + c4);
    float4 qv = *(const float4*)(query + (size_t)gtok*C_ + c4);
    float4 dv = *(const float4*)(dsb + n*C_ + c4);
    smA[(c4+0)*66+tk] = f2bf(ov.x); smA[(c4+1)*66+tk] = f2bf(ov.y);
    smA[(c4+2)*66+tk] = f2bf(ov.z); smA[(c4+3)*66+tk] = f2bf(ov.w);
    smB[(c4+0)*66+tk] = f2bf(qv.x+dv.x); smB[(c4+1)*66+tk] = f2bf(qv.y+dv.y);
    smB[(c4+2)*66+tk] = f2bf(qv.z+dv.z); smB[(c4+3)*66+tk] = f2bf(qv.w+dv.w);
  }
  __syncthreads();

  // fc
  float x1[16];
  #pragma unroll
  for (int j = 0; j < 16; j++) x1[j] = 0.f;
  for (int i = 0; i < C_; i++){
    float ov = bf2f(smA[i*66 + tok]);
    const float* wrow = Wfc + i*C_ + c0;
    #pragma unroll
    for (int j = 0; j < 16; j++) x1[j] += ov * wrow[j];
  }
  #pragma unroll
  for (int j = 0; j < 16; j++) x1[j] += bfc[c0+j] + bf2f(smB[(c0+j)*66 + tok]);

  // LN1
  float s1 = 0.f;
  #pragma unroll
  for (int j = 0; j < 16; j++) s1 += x1[j];
  lnxA[w][tok] = s1;
  __syncthreads();
  float mu = (lnxA[0][tok]+lnxA[1][tok]+lnxA[2][tok]+lnxA[3][tok]) * (1.f/64.f);
  float v1 = 0.f;
  #pragma unroll
  for (int j = 0; j < 16; j++){ float d = x1[j]-mu; v1 += d*d; }
  lnxB[w][tok] = v1;
  __syncthreads();
  float var = (lnxB[0][tok]+lnxB[1][tok]+lnxB[2][tok]+lnxB[3][tok]) * (1.f/64.f);
  float rstd = rsqrtf(var + 1e-5f);
  float ms[16];
  #pragma unroll
  for (int j = 0; j < 16; j++) ms[j] = (x1[j]-mu)*rstd*ln1g[c0+j] + ln1b[c0+j];
  __syncthreads();
  #pragma unroll
  for (int j = 0; j < 16; j++) smB[(c0+j)*66 + tok] = f2bf(ms[j]);
  __syncthreads();

  // FFN
  float part[16];
  #pragma unroll
  for (int j = 0; j < 16; j++) part[j] = 0.f;
  #pragma unroll
  for (int ch = 0; ch < 2; ch++){
    float fch[32];
    #pragma unroll
    for (int kk = 0; kk < 32; kk++) fch[kk] = 0.f;
    const int kbase = w*64 + ch*32;
    for (int i = 0; i < C_; i++){
      float msv = bf2f(smB[i*66 + tok]);
      const float* wrow = Wff1 + i*(4*C_) + kbase;
      #pragma unroll
      for (int kk = 0; kk < 32; kk++) fch[kk] += msv * wrow[kk];
    }
    #pragma unroll
    for (int kk = 0; kk < 32; kk++){
      float v = fch[kk] + bff1[kbase+kk];
      fch[kk] = v > 0.f ? v : 0.f;
    }
    if (ch) __syncthreads();
    #pragma unroll
    for (int kk = 0; kk < 32; kk++) HH.h[(w*32+kk)*66 + tok] = f2bf(fch[kk]);
    __syncthreads();
    #pragma unroll
    for (int wq = 0; wq < 4; wq++){
      #pragma unroll 8
      for (int kk = 0; kk < 32; kk++){
        int k = wq*64 + ch*32 + kk;
        float hv = bf2f(HH.h[(wq*32+kk)*66 + tok]);
        const float* wrow = Wff2 + k*C_ + c0;
        #pragma unroll
        for (int j = 0; j < 16; j++) part[j] += hv * wrow[j];
      }
    }
  }
  float x2[16];
  #pragma unroll
  for (int j = 0; j < 16; j++) x2[j] = part[j] + bff2[c0+j] + ms[j];

  // LN2
  float s2 = 0.f;
  #pragma unroll
  for (int j = 0; j < 16; j++) s2 += x2[j];
  __syncthreads();
  lnxA[w][tok] = s2;
  __syncthreads();
  float mu2 = (lnxA[0][tok]+lnxA[1][tok]+lnxA[2][tok]+lnxA[3][tok]) * (1.f/64.f);
  float v2 = 0.f;
  #pragma unroll
  for (int j = 0; j < 16; j++){ float d = x2[j]-mu2; v2 += d*d; }
  lnxB[w][tok] = v2;
  __syncthreads();
  float var2 = (lnxB[0][tok]+lnxB[1][tok]+lnxB[2][tok]+lnxB[3][tok]) * (1.f/64.f);
  float rstd2 = rsqrtf(var2 + 1e-5f);
  float us[16];
  #pragma unroll
  for (int j = 0; j < 16; j++) us[j] = (x2[j]-mu2)*rstd2*ln2g[c0+j] + ln2b[c0+j];

  // us -> smA ; xg -> HH.h rows 0..63 (hidden dead)
  #pragma unroll
  for (int j = 0; j < 16; j++) smA[(c0+j)*66 + tok] = f2bf(us[j]);
  #pragma unroll
  for (int it = 0; it < 4; it++){
    int idx = tid + 256*it;
    int tk = idx >> 4, c4 = (idx & 15) * 4;
    int gtok = token0 + tk;
    float4 xv = *(const float4*)(xg_ws + (size_t)gtok*C_ + c4);
    HH.h[(c4+0)*66+tk] = f2bf(xv.x); HH.h[(c4+1)*66+tk] = f2bf(xv.y);
    HH.h[(c4+2)*66+tk] = f2bf(xv.z); HH.h[(c4+3)*66+tk] = f2bf(xv.w);
  }
  __syncthreads();

  // gate
  float ga[16];
  #pragma unroll
  for (int j = 0; j < 16; j++) ga[j] = 0.f;
  for (int i = 0; i < C_; i++){
    float uv = bf2f(smA[i*66 + tok]);
    float xv = bf2f(HH.h[i*66 + tok]);
    const float* wsr = Wfs + i*C_ + c0;
    const float* wgr = Wfg + i*C_ + c0;
    #pragma unroll
    for (int j = 0; j < 16; j++) ga[j] += uv*wsr[j] + xv*wgr[j];
  }
  float res[16];
  #pragma unroll
  for (int j = 0; j < 16; j++){
    float a = ga[j] + bfs[c0+j] + bfg[c0+j];
    float gg = 1.f / (1.f + __expf(-a));
    float xgv = bf2f(HH.h[(c0+j)*66 + tok]);
    res[j] = gg*us[j] + (1.f-gg)*xgv;
  }
  __syncthreads();   // all xg reads done before f32 reuse of HH
  #pragma unroll
  for (int j = 0; j < 16; j++) HH.o[(c0+j)*66 + tok] = res[j];
  __syncthreads();
  #pragma unroll
  for (int it = 0; it < 4; it++){
    int idx = tid + 256*it;
    int tk = idx >> 4, c4 = (idx & 15) * 4;
    int gtok = token0 + tk;
    float4 v = make_float4(HH.o[(c4+0)*66+tk], HH.o[(c4+1)*66+tk],
                           HH.o[(c4+2)*66+tk], HH.o[(c4+3)*66+tk]);
    *(float4*)(out + (size_t)gtok*C_ + c4) = v;
  }
}

extern "C" void kernel_launch(void* const* d_in, const int* in_sizes, int n_in,
                              void* d_out, int out_size, void* d_ws, size_t ws_size,
                              hipStream_t stream)
{
  (void)in_sizes; (void)n_in; (void)out_size; (void)ws_size;
  const float* query = (const float*)d_in[0];
  const float* key   = (const float*)d_in[1];
  const float* value = (const float*)d_in[2];
  const float* DSm   = (const float*)d_in[4];
  const float* Wemb  = (const float*)d_in[5];
  const float* bemb  = (const float*)d_in[6];
  const float* Wq    = (const float*)d_in[7];
  const float* Wk    = (const float*)d_in[8];
  const float* Wv    = (const float*)d_in[9];
  const float* Wfc   = (const float*)d_in[10];
  const float* bfc   = (const float*)d_in[11];
  const float* ln1g  = (const float*)d_in[12];
  const float* ln1b  = (const float*)d_in[13];
  const float* ln2g  = (const float*)d_in[14];
  const float* ln2b  = (const float*)d_in[15];
  const float* Wff1  = (const float*)d_in[16];
  const float* bff1  = (const float*)d_in[17];
  const float* Wff2  = (const float*)d_in[18];
  const float* bff2  = (const float*)d_in[19];
  const float* g1W   = (const float*)d_in[20];
  const float* g1as  = (const float*)d_in[21];
  const float* g1ad  = (const float*)d_in[22];
  const float* g1b   = (const float*)d_in[23];
  const float* g2W   = (const float*)d_in[24];
  const float* g2as  = (const float*)d_in[25];
  const float* g2ad  = (const float*)d_in[26];
  const float* g2b   = (const float*)d_in[27];
  const float* jkW   = (const float*)d_in[28];
  const float* jkb   = (const float*)d_in[29];
  const float* Wfs   = (const float*)d_in[30];
  const float* bfs   = (const float*)d_in[31];
  const float* Wfg   = (const float*)d_in[32];
  const float* bfg   = (const float*)d_in[33];
  const int* ei      = (const int*)d_in[34];
  float* out = (float*)d_out;

  float* wf     = (float*)d_ws;
  float* dsb    = wf + DS_OFF;
  float* xg_ws  = wf + XG_OFF;
  u16*   hA     = (u16*)(wf + HA_OFF);
  u16*   hB     = (u16*)(wf + HB_OFF);
  float* o_ws   = wf + HA_OFF;             // aliases hA (dead before k_av)
  float* hs_ws  = wf + HS_OFF;
  float* hd_ws  = wf + HD_OFF;
  int*   indptr = (int*)(wf + INT_OFF);
  int*   srcs   = indptr + 260;
  float* mS     = wf + MS_OFF;

  k_pre  <<<dim3(641),  dim3(256), 0, stream>>>(query, g1W, g1as, g1ad, hA, hs_ws, hd_ws,
                                                DSm, Wemb, bemb, dsb, ei, indptr, srcs);
  k_agg1 <<<dim3(576),  dim3(256), 0, stream>>>(hA, hs_ws, hd_ws, indptr, srcs, g1b, hB);
  k_lin2 <<<dim3(576),  dim3(256), 0, stream>>>(hB, g2W, g2as, g2ad, hA, hs_ws, hd_ws);
  k_aggjk<<<dim3(1152), dim3(256), 0, stream>>>(hA, hs_ws, hd_ws, indptr, srcs, g2b, hB,
                                                jkW, jkb, xg_ws,
                                                query, key, Wq, Wk, dsb, mS);
  k_av   <<<dim3(576),  dim3(256), 0, stream>>>(query, key, value, Wq, Wk, Wv, dsb, mS, o_ws);
  k_final<<<dim3(576),  dim3(256), 0, stream>>>(query, dsb, o_ws, xg_ws,
      Wfc, bfc, ln1g, ln1b, ln2g, ln2b,
      Wff1, bff1, Wff2, bff2,
      Wfs, bfs, Wfg, bfg, out);
}

// Round 9
// 322.607 us; speedup vs baseline: 1.3484x; 1.0114x over previous
//
#include <hip/hip_runtime.h>

typedef unsigned short u16;
typedef unsigned int u32;

#define B_ 4
#define N_ 256
#define T_ 36
#define C_ 64
#define H_ 4
#define D_ 16
#define CH_ 128
#define E_ 4096
#define G_ (B_*T_)
#define TOK_ (B_*N_*T_)

// workspace layout (float offsets)
#define DS_OFF  0
#define XG_OFF  (DS_OFF + N_*C_)
#define HA_OFF  (XG_OFF + TOK_*C_)          // bf16 h buffer A (conv outs); aliased by o_ws later
#define HB_OFF  (HA_OFF + G_*N_*CH_/2)      // bf16 buffer B (h1)
#define HS_OFF  (HB_OFF + G_*N_*CH_/2)
#define HD_OFF  (HS_OFF + G_*N_)
#define INT_OFF (HD_OFF + G_*N_)
#define MS_OFF  (INT_OFF + 4608)            // (m, 1/S) pairs: 576 * 512 floats

__device__ __forceinline__ float bf2f(u16 u){
  u32 x = ((u32)u) << 16;
  return __builtin_bit_cast(float, x);
}
__device__ __forceinline__ u16 f2bf(float f){
  u32 x = __builtin_bit_cast(u32, f);
  x += 0x7fffu + ((x >> 16) & 1u);
  return (u16)(x >> 16);
}
__device__ __forceinline__ void unpack8(uint4 u, float* f){
  f[0]=bf2f((u16)(u.x & 0xffffu)); f[1]=bf2f((u16)(u.x >> 16));
  f[2]=bf2f((u16)(u.y & 0xffffu)); f[3]=bf2f((u16)(u.y >> 16));
  f[4]=bf2f((u16)(u.z & 0xffffu)); f[5]=bf2f((u16)(u.z >> 16));
  f[6]=bf2f((u16)(u.w & 0xffffu)); f[7]=bf2f((u16)(u.w >> 16));
}
__device__ __forceinline__ uint4 pack8f(const float* f){
  uint4 u;
  u.x = (u32)f2bf(f[0]) | ((u32)f2bf(f[1]) << 16);
  u.y = (u32)f2bf(f[2]) | ((u32)f2bf(f[3]) << 16);
  u.z = (u32)f2bf(f[4]) | ((u32)f2bf(f[5]) << 16);
  u.w = (u32)f2bf(f[6]) | ((u32)f2bf(f[7]) << 16);
  return u;
}
__device__ __forceinline__ int rfl(int v){ return __builtin_amdgcn_readfirstlane(v); }

// XCD swizzle: all 4 quarter-blocks of graph g share bid%8 == g%8 (same XCD L2)
// bid = (g%8) + 8*((g/8)*4 + q)   (bijective on [0,576))
__device__ __forceinline__ void gq_from_bid(int bid, int& g, int& q){
  int xc = bid & 7, slot = bid >> 3;
  q = slot & 3;
  g = xc + ((slot >> 2) << 3);
}

#define SP_ 20   // f32 attn row pitch (80B, 16B-aligned)

// ---------------- fused pre: lin1 (576) + ds (64) + csr (1) ----------------
__global__ __launch_bounds__(256)
void k_pre(const float* __restrict__ query, const float* __restrict__ W1,
           const float* __restrict__ as1, const float* __restrict__ ad1,
           u16* __restrict__ h, float* __restrict__ hs_ws, float* __restrict__ hd_ws,
           const float* __restrict__ DSm, const float* __restrict__ Wemb,
           const float* __restrict__ bemb, float* __restrict__ dsb,
           const int* __restrict__ ei, int* __restrict__ indptr, int* __restrict__ srcs)
{
  __shared__ union UP {
    struct { float xs[64][65]; float red[2][4][64]; } lin;
    struct { int srcL[E_]; int dstL[E_]; int tmp[E_]; int cnt[N_]; int base[N_+1]; } c;
  } S;
  const int bid = blockIdx.x;
  const int tid = threadIdx.x;

  if (bid < 576){
    // ---- GAT conv1 linear: h = bf16(x @ W1), fused hs/hd ----
    int g, q; gq_from_bid(bid, g, q);
    const int n0 = q * 64;
    const int b = g / T_, t = g % T_;
    {
      const size_t gb = (((size_t)b*N_ + n0)*T_ + t)*C_;
      #pragma unroll
      for (int it = 0; it < 4; it++){
        int idx = tid + 256*it;
        int row = idx >> 4, c4 = (idx & 15) * 4;
        float4 v = *(const float4*)(query + gb + (size_t)row*(T_*C_) + c4);
        S.lin.xs[row][c4+0] = v.x; S.lin.xs[row][c4+1] = v.y;
        S.lin.xs[row][c4+2] = v.z; S.lin.xs[row][c4+3] = v.w;
      }
    }
    __syncthreads();

    const int r = tid & 63;
    const int cb = rfl(tid >> 6);
    const int ch0 = cb * 32;

    float acc[32];
    #pragma unroll
    for (int j = 0; j < 32; j++) acc[j] = 0.f;
    for (int k = 0; k < 64; k++){
      float xv = S.lin.xs[r][k];
      const float* wrow = W1 + k*CH_ + ch0;   // wave-uniform -> scalar loads
      #pragma unroll
      for (int j = 0; j < 32; j++) acc[j] += xv * wrow[j];
    }
    float hs = 0.f, hd = 0.f;
    #pragma unroll
    for (int j = 0; j < 32; j++){ hs += acc[j]*as1[ch0+j]; hd += acc[j]*ad1[ch0+j]; }
    S.lin.red[0][cb][r] = hs; S.lin.red[1][cb][r] = hd;

    u16* hp = h + ((size_t)(g*N_ + n0 + r))*CH_ + ch0;
    #pragma unroll
    for (int j8 = 0; j8 < 32; j8 += 8)
      *(uint4*)(hp + j8) = pack8f(&acc[j8]);

    __syncthreads();
    if (tid < 64){
      float a = S.lin.red[0][0][tid]+S.lin.red[0][1][tid]+S.lin.red[0][2][tid]+S.lin.red[0][3][tid];
      float d = S.lin.red[1][0][tid]+S.lin.red[1][1][tid]+S.lin.red[1][2][tid]+S.lin.red[1][3][tid];
      hs_ws[g*N_ + n0 + tid] = a;
      hd_ws[g*N_ + n0 + tid] = d;
    }
  } else if (bid < 640){
    // ---- ds = D_S @ W_emb + b_emb ; 4 rows per block ----
    const int n = (bid - 576) * 4 + (tid >> 6);   // wave-uniform
    const int c = tid & 63;
    float acc = bemb[c];
    for (int m = 0; m < N_; m++) acc += DSm[n*N_ + m] * Wemb[m*C_ + c];
    dsb[n*C_ + c] = acc;
  } else {
    // ---- deterministic CSR ----
    for (int e = tid; e < E_; e += 256){ S.c.srcL[e] = ei[e]; S.c.dstL[e] = ei[E_ + e]; }
    S.c.cnt[tid] = 0;
    __syncthreads();
    for (int e = tid; e < E_; e += 256) atomicAdd(&S.c.cnt[S.c.dstL[e]], 1);
    __syncthreads();
    if (tid == 0){
      int run = 0;
      for (int i = 0; i < N_; i++){ S.c.base[i] = run; run += S.c.cnt[i]; }
      S.c.base[N_] = run;
    }
    __syncthreads();
    S.c.cnt[tid] = 0;
    __syncthreads();
    for (int e = tid; e < E_; e += 256){
      int d = S.c.dstL[e];
      int p = atomicAdd(&S.c.cnt[d], 1);
      S.c.tmp[S.c.base[d] + p] = e;
    }
    __syncthreads();
    {
      const int p0 = S.c.base[tid], p1 = S.c.base[tid] + S.c.cnt[tid];
      for (int i = p0 + 1; i < p1; i++){      // insertion sort by edge id -> deterministic
        int v = S.c.tmp[i]; int j = i - 1;
        while (j >= p0 && S.c.tmp[j] > v){ S.c.tmp[j+1] = S.c.tmp[j]; j--; }
        S.c.tmp[j+1] = v;
      }
      for (int j = p0; j < p1; j++) srcs[j] = S.c.srcL[S.c.tmp[j]];
    }
    indptr[tid] = S.c.base[tid];
    if (tid == 0) indptr[N_] = S.c.base[N_];
  }
}

// ---------------- agg1: softmax + gather, h1 = relu(agg + b1) -> hB ----------------
__global__ __launch_bounds__(256)
void k_agg1(const u16* __restrict__ hin, const float* __restrict__ hs_ws, const float* __restrict__ hd_ws,
            const int* __restrict__ indptr, const int* __restrict__ srcs,
            const float* __restrict__ bias, u16* __restrict__ hout)
{
  __shared__ int   srcs_l[E_];
  __shared__ float alpha_l[E_];
  __shared__ float hs_l[N_];
  const int bid = blockIdx.x;
  int g, q; gq_from_bid(bid, g, q);
  const int n0 = q * 64;
  const int tid = threadIdx.x;

  const int p00 = indptr[n0];
  const int pend = indptr[n0 + 64];
  const int cntE = pend - p00;
  for (int i = tid; i < cntE; i += 256) srcs_l[i] = srcs[p00 + i];
  hs_l[tid] = hs_ws[g*N_ + tid];
  __syncthreads();

  if (tid < 64){
    const int dst = n0 + tid;
    const int p0 = indptr[dst] - p00, p1 = indptr[dst+1] - p00;
    const float hdn = hd_ws[g*N_ + dst];
    for (int j = p0; j < p1; j++){
      float e = hs_l[srcs_l[j]] + hdn;
      alpha_l[j] = e > 0.f ? e : 0.2f * e;
    }
    float m = -1e30f;
    for (int j = p0; j < p1; j++) m = fmaxf(m, alpha_l[j]);
    float s = 0.f;
    for (int j = p0; j < p1; j++){
      float w = __expf(alpha_l[j] - m);
      alpha_l[j] = w; s += w;
    }
    float inv = 1.f / (s + 1e-16f);
    for (int j = p0; j < p1; j++) alpha_l[j] *= inv;
  }
  __syncthreads();

  const int r = tid & 63;
  const int cb = rfl(tid >> 6);
  const int ch0 = cb * 32;
  const int dst = n0 + r;
  const int p0 = indptr[dst] - p00, p1 = indptr[dst+1] - p00;

  float acc[32];
  #pragma unroll
  for (int j = 0; j < 32; j++) acc[j] = 0.f;
  for (int j = p0; j < p1; j++){
    float a = alpha_l[j];
    int s = srcs_l[j];
    const uint4* hp = (const uint4*)(hin + ((size_t)(g*N_ + s))*CH_ + ch0);
    #pragma unroll
    for (int qq = 0; qq < 4; qq++){
      float hv[8]; unpack8(hp[qq], hv);
      #pragma unroll
      for (int i = 0; i < 8; i++) acc[qq*8+i] += a * hv[i];
    }
  }
  float o[32];
  #pragma unroll
  for (int j = 0; j < 32; j++){
    float v = acc[j] + bias[ch0+j];
    o[j] = v > 0.f ? v : 0.f;
  }
  u16* op = hout + ((size_t)(g*N_ + dst))*CH_ + ch0;
  #pragma unroll
  for (int j8 = 0; j8 < 32; j8 += 8)
    *(uint4*)(op + j8) = pack8f(&o[j8]);
}

// ---------------- lin2: h2 = bf16(h1 @ W2), fused hs2/hd2 ----------------
__global__ __launch_bounds__(256)
void k_lin2(const u16* __restrict__ h1, const float* __restrict__ W2,
            const float* __restrict__ as2, const float* __restrict__ ad2,
            u16* __restrict__ h2, float* __restrict__ hs_ws, float* __restrict__ hd_ws)
{
  __shared__ float xs[64][129];
  __shared__ float red[2][4][64];
  const int bid = blockIdx.x;
  int g, q; gq_from_bid(bid, g, q);
  const int n0 = q * 64;
  const int tid = threadIdx.x;

  {
    #pragma unroll
    for (int it = 0; it < 4; it++){
      int idx = tid + 256*it;
      int row = idx >> 4, c8 = (idx & 15) * 8;
      uint4 u = *(const uint4*)(h1 + ((size_t)(g*N_ + n0 + row))*CH_ + c8);
      float v[8]; unpack8(u, v);
      #pragma unroll
      for (int i = 0; i < 8; i++) xs[row][c8+i] = v[i];
    }
  }
  __syncthreads();

  const int r = tid & 63;
  const int cb = rfl(tid >> 6);
  const int ch0 = cb * 32;

  float acc[32];
  #pragma unroll
  for (int j = 0; j < 32; j++) acc[j] = 0.f;
  for (int k = 0; k < 128; k++){
    float xv = xs[r][k];
    const float* wrow = W2 + k*CH_ + ch0;
    #pragma unroll
    for (int j = 0; j < 32; j++) acc[j] += xv * wrow[j];
  }
  float hs = 0.f, hd = 0.f;
  #pragma unroll
  for (int j = 0; j < 32; j++){ hs += acc[j]*as2[ch0+j]; hd += acc[j]*ad2[ch0+j]; }
  red[0][cb][r] = hs; red[1][cb][r] = hd;

  u16* hp = h2 + ((size_t)(g*N_ + n0 + r))*CH_ + ch0;
  #pragma unroll
  for (int j8 = 0; j8 < 32; j8 += 8)
    *(uint4*)(hp + j8) = pack8f(&acc[j8]);

  __syncthreads();
  if (tid < 64){
    float a = red[0][0][tid]+red[0][1][tid]+red[0][2][tid]+red[0][3][tid];
    float d = red[1][0][tid]+red[1][1][tid]+red[1][2][tid]+red[1][3][tid];
    hs_ws[g*N_ + n0 + tid] = a;
    hd_ws[g*N_ + n0 + tid] = d;
  }
}

// ---------------- fused: agg2 + jk-max + jk-linear (blocks 0..575) ; attn stats (576..1151) ----------------
__global__ __launch_bounds__(256)
void k_aggjk(const u16* __restrict__ h2, const float* __restrict__ hs_ws, const float* __restrict__ hd_ws,
             const int* __restrict__ indptr, const int* __restrict__ srcs,
             const float* __restrict__ b2, const u16* __restrict__ h1,
             const float* __restrict__ jkW, const float* __restrict__ jkb, float* __restrict__ xg,
             const float* __restrict__ query, const float* __restrict__ key,
             const float* __restrict__ Wq, const float* __restrict__ Wk,
             const float* __restrict__ dsb, float* __restrict__ mS)
{
  __shared__ union UJ {
    struct { int srcs_l[E_]; float alpha_l[E_]; float hs_l[N_]; } a;
    struct { float xs[64][129]; } l;
    struct { float qs[N_][SP_]; float wq[16][16]; float wk[16][16]; } s;
  } U;
  const int bid = blockIdx.x;
  const int tid = threadIdx.x;

  if (bid < 576){
    int g, q; gq_from_bid(bid, g, q);
    const int n0 = q * 64;
    const int b = g / T_, t = g % T_;

    // ---- agg2 phase (output stays in regs) ----
    const int p00 = indptr[n0];
    const int pend = indptr[n0 + 64];
    const int cntE = pend - p00;
    for (int i = tid; i < cntE; i += 256) U.a.srcs_l[i] = srcs[p00 + i];
    U.a.hs_l[tid] = hs_ws[g*N_ + tid];
    __syncthreads();

    if (tid < 64){
      const int dst = n0 + tid;
      const int p0 = indptr[dst] - p00, p1 = indptr[dst+1] - p00;
      const float hdn = hd_ws[g*N_ + dst];
      for (int j = p0; j < p1; j++){
        float e = U.a.hs_l[U.a.srcs_l[j]] + hdn;
        U.a.alpha_l[j] = e > 0.f ? e : 0.2f * e;
      }
      float m = -1e30f;
      for (int j = p0; j < p1; j++) m = fmaxf(m, U.a.alpha_l[j]);
      float s = 0.f;
      for (int j = p0; j < p1; j++){
        float w = __expf(U.a.alpha_l[j] - m);
        U.a.alpha_l[j] = w; s += w;
      }
      float inv = 1.f / (s + 1e-16f);
      for (int j = p0; j < p1; j++) U.a.alpha_l[j] *= inv;
    }
    __syncthreads();

    const int r = tid & 63;
    const int cb = rfl(tid >> 6);
    const int ch0 = cb * 32;
    const int dst = n0 + r;
    const int p0 = indptr[dst] - p00, p1 = indptr[dst+1] - p00;

    float acc[32];
    #pragma unroll
    for (int j = 0; j < 32; j++) acc[j] = 0.f;
    for (int j = p0; j < p1; j++){
      float a = U.a.alpha_l[j];
      int s = U.a.srcs_l[j];
      const uint4* hp = (const uint4*)(h2 + ((size_t)(g*N_ + s))*CH_ + ch0);
      #pragma unroll
      for (int qq = 0; qq < 4; qq++){
        float hv[8]; unpack8(hp[qq], hv);
        #pragma unroll
        for (int i = 0; i < 8; i++) acc[qq*8+i] += a * hv[i];
      }
    }
    float o[32];
    {
      const uint4* h1p = (const uint4*)(h1 + ((size_t)(g*N_ + dst))*CH_ + ch0);
      #pragma unroll
      for (int j8 = 0; j8 < 32; j8 += 8){
        float h1v[8]; unpack8(h1p[j8>>3], h1v);
        #pragma unroll
        for (int i = 0; i < 8; i++){
          float v = acc[j8+i] + b2[ch0+j8+i];
          v = v > 0.f ? v : 0.f;
          o[j8+i] = fmaxf(h1v[i], v);
        }
      }
    }
    __syncthreads();   // all agg reads of U.a done

    // ---- transition: regs -> xs (f32) ----
    #pragma unroll
    for (int j = 0; j < 32; j++) U.l.xs[r][ch0+j] = o[j];
    __syncthreads();

    // ---- jk linear: xg(time-reversed) = xs @ jkW + jkb ----
    const int o0 = cb * 16;
    float acc2[16];
    #pragma unroll
    for (int j = 0; j < 16; j++) acc2[j] = 0.f;
    for (int k = 0; k < 128; k++){
      float xv = U.l.xs[r][k];
      const float* wrow = jkW + k*C_ + o0;
      #pragma unroll
      for (int j = 0; j < 16; j++) acc2[j] += xv * wrow[j];
    }
    float* op = xg + ((((size_t)b*N_ + n0 + r)*T_) + (T_-1-t))*C_ + o0;
    #pragma unroll
    for (int j4 = 0; j4 < 16; j4 += 4){
      float4 v = make_float4(acc2[j4]+jkb[o0+j4], acc2[j4+1]+jkb[o0+j4+1],
                             acc2[j4+2]+jkb[o0+j4+2], acc2[j4+3]+jkb[o0+j4+3]);
      *(float4*)(op + j4) = v;
    }
  } else {
    // ---- attention stats: per (b,t,h), thread = column k; (m, 1/S) over q axis ----
    const int sb = bid - 576;
    const int b = sb / (T_*H_);
    const int rem = sb % (T_*H_);
    const int t = rem / H_;
    const int h = rem % H_;
    const int n = tid;

    U.s.wq[n>>4][n&15] = Wq[n];
    U.s.wk[n>>4][n&15] = Wk[n];

    const size_t base = ((((size_t)b*N_ + n)*T_) + t)*C_ + h*D_;
    const float* dsp = dsb + n*C_ + h*D_;

    float x[16];
    #pragma unroll
    for (int j4 = 0; j4 < 16; j4 += 4){
      float4 a = *(const float4*)(query + base + j4);
      float4 d = *(const float4*)(dsp + j4);
      x[j4]=a.x+d.x; x[j4+1]=a.y+d.y; x[j4+2]=a.z+d.z; x[j4+3]=a.w+d.w;
    }
    __syncthreads();   // weights staged
    #pragma unroll
    for (int j = 0; j < 16; j++){
      float a = 0.f;
      #pragma unroll
      for (int i = 0; i < 16; i++) a += x[i]*U.s.wq[i][j];
      U.s.qs[n][j] = a;
    }
    float khr[16];
    #pragma unroll
    for (int j4 = 0; j4 < 16; j4 += 4){
      float4 a = *(const float4*)(key + base + j4);
      float4 d = *(const float4*)(dsp + j4);
      x[j4]=a.x+d.x; x[j4+1]=a.y+d.y; x[j4+2]=a.z+d.z; x[j4+3]=a.w+d.w;
    }
    #pragma unroll
    for (int j = 0; j < 16; j++){
      float a = 0.f;
      #pragma unroll
      for (int i = 0; i < 16; i++) a += x[i]*U.s.wk[i][j];
      khr[j] = a;
    }
    __syncthreads();   // qs complete

    float m[4], s[4];
    #pragma unroll
    for (int c = 0; c < 4; c++){ m[c] = -1e30f; s[c] = 0.f; }
    for (int qq = 0; qq < 64; qq++){
      #pragma unroll
      for (int c = 0; c < 4; c++){
        const float* qrow = &U.s.qs[qq + 64*c][0];
        float4 a0 = *(const float4*)(qrow);
        float4 a1 = *(const float4*)(qrow+4);
        float4 a2 = *(const float4*)(qrow+8);
        float4 a3 = *(const float4*)(qrow+12);
        float d = a0.x*khr[0]+a0.y*khr[1]+a0.z*khr[2]+a0.w*khr[3]
                + a1.x*khr[4]+a1.y*khr[5]+a1.z*khr[6]+a1.w*khr[7]
                + a2.x*khr[8]+a2.y*khr[9]+a2.z*khr[10]+a2.w*khr[11]
                + a3.x*khr[12]+a3.y*khr[13]+a3.z*khr[14]+a3.w*khr[15];
        d *= 0.125f;
        float mn = fmaxf(m[c], d);
        s[c] = s[c]*__expf(m[c]-mn) + __expf(d-mn);
        m[c] = mn;
      }
    }
    float M = fmaxf(fmaxf(m[0],m[1]), fmaxf(m[2],m[3]));
    float S = s[0]*__expf(m[0]-M) + s[1]*__expf(m[1]-M)
            + s[2]*__expf(m[2]-M) + s[3]*__expf(m[3]-M);
    mS[(size_t)sb*512 + n*2]     = M;
    mS[(size_t)sb*512 + n*2 + 1] = 1.f / S;
  }
}

// ---------------- attention AV: per (b,t,h), thread = row q; stats precomputed ----------------
__global__ __launch_bounds__(256)
void k_av(const float* __restrict__ query, const float* __restrict__ key, const float* __restrict__ value,
          const float* __restrict__ Wq, const float* __restrict__ Wk, const float* __restrict__ Wv,
          const float* __restrict__ dsb, const float* __restrict__ mS, float* __restrict__ o_ws)
{
  __shared__ float ks[N_][SP_];
  __shared__ float vs[N_][SP_];
  __shared__ float2 msl[N_];
  __shared__ float wq[16][16], wk[16][16], wv[16][16];

  const int bx = blockIdx.x;
  const int b = bx / (T_*H_);
  const int rem = bx % (T_*H_);
  const int t = rem / H_;
  const int h = rem % H_;
  const int n = threadIdx.x;

  wq[n>>4][n&15] = Wq[n];
  wk[n>>4][n&15] = Wk[n];
  wv[n>>4][n&15] = Wv[n];
  msl[n] = *(const float2*)(mS + (size_t)bx*512 + n*2);

  const size_t base = ((((size_t)b*N_ + n)*T_) + t)*C_ + h*D_;
  const float* dsp = dsb + n*C_ + h*D_;

  float ds16[16];
  #pragma unroll
  for (int j4 = 0; j4 < 16; j4 += 4){
    float4 d = *(const float4*)(dsp + j4);
    ds16[j4]=d.x; ds16[j4+1]=d.y; ds16[j4+2]=d.z; ds16[j4+3]=d.w;
  }
  __syncthreads();   // weights staged

  float x[16];
  #pragma unroll
  for (int j4 = 0; j4 < 16; j4 += 4){
    float4 a = *(const float4*)(key + base + j4);
    x[j4]=a.x+ds16[j4]; x[j4+1]=a.y+ds16[j4+1]; x[j4+2]=a.z+ds16[j4+2]; x[j4+3]=a.w+ds16[j4+3];
  }
  #pragma unroll
  for (int j = 0; j < 16; j++){
    float a = 0.f;
    #pragma unroll
    for (int i = 0; i < 16; i++) a += x[i]*wk[i][j];
    ks[n][j] = a;
  }
  #pragma unroll
  for (int j4 = 0; j4 < 16; j4 += 4){
    float4 a = *(const float4*)(value + base + j4);
    x[j4]=a.x+ds16[j4]; x[j4+1]=a.y+ds16[j4+1]; x[j4+2]=a.z+ds16[j4+2]; x[j4+3]=a.w+ds16[j4+3];
  }
  #pragma unroll
  for (int j = 0; j < 16; j++){
    float a = 0.f;
    #pragma unroll
    for (int i = 0; i < 16; i++) a += x[i]*wv[i][j];
    vs[n][j] = a;
  }
  float qhr[16];
  #pragma unroll
  for (int j4 = 0; j4 < 16; j4 += 4){
    float4 a = *(const float4*)(query + base + j4);
    x[j4]=a.x+ds16[j4]; x[j4+1]=a.y+ds16[j4+1]; x[j4+2]=a.z+ds16[j4+2]; x[j4+3]=a.w+ds16[j4+3];
  }
  #pragma unroll
  for (int j = 0; j < 16; j++){
    float a = 0.f;
    #pragma unroll
    for (int i = 0; i < 16; i++) a += x[i]*wq[i][j];
    qhr[j] = a;
  }
  __syncthreads();   // ks/vs/msl complete

  float o0[16], o1[16];
  #pragma unroll
  for (int j = 0; j < 16; j++){ o0[j] = 0.f; o1[j] = 0.f; }
  for (int k = 0; k < N_; k += 2){
    {
      const float* krow = &ks[k][0];
      float4 a0 = *(const float4*)(krow);
      float4 a1 = *(const float4*)(krow+4);
      float4 a2 = *(const float4*)(krow+8);
      float4 a3 = *(const float4*)(krow+12);
      float d = a0.x*qhr[0]+a0.y*qhr[1]+a0.z*qhr[2]+a0.w*qhr[3]
              + a1.x*qhr[4]+a1.y*qhr[5]+a1.z*qhr[6]+a1.w*qhr[7]
              + a2.x*qhr[8]+a2.y*qhr[9]+a2.z*qhr[10]+a2.w*qhr[11]
              + a3.x*qhr[12]+a3.y*qhr[13]+a3.z*qhr[14]+a3.w*qhr[15];
      float2 ms0 = msl[k];
      float p = __expf(d*0.125f - ms0.x) * ms0.y;
      const float* vrow = &vs[k][0];
      float4 v0 = *(const float4*)(vrow);
      float4 v1 = *(const float4*)(vrow+4);
      float4 v2 = *(const float4*)(vrow+8);
      float4 v3 = *(const float4*)(vrow+12);
      o0[0]+=p*v0.x; o0[1]+=p*v0.y; o0[2]+=p*v0.z; o0[3]+=p*v0.w;
      o0[4]+=p*v1.x; o0[5]+=p*v1.y; o0[6]+=p*v1.z; o0[7]+=p*v1.w;
      o0[8]+=p*v2.x; o0[9]+=p*v2.y; o0[10]+=p*v2.z; o0[11]+=p*v2.w;
      o0[12]+=p*v3.x; o0[13]+=p*v3.y; o0[14]+=p*v3.z; o0[15]+=p*v3.w;
    }
    {
      const float* krow = &ks[k+1][0];
      float4 a0 = *(const float4*)(krow);
      float4 a1 = *(const float4*)(krow+4);
      float4 a2 = *(const float4*)(krow+8);
      float4 a3 = *(const float4*)(krow+12);
      float d = a0.x*qhr[0]+a0.y*qhr[1]+a0.z*qhr[2]+a0.w*qhr[3]
              + a1.x*qhr[4]+a1.y*qhr[5]+a1.z*qhr[6]+a1.w*qhr[7]
              + a2.x*qhr[8]+a2.y*qhr[9]+a2.z*qhr[10]+a2.w*qhr[11]
              + a3.x*qhr[12]+a3.y*qhr[13]+a3.z*qhr[14]+a3.w*qhr[15];
      float2 ms1 = msl[k+1];
      float p = __expf(d*0.125f - ms1.x) * ms1.y;
      const float* vrow = &vs[k+1][0];
      float4 v0 = *(const float4*)(vrow);
      float4 v1 = *(const float4*)(vrow+4);
      float4 v2 = *(const float4*)(vrow+8);
      float4 v3 = *(const float4*)(vrow+12);
      o1[0]+=p*v0.x; o1[1]+=p*v0.y; o1[2]+=p*v0.z; o1[3]+=p*v0.w;
      o1[4]+=p*v1.x; o1[5]+=p*v1.y; o1[6]+=p*v1.z; o1[7]+=p*v1.w;
      o1[8]+=p*v2.x; o1[9]+=p*v2.y; o1[10]+=p*v2.z; o1[11]+=p*v2.w;
      o1[12]+=p*v3.x; o1[13]+=p*v3.y; o1[14]+=p*v3.z; o1[15]+=p*v3.w;
    }
  }
  float* op = o_ws + base;
  #pragma unroll
  for (int j4 = 0; j4 < 16; j4 += 4)
    *(float4*)(op + j4) = make_float4(o0[j4]+o1[j4], o0[j4+1]+o1[j4+1],
                                      o0[j4+2]+o1[j4+2], o0[j4+3]+o1[j4+3]);
}

// ---------------- fused epilogue v3: bf16 LDS staging ----------------
__global__ __launch_bounds__(256)
void k_final(const float* __restrict__ query, const float* __restrict__ dsb,
             const float* __restrict__ o_ws, const float* __restrict__ xg_ws,
             const float* __restrict__ Wfc, const float* __restrict__ bfc,
             const float* __restrict__ ln1g, const float* __restrict__ ln1b,
             const float* __restrict__ ln2g, const float* __restrict__ ln2b,
             const float* __restrict__ Wff1, const float* __restrict__ bff1,
             const float* __restrict__ Wff2, const float* __restrict__ bff2,
             const float* __restrict__ Wfs, const float* __restrict__ bfs,
             const float* __restrict__ Wfg, const float* __restrict__ bfg,
             float* __restrict__ out)
{
  __shared__ u16 smA[64*66];                       // o_t -> us_t (bf16)
  __shared__ u16 smB[64*66];                       // qd_t -> ms_t (bf16)
  __shared__ union UH { u16 h[128*66]; float o[64*66]; } HH;  // hidden/xg (bf16) -> out_t (f32)
  __shared__ float lnxA[4][64];
  __shared__ float lnxB[4][64];

  const int tid = threadIdx.x;
  const int token0 = blockIdx.x * 64;
  const int w = rfl(tid >> 6);
  const int tok = tid & 63;
  const int c0 = w * 16;

  #pragma unroll
  for (int it = 0; it < 4; it++){
    int idx = tid + 256*it;
    int tk = idx >> 4, c4 = (idx & 15) * 4;
    int gtok = token0 + tk;
    int n = (gtok / T_) & (N_-1);
    float4 ov = *(const float4*)(o_ws + (size_t)gtok*C_ + c4);
    float4 qv = *(const float4*)(query + (size_t)gtok*C_ + c4);
    float4 dv = *(const float4*)(dsb + n*C_ + c4);
    smA[(c4+0)*66+tk] = f2bf(ov.x); smA[(c4+1)*66+tk] = f2bf(ov.y);
    smA[(c4+2)*66+tk] = f2bf(ov.z); smA[(c4+3)*66+tk] = f2bf(ov.w);
    smB[(c4+0)*66+tk] = f2bf(qv.x+dv.x); smB[(c4+1)*66+tk] = f2bf(qv.y+dv.y);
    smB[(c4+2)*66+tk] = f2bf(qv.z+dv.z); smB[(c4+3)*66+tk] = f2bf(qv.w+dv.w);
  }
  __syncthreads();

  // fc
  float x1[16];
  #pragma unroll
  for (int j = 0; j < 16; j++) x1[j] = 0.f;
  for (int i = 0; i < C_; i++){
    float ov = bf2f(smA[i*66 + tok]);
    const float* wrow = Wfc + i*C_ + c0;
    #pragma unroll
    for (int j = 0; j < 16; j++) x1[j] += ov * wrow[j];
  }
  #pragma unroll
  for (int j = 0; j < 16; j++) x1[j] += bfc[c0+j] + bf2f(smB[(c0+j)*66 + tok]);

  // LN1
  float s1 = 0.f;
  #pragma unroll
  for (int j = 0; j < 16; j++) s1 += x1[j];
  lnxA[w][tok] = s1;
  __syncthreads();
  float mu = (lnxA[0][tok]+lnxA[1][tok]+lnxA[2][tok]+lnxA[3][tok]) * (1.f/64.f);
  float v1 = 0.f;
  #pragma unroll
  for (int j = 0; j < 16; j++){ float d = x1[j]-mu; v1 += d*d; }
  lnxB[w][tok] = v1;
  __syncthreads();
  float var = (lnxB[0][tok]+lnxB[1][tok]+lnxB[2][tok]+lnxB[3][tok]) * (1.f/64.f);
  float rstd = rsqrtf(var + 1e-5f);
  float ms[16];
  #pragma unroll
  for (int j = 0; j < 16; j++) ms[j] = (x1[j]-mu)*rstd*ln1g[c0+j] + ln1b[c0+j];
  __syncthreads();
  #pragma unroll
  for (int j = 0; j < 16; j++) smB[(c0+j)*66 + tok] = f2bf(ms[j]);
  __syncthreads();

  // FFN
  float part[16];
  #pragma unroll
  for (int j = 0; j < 16; j++) part[j] = 0.f;
  #pragma unroll
  for (int ch = 0; ch < 2; ch++){
    float fch[32];
    #pragma unroll
    for (int kk = 0; kk < 32; kk++) fch[kk] = 0.f;
    const int kbase = w*64 + ch*32;
    for (int i = 0; i < C_; i++){
      float msv = bf2f(smB[i*66 + tok]);
      const float* wrow = Wff1 + i*(4*C_) + kbase;
      #pragma unroll
      for (int kk = 0; kk < 32; kk++) fch[kk] += msv * wrow[kk];
    }
    #pragma unroll
    for (int kk = 0; kk < 32; kk++){
      float v = fch[kk] + bff1[kbase+kk];
      fch[kk] = v > 0.f ? v : 0.f;
    }
    if (ch) __syncthreads();
    #pragma unroll
    for (int kk = 0; kk < 32; kk++) HH.h[(w*32+kk)*66 + tok] = f2bf(fch[kk]);
    __syncthreads();
    #pragma unroll
    for (int wq = 0; wq < 4; wq++){
      #pragma unroll 8
      for (int kk = 0; kk < 32; kk++){
        int k = wq*64 + ch*32 + kk;
        float hv = bf2f(HH.h[(wq*32+kk)*66 + tok]);
        const float* wrow = Wff2 + k*C_ + c0;
        #pragma unroll
        for (int j = 0; j < 16; j++) part[j] += hv * wrow[j];
      }
    }
  }
  float x2[16];
  #pragma unroll
  for (int j = 0; j < 16; j++) x2[j] = part[j] + bff2[c0+j] + ms[j];

  // LN2
  float s2 = 0.f;
  #pragma unroll
  for (int j = 0; j < 16; j++) s2 += x2[j];
  __syncthreads();
  lnxA[w][tok] = s2;
  __syncthreads();
  float mu2 = (lnxA[0][tok]+lnxA[1][tok]+lnxA[2][tok]+lnxA[3][tok]) * (1.f/64.f);
  float v2 = 0.f;
  #pragma unroll
  for (int j = 0; j < 16; j++){ float d = x2[j]-mu2; v2 += d*d; }
  lnxB[w][tok] = v2;
  __syncthreads();
  float var2 = (lnxB[0][tok]+lnxB[1][tok]+lnxB[2][tok]+lnxB[3][tok]) * (1.f/64.f);
  float rstd2 = rsqrtf(var2 + 1e-5f);
  float us[16];
  #pragma unroll
  for (int j = 0; j < 16; j++) us[j] = (x2[j]-mu2)*rstd2*ln2g[c0+j] + ln2b[c0+j];

  // us -> smA ; xg -> HH.h rows 0..63 (hidden dead)
  #pragma unroll
  for (int j = 0; j < 16; j++) smA[(c0+j)*66 + tok] = f2bf(us[j]);
  #pragma unroll
  for (int it = 0; it < 4; it++){
    int idx = tid + 256*it;
    int tk = idx >> 4, c4 = (idx & 15) * 4;
    int gtok = token0 + tk;
    float4 xv = *(const float4*)(xg_ws + (size_t)gtok*C_ + c4);
    HH.h[(c4+0)*66+tk] = f2bf(xv.x); HH.h[(c4+1)*66+tk] = f2bf(xv.y);
    HH.h[(c4+2)*66+tk] = f2bf(xv.z); HH.h[(c4+3)*66+tk] = f2bf(xv.w);
  }
  __syncthreads();

  // gate
  float ga[16];
  #pragma unroll
  for (int j = 0; j < 16; j++) ga[j] = 0.f;
  for (int i = 0; i < C_; i++){
    float uv = bf2f(smA[i*66 + tok]);
    float xv = bf2f(HH.h[i*66 + tok]);
    const float* wsr = Wfs + i*C_ + c0;
    const float* wgr = Wfg + i*C_ + c0;
    #pragma unroll
    for (int j = 0; j < 16; j++) ga[j] += uv*wsr[j] + xv*wgr[j];
  }
  float res[16];
  #pragma unroll
  for (int j = 0; j < 16; j++){
    float a = ga[j] + bfs[c0+j] + bfg[c0+j];
    float gg = 1.f / (1.f + __expf(-a));
    float xgv = bf2f(HH.h[(c0+j)*66 + tok]);
    res[j] = gg*us[j] + (1.f-gg)*xgv;
  }
  __syncthreads();   // all xg reads done before f32 reuse of HH
  #pragma unroll
  for (int j = 0; j < 16; j++) HH.o[(c0+j)*66 + tok] = res[j];
  __syncthreads();
  #pragma unroll
  for (int it = 0; it < 4; it++){
    int idx = tid + 256*it;
    int tk = idx >> 4, c4 = (idx & 15) * 4;
    int gtok = token0 + tk;
    float4 v = make_float4(HH.o[(c4+0)*66+tk], HH.o[(c4+1)*66+tk],
                           HH.o[(c4+2)*66+tk], HH.o[(c4+3)*66+tk]);
    *(float4*)(out + (size_t)gtok*C_ + c4) = v;
  }
}

extern "C" void kernel_launch(void* const* d_in, const int* in_sizes, int n_in,
                              void* d_out, int out_size, void* d_ws, size_t ws_size,
                              hipStream_t stream)
{
  (void)in_sizes; (void)n_in; (void)out_size; (void)ws_size;
  const float* query = (const float*)d_in[0];
  const float* key   = (const float*)d_in[1];
  const float* value = (const float*)d_in[2];
  const float* DSm   = (const float*)d_in[4];
  const float* Wemb  = (const float*)d_in[5];
  const float* bemb  = (const float*)d_in[6];
  const float* Wq    = (const float*)d_in[7];
  const float* Wk    = (const float*)d_in[8];
  const float* Wv    = (const float*)d_in[9];
  const float* Wfc   = (const float*)d_in[10];
  const float* bfc   = (const float*)d_in[11];
  const float* ln1g  = (const float*)d_in[12];
  const float* ln1b  = (const float*)d_in[13];
  const float* ln2g  = (const float*)d_in[14];
  const float* ln2b  = (const float*)d_in[15];
  const float* Wff1  = (const float*)d_in[16];
  const float* bff1  = (const float*)d_in[17];
  const float* Wff2  = (const float*)d_in[18];
  const float* bff2  = (const float*)d_in[19];
  const float* g1W   = (const float*)d_in[20];
  const float* g1as  = (const float*)d_in[21];
  const float* g1ad  = (const float*)d_in[22];
  const float* g1b   = (const float*)d_in[23];
  const float* g2W   = (const float*)d_in[24];
  const float* g2as  = (const float*)d_in[25];
  const float* g2ad  = (const float*)d_in[26];
  const float* g2b   = (const float*)d_in[27];
  const float* jkW   = (const float*)d_in[28];
  const float* jkb   = (const float*)d_in[29];
  const float* Wfs   = (const float*)d_in[30];
  const float* bfs   = (const float*)d_in[31];
  const float* Wfg   = (const float*)d_in[32];
  const float* bfg   = (const float*)d_in[33];
  const int* ei      = (const int*)d_in[34];
  float* out = (float*)d_out;

  float* wf     = (float*)d_ws;
  float* dsb    = wf + DS_OFF;
  float* xg_ws  = wf + XG_OFF;
  u16*   hA     = (u16*)(wf + HA_OFF);
  u16*   hB     = (u16*)(wf + HB_OFF);
  float* o_ws   = wf + HA_OFF;             // aliases hA (dead before k_av)
  float* hs_ws  = wf + HS_OFF;
  float* hd_ws  = wf + HD_OFF;
  int*   indptr = (int*)(wf + INT_OFF);
  int*   srcs   = indptr + 260;
  float* mS     = wf + MS_OFF;

  k_pre  <<<dim3(641),  dim3(256), 0, stream>>>(query, g1W, g1as, g1ad, hA, hs_ws, hd_ws,
                                                DSm, Wemb, bemb, dsb, ei, indptr, srcs);
  k_agg1 <<<dim3(576),  dim3(256), 0, stream>>>(hA, hs_ws, hd_ws, indptr, srcs, g1b, hB);
  k_lin2 <<<dim3(576),  dim3(256), 0, stream>>>(hB, g2W, g2as, g2ad, hA, hs_ws, hd_ws);
  k_aggjk<<<dim3(1152), dim3(256), 0, stream>>>(hA, hs_ws, hd_ws, indptr, srcs, g2b, hB,
                                                jkW, jkb, xg_ws,
                                                query, key, Wq, Wk, dsb, mS);
  k_av   <<<dim3(576),  dim3(256), 0, stream>>>(query, key, value, Wq, Wk, Wv, dsb, mS, o_ws);
  k_final<<<dim3(576),  dim3(256), 0, stream>>>(query, dsb, o_ws, xg_ws,
      Wfc, bfc, ln1g, ln1b, ln2g, ln2b,
      Wff1, bff1, Wff2, bff2,
      Wfs, bfs, Wfg, bfg, out);
}

// Round 10
// 304.559 us; speedup vs baseline: 1.4283x; 1.0593x over previous
//
#include <hip/hip_runtime.h>

typedef unsigned short u16;
typedef unsigned int u32;

#define B_ 4
#define N_ 256
#define T_ 36
#define C_ 64
#define H_ 4
#define D_ 16
#define CH_ 128
#define E_ 4096
#define EQ_ 1408   // per-quarter edge cap (mean 1024, sigma ~28 -> +14 sigma)
#define G_ (B_*T_)
#define TOK_ (B_*N_*T_)

// workspace layout (float offsets)
#define DS_OFF  0
#define XG_OFF  (DS_OFF + N_*C_)
#define HA_OFF  (XG_OFF + TOK_*C_)          // bf16 h buffer A (conv outs); aliased by o_ws later
#define HB_OFF  (HA_OFF + G_*N_*CH_/2)      // bf16 buffer B (h1)
#define HS_OFF  (HB_OFF + G_*N_*CH_/2)
#define HD_OFF  (HS_OFF + G_*N_)
#define INT_OFF (HD_OFF + G_*N_)
#define MS_OFF  (INT_OFF + 4608)            // (m, 1/S) pairs: 576 * 512 floats

__device__ __forceinline__ float bf2f(u16 u){
  u32 x = ((u32)u) << 16;
  return __builtin_bit_cast(float, x);
}
__device__ __forceinline__ u16 f2bf(float f){
  u32 x = __builtin_bit_cast(u32, f);
  x += 0x7fffu + ((x >> 16) & 1u);
  return (u16)(x >> 16);
}
__device__ __forceinline__ void unpack8(uint4 u, float* f){
  f[0]=bf2f((u16)(u.x & 0xffffu)); f[1]=bf2f((u16)(u.x >> 16));
  f[2]=bf2f((u16)(u.y & 0xffffu)); f[3]=bf2f((u16)(u.y >> 16));
  f[4]=bf2f((u16)(u.z & 0xffffu)); f[5]=bf2f((u16)(u.z >> 16));
  f[6]=bf2f((u16)(u.w & 0xffffu)); f[7]=bf2f((u16)(u.w >> 16));
}
__device__ __forceinline__ uint4 pack8f(const float* f){
  uint4 u;
  u.x = (u32)f2bf(f[0]) | ((u32)f2bf(f[1]) << 16);
  u.y = (u32)f2bf(f[2]) | ((u32)f2bf(f[3]) << 16);
  u.z = (u32)f2bf(f[4]) | ((u32)f2bf(f[5]) << 16);
  u.w = (u32)f2bf(f[6]) | ((u32)f2bf(f[7]) << 16);
  return u;
}
__device__ __forceinline__ int rfl(int v){ return __builtin_amdgcn_readfirstlane(v); }

// XCD swizzle: all 4 quarter-blocks of graph g share bid%8 == g%8 (same XCD L2)
__device__ __forceinline__ void gq_from_bid(int bid, int& g, int& q){
  int xc = bid & 7, slot = bid >> 3;
  q = slot & 3;
  g = xc + ((slot >> 2) << 3);
}

#define SP_ 20   // f32 attn row pitch (80B, 16B-aligned)

// parallel per-dst edge softmax: 4 threads per dst (slices mod 4), shfl-combined.
// tid in [0,256); writes alpha_l[p0..p1) normalized. Requires hs_l staged + __syncthreads before.
__device__ __forceinline__ void edge_softmax_par(int tid, int n0,
    const int* __restrict__ indptr, int p00,
    const int* srcs_l, const float* hs_l, const float* __restrict__ hd_ws,
    int g, float* alpha_l)
{
  const int ld = tid >> 2;
  const int sl = tid & 3;
  const int dst = n0 + ld;
  const int p0 = indptr[dst] - p00, p1 = indptr[dst+1] - p00;
  const float hdn = hd_ws[g*N_ + dst];
  float m = -1e30f;
  for (int j = p0 + sl; j < p1; j += 4){
    float e = hs_l[srcs_l[j]] + hdn;
    e = e > 0.f ? e : 0.2f * e;
    alpha_l[j] = e;
    m = fmaxf(m, e);
  }
  m = fmaxf(m, __shfl_xor(m, 1, 64));
  m = fmaxf(m, __shfl_xor(m, 2, 64));
  float s = 0.f;
  for (int j = p0 + sl; j < p1; j += 4){
    float w = __expf(alpha_l[j] - m);
    alpha_l[j] = w; s += w;
  }
  s += __shfl_xor(s, 1, 64);
  s += __shfl_xor(s, 2, 64);
  float inv = 1.f / (s + 1e-16f);
  for (int j = p0 + sl; j < p1; j += 4) alpha_l[j] *= inv;
}

// ---------------- fused pre: lin1 (576) + ds (64) + csr (1) ----------------
__global__ __launch_bounds__(256)
void k_pre(const float* __restrict__ query, const float* __restrict__ W1,
           const float* __restrict__ as1, const float* __restrict__ ad1,
           u16* __restrict__ h, float* __restrict__ hs_ws, float* __restrict__ hd_ws,
           const float* __restrict__ DSm, const float* __restrict__ Wemb,
           const float* __restrict__ bemb, float* __restrict__ dsb,
           const int* __restrict__ ei, int* __restrict__ indptr, int* __restrict__ srcs)
{
  __shared__ union UP {
    struct { float xs[64][65]; float red[2][4][64]; } lin;
    struct { int srcL[E_]; int dstL[E_]; int tmp[E_]; int cnt[N_]; int base[N_+1]; } c;
  } S;
  const int bid = blockIdx.x;
  const int tid = threadIdx.x;

  if (bid < 576){
    int g, q; gq_from_bid(bid, g, q);
    const int n0 = q * 64;
    const int b = g / T_, t = g % T_;
    {
      const size_t gb = (((size_t)b*N_ + n0)*T_ + t)*C_;
      #pragma unroll
      for (int it = 0; it < 4; it++){
        int idx = tid + 256*it;
        int row = idx >> 4, c4 = (idx & 15) * 4;
        float4 v = *(const float4*)(query + gb + (size_t)row*(T_*C_) + c4);
        S.lin.xs[row][c4+0] = v.x; S.lin.xs[row][c4+1] = v.y;
        S.lin.xs[row][c4+2] = v.z; S.lin.xs[row][c4+3] = v.w;
      }
    }
    __syncthreads();

    const int r = tid & 63;
    const int cb = rfl(tid >> 6);
    const int ch0 = cb * 32;

    float acc[32];
    #pragma unroll
    for (int j = 0; j < 32; j++) acc[j] = 0.f;
    for (int k = 0; k < 64; k++){
      float xv = S.lin.xs[r][k];
      const float* wrow = W1 + k*CH_ + ch0;   // wave-uniform -> scalar loads
      #pragma unroll
      for (int j = 0; j < 32; j++) acc[j] += xv * wrow[j];
    }
    float hs = 0.f, hd = 0.f;
    #pragma unroll
    for (int j = 0; j < 32; j++){ hs += acc[j]*as1[ch0+j]; hd += acc[j]*ad1[ch0+j]; }
    S.lin.red[0][cb][r] = hs; S.lin.red[1][cb][r] = hd;

    u16* hp = h + ((size_t)(g*N_ + n0 + r))*CH_ + ch0;
    #pragma unroll
    for (int j8 = 0; j8 < 32; j8 += 8)
      *(uint4*)(hp + j8) = pack8f(&acc[j8]);

    __syncthreads();
    if (tid < 64){
      float a = S.lin.red[0][0][tid]+S.lin.red[0][1][tid]+S.lin.red[0][2][tid]+S.lin.red[0][3][tid];
      float d = S.lin.red[1][0][tid]+S.lin.red[1][1][tid]+S.lin.red[1][2][tid]+S.lin.red[1][3][tid];
      hs_ws[g*N_ + n0 + tid] = a;
      hd_ws[g*N_ + n0 + tid] = d;
    }
  } else if (bid < 640){
    const int n = (bid - 576) * 4 + (tid >> 6);   // wave-uniform
    const int c = tid & 63;
    float acc = bemb[c];
    for (int m = 0; m < N_; m++) acc += DSm[n*N_ + m] * Wemb[m*C_ + c];
    dsb[n*C_ + c] = acc;
  } else {
    for (int e = tid; e < E_; e += 256){ S.c.srcL[e] = ei[e]; S.c.dstL[e] = ei[E_ + e]; }
    S.c.cnt[tid] = 0;
    __syncthreads();
    for (int e = tid; e < E_; e += 256) atomicAdd(&S.c.cnt[S.c.dstL[e]], 1);
    __syncthreads();
    if (tid == 0){
      int run = 0;
      for (int i = 0; i < N_; i++){ S.c.base[i] = run; run += S.c.cnt[i]; }
      S.c.base[N_] = run;
    }
    __syncthreads();
    S.c.cnt[tid] = 0;
    __syncthreads();
    for (int e = tid; e < E_; e += 256){
      int d = S.c.dstL[e];
      int p = atomicAdd(&S.c.cnt[d], 1);
      S.c.tmp[S.c.base[d] + p] = e;
    }
    __syncthreads();
    {
      const int p0 = S.c.base[tid], p1 = S.c.base[tid] + S.c.cnt[tid];
      for (int i = p0 + 1; i < p1; i++){      // insertion sort by edge id -> deterministic
        int v = S.c.tmp[i]; int j = i - 1;
        while (j >= p0 && S.c.tmp[j] > v){ S.c.tmp[j+1] = S.c.tmp[j]; j--; }
        S.c.tmp[j+1] = v;
      }
      for (int j = p0; j < p1; j++) srcs[j] = S.c.srcL[S.c.tmp[j]];
    }
    indptr[tid] = S.c.base[tid];
    if (tid == 0) indptr[N_] = S.c.base[N_];
  }
}

// ---------------- agg1: parallel softmax + gather, h1 = relu(agg + b1) -> hB ----------------
__global__ __launch_bounds__(256)
void k_agg1(const u16* __restrict__ hin, const float* __restrict__ hs_ws, const float* __restrict__ hd_ws,
            const int* __restrict__ indptr, const int* __restrict__ srcs,
            const float* __restrict__ bias, u16* __restrict__ hout)
{
  __shared__ int   srcs_l[EQ_];
  __shared__ float alpha_l[EQ_];
  __shared__ float hs_l[N_];
  const int bid = blockIdx.x;
  int g, q; gq_from_bid(bid, g, q);
  const int n0 = q * 64;
  const int tid = threadIdx.x;

  const int p00 = indptr[n0];
  const int pend = indptr[n0 + 64];
  const int cntE = pend - p00;
  for (int i = tid; i < cntE; i += 256) srcs_l[i] = srcs[p00 + i];
  hs_l[tid] = hs_ws[g*N_ + tid];
  __syncthreads();

  edge_softmax_par(tid, n0, indptr, p00, srcs_l, hs_l, hd_ws, g, alpha_l);
  __syncthreads();

  const int r = tid & 63;
  const int cb = rfl(tid >> 6);
  const int ch0 = cb * 32;
  const int dst = n0 + r;
  const int p0 = indptr[dst] - p00, p1 = indptr[dst+1] - p00;

  float acc[32];
  #pragma unroll
  for (int j = 0; j < 32; j++) acc[j] = 0.f;
  for (int j = p0; j < p1; j++){
    float a = alpha_l[j];
    int s = srcs_l[j];
    const uint4* hp = (const uint4*)(hin + ((size_t)(g*N_ + s))*CH_ + ch0);
    #pragma unroll
    for (int qq = 0; qq < 4; qq++){
      float hv[8]; unpack8(hp[qq], hv);
      #pragma unroll
      for (int i = 0; i < 8; i++) acc[qq*8+i] += a * hv[i];
    }
  }
  float o[32];
  #pragma unroll
  for (int j = 0; j < 32; j++){
    float v = acc[j] + bias[ch0+j];
    o[j] = v > 0.f ? v : 0.f;
  }
  u16* op = hout + ((size_t)(g*N_ + dst))*CH_ + ch0;
  #pragma unroll
  for (int j8 = 0; j8 < 32; j8 += 8)
    *(uint4*)(op + j8) = pack8f(&o[j8]);
}

// ---------------- lin2: h2 = bf16(h1 @ W2), fused hs2/hd2 ----------------
__global__ __launch_bounds__(256)
void k_lin2(const u16* __restrict__ h1, const float* __restrict__ W2,
            const float* __restrict__ as2, const float* __restrict__ ad2,
            u16* __restrict__ h2, float* __restrict__ hs_ws, float* __restrict__ hd_ws)
{
  __shared__ float xs[64][129];
  __shared__ float red[2][4][64];
  const int bid = blockIdx.x;
  int g, q; gq_from_bid(bid, g, q);
  const int n0 = q * 64;
  const int tid = threadIdx.x;

  {
    #pragma unroll
    for (int it = 0; it < 4; it++){
      int idx = tid + 256*it;
      int row = idx >> 4, c8 = (idx & 15) * 8;
      uint4 u = *(const uint4*)(h1 + ((size_t)(g*N_ + n0 + row))*CH_ + c8);
      float v[8]; unpack8(u, v);
      #pragma unroll
      for (int i = 0; i < 8; i++) xs[row][c8+i] = v[i];
    }
  }
  __syncthreads();

  const int r = tid & 63;
  const int cb = rfl(tid >> 6);
  const int ch0 = cb * 32;

  float acc[32];
  #pragma unroll
  for (int j = 0; j < 32; j++) acc[j] = 0.f;
  for (int k = 0; k < 128; k++){
    float xv = xs[r][k];
    const float* wrow = W2 + k*CH_ + ch0;
    #pragma unroll
    for (int j = 0; j < 32; j++) acc[j] += xv * wrow[j];
  }
  float hs = 0.f, hd = 0.f;
  #pragma unroll
  for (int j = 0; j < 32; j++){ hs += acc[j]*as2[ch0+j]; hd += acc[j]*ad2[ch0+j]; }
  red[0][cb][r] = hs; red[1][cb][r] = hd;

  u16* hp = h2 + ((size_t)(g*N_ + n0 + r))*CH_ + ch0;
  #pragma unroll
  for (int j8 = 0; j8 < 32; j8 += 8)
    *(uint4*)(hp + j8) = pack8f(&acc[j8]);

  __syncthreads();
  if (tid < 64){
    float a = red[0][0][tid]+red[0][1][tid]+red[0][2][tid]+red[0][3][tid];
    float d = red[1][0][tid]+red[1][1][tid]+red[1][2][tid]+red[1][3][tid];
    hs_ws[g*N_ + n0 + tid] = a;
    hd_ws[g*N_ + n0 + tid] = d;
  }
}

// ---------------- fused: agg2 + jk-max + jk-linear (blocks 0..575) ; attn stats (576..1151) ----------------
__global__ __launch_bounds__(256)
void k_aggjk(const u16* __restrict__ h2, const float* __restrict__ hs_ws, const float* __restrict__ hd_ws,
             const int* __restrict__ indptr, const int* __restrict__ srcs,
             const float* __restrict__ b2, const u16* __restrict__ h1,
             const float* __restrict__ jkW, const float* __restrict__ jkb, float* __restrict__ xg,
             const float* __restrict__ query, const float* __restrict__ key,
             const float* __restrict__ Wq, const float* __restrict__ Wk,
             const float* __restrict__ dsb, float* __restrict__ mS)
{
  __shared__ union UJ {
    struct { int srcs_l[EQ_]; float alpha_l[EQ_]; float hs_l[N_]; } a;
    struct { u16 xs[64][136]; } l;          // bf16 jk input (16B-aligned rows)
    struct { float qs[N_][SP_]; float wq[16][16]; float wk[16][16]; } s;
  } U;
  const int bid = blockIdx.x;
  const int tid = threadIdx.x;

  if (bid < 576){
    int g, q; gq_from_bid(bid, g, q);
    const int n0 = q * 64;
    const int b = g / T_, t = g % T_;

    // ---- agg2 phase (output stays in regs) ----
    const int p00 = indptr[n0];
    const int pend = indptr[n0 + 64];
    const int cntE = pend - p00;
    for (int i = tid; i < cntE; i += 256) U.a.srcs_l[i] = srcs[p00 + i];
    U.a.hs_l[tid] = hs_ws[g*N_ + tid];
    __syncthreads();

    edge_softmax_par(tid, n0, indptr, p00, U.a.srcs_l, U.a.hs_l, hd_ws, g, U.a.alpha_l);
    __syncthreads();

    const int r = tid & 63;
    const int cb = rfl(tid >> 6);
    const int ch0 = cb * 32;
    const int dst = n0 + r;
    const int p0 = indptr[dst] - p00, p1 = indptr[dst+1] - p00;

    float acc[32];
    #pragma unroll
    for (int j = 0; j < 32; j++) acc[j] = 0.f;
    for (int j = p0; j < p1; j++){
      float a = U.a.alpha_l[j];
      int s = U.a.srcs_l[j];
      const uint4* hp = (const uint4*)(h2 + ((size_t)(g*N_ + s))*CH_ + ch0);
      #pragma unroll
      for (int qq = 0; qq < 4; qq++){
        float hv[8]; unpack8(hp[qq], hv);
        #pragma unroll
        for (int i = 0; i < 8; i++) acc[qq*8+i] += a * hv[i];
      }
    }
    float o[32];
    {
      const uint4* h1p = (const uint4*)(h1 + ((size_t)(g*N_ + dst))*CH_ + ch0);
      #pragma unroll
      for (int j8 = 0; j8 < 32; j8 += 8){
        float h1v[8]; unpack8(h1p[j8>>3], h1v);
        #pragma unroll
        for (int i = 0; i < 8; i++){
          float v = acc[j8+i] + b2[ch0+j8+i];
          v = v > 0.f ? v : 0.f;
          o[j8+i] = fmaxf(h1v[i], v);
        }
      }
    }
    __syncthreads();   // all agg reads of U.a done

    // ---- transition: regs -> xs (bf16) ----
    #pragma unroll
    for (int j8 = 0; j8 < 32; j8 += 8)
      *(uint4*)&U.l.xs[r][ch0 + j8] = pack8f(&o[j8]);
    __syncthreads();

    // ---- jk linear: xg(time-reversed) = xs @ jkW + jkb ----
    const int o0 = cb * 16;
    float acc2[16];
    #pragma unroll
    for (int j = 0; j < 16; j++) acc2[j] = 0.f;
    for (int k8 = 0; k8 < 16; k8++){
      uint4 u = *(const uint4*)&U.l.xs[r][k8*8];
      float hv[8]; unpack8(u, hv);
      #pragma unroll
      for (int kk = 0; kk < 8; kk++){
        const float* wrow = jkW + (k8*8+kk)*C_ + o0;
        #pragma unroll
        for (int j = 0; j < 16; j++) acc2[j] += hv[kk] * wrow[j];
      }
    }
    float* op = xg + ((((size_t)b*N_ + n0 + r)*T_) + (T_-1-t))*C_ + o0;
    #pragma unroll
    for (int j4 = 0; j4 < 16; j4 += 4){
      float4 v = make_float4(acc2[j4]+jkb[o0+j4], acc2[j4+1]+jkb[o0+j4+1],
                             acc2[j4+2]+jkb[o0+j4+2], acc2[j4+3]+jkb[o0+j4+3]);
      *(float4*)(op + j4) = v;
    }
  } else {
    // ---- attention stats: per (b,t,h), thread = column k; (m, 1/S) over q axis ----
    const int sb = bid - 576;
    const int b = sb / (T_*H_);
    const int rem = sb % (T_*H_);
    const int t = rem / H_;
    const int h = rem % H_;
    const int n = tid;

    U.s.wq[n>>4][n&15] = Wq[n];
    U.s.wk[n>>4][n&15] = Wk[n];

    const size_t base = ((((size_t)b*N_ + n)*T_) + t)*C_ + h*D_;
    const float* dsp = dsb + n*C_ + h*D_;

    float x[16];
    #pragma unroll
    for (int j4 = 0; j4 < 16; j4 += 4){
      float4 a = *(const float4*)(query + base + j4);
      float4 d = *(const float4*)(dsp + j4);
      x[j4]=a.x+d.x; x[j4+1]=a.y+d.y; x[j4+2]=a.z+d.z; x[j4+3]=a.w+d.w;
    }
    __syncthreads();   // weights staged
    #pragma unroll
    for (int j = 0; j < 16; j++){
      float a = 0.f;
      #pragma unroll
      for (int i = 0; i < 16; i++) a += x[i]*U.s.wq[i][j];
      U.s.qs[n][j] = a;
    }
    float khr[16];
    #pragma unroll
    for (int j4 = 0; j4 < 16; j4 += 4){
      float4 a = *(const float4*)(key + base + j4);
      float4 d = *(const float4*)(dsp + j4);
      x[j4]=a.x+d.x; x[j4+1]=a.y+d.y; x[j4+2]=a.z+d.z; x[j4+3]=a.w+d.w;
    }
    #pragma unroll
    for (int j = 0; j < 16; j++){
      float a = 0.f;
      #pragma unroll
      for (int i = 0; i < 16; i++) a += x[i]*U.s.wk[i][j];
      khr[j] = a;
    }
    __syncthreads();   // qs complete

    float m[4], s[4];
    #pragma unroll
    for (int c = 0; c < 4; c++){ m[c] = -1e30f; s[c] = 0.f; }
    for (int qq = 0; qq < 64; qq++){
      #pragma unroll
      for (int c = 0; c < 4; c++){
        const float* qrow = &U.s.qs[qq + 64*c][0];
        float4 a0 = *(const float4*)(qrow);
        float4 a1 = *(const float4*)(qrow+4);
        float4 a2 = *(const float4*)(qrow+8);
        float4 a3 = *(const float4*)(qrow+12);
        float d = a0.x*khr[0]+a0.y*khr[1]+a0.z*khr[2]+a0.w*khr[3]
                + a1.x*khr[4]+a1.y*khr[5]+a1.z*khr[6]+a1.w*khr[7]
                + a2.x*khr[8]+a2.y*khr[9]+a2.z*khr[10]+a2.w*khr[11]
                + a3.x*khr[12]+a3.y*khr[13]+a3.z*khr[14]+a3.w*khr[15];
        d *= 0.125f;
        float mn = fmaxf(m[c], d);
        s[c] = s[c]*__expf(m[c]-mn) + __expf(d-mn);
        m[c] = mn;
      }
    }
    float M = fmaxf(fmaxf(m[0],m[1]), fmaxf(m[2],m[3]));
    float S = s[0]*__expf(m[0]-M) + s[1]*__expf(m[1]-M)
            + s[2]*__expf(m[2]-M) + s[3]*__expf(m[3]-M);
    mS[(size_t)sb*512 + n*2]     = M;
    mS[(size_t)sb*512 + n*2 + 1] = 1.f / S;
  }
}

// ---------------- attention AV: per (b,t,h), thread = row q; stats precomputed ----------------
__global__ __launch_bounds__(256)
void k_av(const float* __restrict__ query, const float* __restrict__ key, const float* __restrict__ value,
          const float* __restrict__ Wq, const float* __restrict__ Wk, const float* __restrict__ Wv,
          const float* __restrict__ dsb, const float* __restrict__ mS, float* __restrict__ o_ws)
{
  __shared__ float ks[N_][SP_];
  __shared__ float vs[N_][SP_];
  __shared__ float2 msl[N_];
  __shared__ float wq[16][16], wk[16][16], wv[16][16];

  const int bx = blockIdx.x;
  const int b = bx / (T_*H_);
  const int rem = bx % (T_*H_);
  const int t = rem / H_;
  const int h = rem % H_;
  const int n = threadIdx.x;

  wq[n>>4][n&15] = Wq[n];
  wk[n>>4][n&15] = Wk[n];
  wv[n>>4][n&15] = Wv[n];
  msl[n] = *(const float2*)(mS + (size_t)bx*512 + n*2);

  const size_t base = ((((size_t)b*N_ + n)*T_) + t)*C_ + h*D_;
  const float* dsp = dsb + n*C_ + h*D_;

  float ds16[16];
  #pragma unroll
  for (int j4 = 0; j4 < 16; j4 += 4){
    float4 d = *(const float4*)(dsp + j4);
    ds16[j4]=d.x; ds16[j4+1]=d.y; ds16[j4+2]=d.z; ds16[j4+3]=d.w;
  }
  __syncthreads();   // weights staged

  float x[16];
  #pragma unroll
  for (int j4 = 0; j4 < 16; j4 += 4){
    float4 a = *(const float4*)(key + base + j4);
    x[j4]=a.x+ds16[j4]; x[j4+1]=a.y+ds16[j4+1]; x[j4+2]=a.z+ds16[j4+2]; x[j4+3]=a.w+ds16[j4+3];
  }
  #pragma unroll
  for (int j = 0; j < 16; j++){
    float a = 0.f;
    #pragma unroll
    for (int i = 0; i < 16; i++) a += x[i]*wk[i][j];
    ks[n][j] = a;
  }
  #pragma unroll
  for (int j4 = 0; j4 < 16; j4 += 4){
    float4 a = *(const float4*)(value + base + j4);
    x[j4]=a.x+ds16[j4]; x[j4+1]=a.y+ds16[j4+1]; x[j4+2]=a.z+ds16[j4+2]; x[j4+3]=a.w+ds16[j4+3];
  }
  #pragma unroll
  for (int j = 0; j < 16; j++){
    float a = 0.f;
    #pragma unroll
    for (int i = 0; i < 16; i++) a += x[i]*wv[i][j];
    vs[n][j] = a;
  }
  float qhr[16];
  #pragma unroll
  for (int j4 = 0; j4 < 16; j4 += 4){
    float4 a = *(const float4*)(query + base + j4);
    x[j4]=a.x+ds16[j4]; x[j4+1]=a.y+ds16[j4+1]; x[j4+2]=a.z+ds16[j4+2]; x[j4+3]=a.w+ds16[j4+3];
  }
  #pragma unroll
  for (int j = 0; j < 16; j++){
    float a = 0.f;
    #pragma unroll
    for (int i = 0; i < 16; i++) a += x[i]*wq[i][j];
    qhr[j] = a;
  }
  __syncthreads();   // ks/vs/msl complete

  float o0[16], o1[16];
  #pragma unroll
  for (int j = 0; j < 16; j++){ o0[j] = 0.f; o1[j] = 0.f; }
  for (int k = 0; k < N_; k += 2){
    {
      const float* krow = &ks[k][0];
      float4 a0 = *(const float4*)(krow);
      float4 a1 = *(const float4*)(krow+4);
      float4 a2 = *(const float4*)(krow+8);
      float4 a3 = *(const float4*)(krow+12);
      float d = a0.x*qhr[0]+a0.y*qhr[1]+a0.z*qhr[2]+a0.w*qhr[3]
              + a1.x*qhr[4]+a1.y*qhr[5]+a1.z*qhr[6]+a1.w*qhr[7]
              + a2.x*qhr[8]+a2.y*qhr[9]+a2.z*qhr[10]+a2.w*qhr[11]
              + a3.x*qhr[12]+a3.y*qhr[13]+a3.z*qhr[14]+a3.w*qhr[15];
      float2 ms0 = msl[k];
      float p = __expf(d*0.125f - ms0.x) * ms0.y;
      const float* vrow = &vs[k][0];
      float4 v0 = *(const float4*)(vrow);
      float4 v1 = *(const float4*)(vrow+4);
      float4 v2 = *(const float4*)(vrow+8);
      float4 v3 = *(const float4*)(vrow+12);
      o0[0]+=p*v0.x; o0[1]+=p*v0.y; o0[2]+=p*v0.z; o0[3]+=p*v0.w;
      o0[4]+=p*v1.x; o0[5]+=p*v1.y; o0[6]+=p*v1.z; o0[7]+=p*v1.w;
      o0[8]+=p*v2.x; o0[9]+=p*v2.y; o0[10]+=p*v2.z; o0[11]+=p*v2.w;
      o0[12]+=p*v3.x; o0[13]+=p*v3.y; o0[14]+=p*v3.z; o0[15]+=p*v3.w;
    }
    {
      const float* krow = &ks[k+1][0];
      float4 a0 = *(const float4*)(krow);
      float4 a1 = *(const float4*)(krow+4);
      float4 a2 = *(const float4*)(krow+8);
      float4 a3 = *(const float4*)(krow+12);
      float d = a0.x*qhr[0]+a0.y*qhr[1]+a0.z*qhr[2]+a0.w*qhr[3]
              + a1.x*qhr[4]+a1.y*qhr[5]+a1.z*qhr[6]+a1.w*qhr[7]
              + a2.x*qhr[8]+a2.y*qhr[9]+a2.z*qhr[10]+a2.w*qhr[11]
              + a3.x*qhr[12]+a3.y*qhr[13]+a3.z*qhr[14]+a3.w*qhr[15];
      float2 ms1 = msl[k+1];
      float p = __expf(d*0.125f - ms1.x) * ms1.y;
      const float* vrow = &vs[k+1][0];
      float4 v0 = *(const float4*)(vrow);
      float4 v1 = *(const float4*)(vrow+4);
      float4 v2 = *(const float4*)(vrow+8);
      float4 v3 = *(const float4*)(vrow+12);
      o1[0]+=p*v0.x; o1[1]+=p*v0.y; o1[2]+=p*v0.z; o1[3]+=p*v0.w;
      o1[4]+=p*v1.x; o1[5]+=p*v1.y; o1[6]+=p*v1.z; o1[7]+=p*v1.w;
      o1[8]+=p*v2.x; o1[9]+=p*v2.y; o1[10]+=p*v2.z; o1[11]+=p*v2.w;
      o1[12]+=p*v3.x; o1[13]+=p*v3.y; o1[14]+=p*v3.z; o1[15]+=p*v3.w;
    }
  }
  float* op = o_ws + base;
  #pragma unroll
  for (int j4 = 0; j4 < 16; j4 += 4)
    *(float4*)(op + j4) = make_float4(o0[j4]+o1[j4], o0[j4+1]+o1[j4+1],
                                      o0[j4+2]+o1[j4+2], o0[j4+3]+o1[j4+3]);
}

// ---------------- fused epilogue v3: bf16 LDS staging ----------------
__global__ __launch_bounds__(256)
void k_final(const float* __restrict__ query, const float* __restrict__ dsb,
             const float* __restrict__ o_ws, const float* __restrict__ xg_ws,
             const float* __restrict__ Wfc, const float* __restrict__ bfc,
             const float* __restrict__ ln1g, const float* __restrict__ ln1b,
             const float* __restrict__ ln2g, const float* __restrict__ ln2b,
             const float* __restrict__ Wff1, const float* __restrict__ bff1,
             const float* __restrict__ Wff2, const float* __restrict__ bff2,
             const float* __restrict__ Wfs, const float* __restrict__ bfs,
             const float* __restrict__ Wfg, const float* __restrict__ bfg,
             float* __restrict__ out)
{
  __shared__ u16 smA[64*66];                       // o_t -> us_t (bf16)
  __shared__ u16 smB[64*66];                       // qd_t -> ms_t (bf16)
  __shared__ union UH { u16 h[128*66]; float o[64*66]; } HH;  // hidden/xg (bf16) -> out_t (f32)
  __shared__ float lnxA[4][64];
  __shared__ float lnxB[4][64];

  const int tid = threadIdx.x;
  const int token0 = blockIdx.x * 64;
  const int w = rfl(tid >> 6);
  const int tok = tid & 63;
  const int c0 = w * 16;

  #pragma unroll
  for (int it = 0; it < 4; it++){
    int idx = tid + 256*it;
    int tk = idx >> 4, c4 = (idx & 15) * 4;
    int gtok = token0 + tk;
    int n = (gtok / T_) & (N_-1);
    float4 ov = *(const float4*)(o_ws + (size_t)gtok*C_ + c4);
    float4 qv = *(const float4*)(query + (size_t)gtok*C_ + c4);
    float4 dv = *(const float4*)(dsb + n*C_ + c4);
    smA[(c4+0)*66+tk] = f2bf(ov.x); smA[(c4+1)*66+tk] = f2bf(ov.y);
    smA[(c4+2)*66+tk] = f2bf(ov.z); smA[(c4+3)*66+tk] = f2bf(ov.w);
    smB[(c4+0)*66+tk] = f2bf(qv.x+dv.x); smB[(c4+1)*66+tk] = f2bf(qv.y+dv.y);
    smB[(c4+2)*66+tk] = f2bf(qv.z+dv.z); smB[(c4+3)*66+tk] = f2bf(qv.w+dv.w);
  }
  __syncthreads();

  // fc
  float x1[16];
  #pragma unroll
  for (int j = 0; j < 16; j++) x1[j] = 0.f;
  for (int i = 0; i < C_; i++){
    float ov = bf2f(smA[i*66 + tok]);
    const float* wrow = Wfc + i*C_ + c0;
    #pragma unroll
    for (int j = 0; j < 16; j++) x1[j] += ov * wrow[j];
  }
  #pragma unroll
  for (int j = 0; j < 16; j++) x1[j] += bfc[c0+j] + bf2f(smB[(c0+j)*66 + tok]);

  // LN1
  float s1 = 0.f;
  #pragma unroll
  for (int j = 0; j < 16; j++) s1 += x1[j];
  lnxA[w][tok] = s1;
  __syncthreads();
  float mu = (lnxA[0][tok]+lnxA[1][tok]+lnxA[2][tok]+lnxA[3][tok]) * (1.f/64.f);
  float v1 = 0.f;
  #pragma unroll
  for (int j = 0; j < 16; j++){ float d = x1[j]-mu; v1 += d*d; }
  lnxB[w][tok] = v1;
  __syncthreads();
  float var = (lnxB[0][tok]+lnxB[1][tok]+lnxB[2][tok]+lnxB[3][tok]) * (1.f/64.f);
  float rstd = rsqrtf(var + 1e-5f);
  float ms[16];
  #pragma unroll
  for (int j = 0; j < 16; j++) ms[j] = (x1[j]-mu)*rstd*ln1g[c0+j] + ln1b[c0+j];
  __syncthreads();
  #pragma unroll
  for (int j = 0; j < 16; j++) smB[(c0+j)*66 + tok] = f2bf(ms[j]);
  __syncthreads();

  // FFN
  float part[16];
  #pragma unroll
  for (int j = 0; j < 16; j++) part[j] = 0.f;
  #pragma unroll
  for (int ch = 0; ch < 2; ch++){
    float fch[32];
    #pragma unroll
    for (int kk = 0; kk < 32; kk++) fch[kk] = 0.f;
    const int kbase = w*64 + ch*32;
    for (int i = 0; i < C_; i++){
      float msv = bf2f(smB[i*66 + tok]);
      const float* wrow = Wff1 + i*(4*C_) + kbase;
      #pragma unroll
      for (int kk = 0; kk < 32; kk++) fch[kk] += msv * wrow[kk];
    }
    #pragma unroll
    for (int kk = 0; kk < 32; kk++){
      float v = fch[kk] + bff1[kbase+kk];
      fch[kk] = v > 0.f ? v : 0.f;
    }
    if (ch) __syncthreads();
    #pragma unroll
    for (int kk = 0; kk < 32; kk++) HH.h[(w*32+kk)*66 + tok] = f2bf(fch[kk]);
    __syncthreads();
    #pragma unroll
    for (int wq = 0; wq < 4; wq++){
      #pragma unroll 8
      for (int kk = 0; kk < 32; kk++){
        int k = wq*64 + ch*32 + kk;
        float hv = bf2f(HH.h[(wq*32+kk)*66 + tok]);
        const float* wrow = Wff2 + k*C_ + c0;
        #pragma unroll
        for (int j = 0; j < 16; j++) part[j] += hv * wrow[j];
      }
    }
  }
  float x2[16];
  #pragma unroll
  for (int j = 0; j < 16; j++) x2[j] = part[j] + bff2[c0+j] + ms[j];

  // LN2
  float s2 = 0.f;
  #pragma unroll
  for (int j = 0; j < 16; j++) s2 += x2[j];
  __syncthreads();
  lnxA[w][tok] = s2;
  __syncthreads();
  float mu2 = (lnxA[0][tok]+lnxA[1][tok]+lnxA[2][tok]+lnxA[3][tok]) * (1.f/64.f);
  float v2 = 0.f;
  #pragma unroll
  for (int j = 0; j < 16; j++){ float d = x2[j]-mu2; v2 += d*d; }
  lnxB[w][tok] = v2;
  __syncthreads();
  float var2 = (lnxB[0][tok]+lnxB[1][tok]+lnxB[2][tok]+lnxB[3][tok]) * (1.f/64.f);
  float rstd2 = rsqrtf(var2 + 1e-5f);
  float us[16];
  #pragma unroll
  for (int j = 0; j < 16; j++) us[j] = (x2[j]-mu2)*rstd2*ln2g[c0+j] + ln2b[c0+j];

  // us -> smA ; xg -> HH.h rows 0..63 (hidden dead)
  #pragma unroll
  for (int j = 0; j < 16; j++) smA[(c0+j)*66 + tok] = f2bf(us[j]);
  #pragma unroll
  for (int it = 0; it < 4; it++){
    int idx = tid + 256*it;
    int tk = idx >> 4, c4 = (idx & 15) * 4;
    int gtok = token0 + tk;
    float4 xv = *(const float4*)(xg_ws + (size_t)gtok*C_ + c4);
    HH.h[(c4+0)*66+tk] = f2bf(xv.x); HH.h[(c4+1)*66+tk] = f2bf(xv.y);
    HH.h[(c4+2)*66+tk] = f2bf(xv.z); HH.h[(c4+3)*66+tk] = f2bf(xv.w);
  }
  __syncthreads();

  // gate
  float ga[16];
  #pragma unroll
  for (int j = 0; j < 16; j++) ga[j] = 0.f;
  for (int i = 0; i < C_; i++){
    float uv = bf2f(smA[i*66 + tok]);
    float xv = bf2f(HH.h[i*66 + tok]);
    const float* wsr = Wfs + i*C_ + c0;
    const float* wgr = Wfg + i*C_ + c0;
    #pragma unroll
    for (int j = 0; j < 16; j++) ga[j] += uv*wsr[j] + xv*wgr[j];
  }
  float res[16];
  #pragma unroll
  for (int j = 0; j < 16; j++){
    float a = ga[j] + bfs[c0+j] + bfg[c0+j];
    float gg = 1.f / (1.f + __expf(-a));
    float xgv = bf2f(HH.h[(c0+j)*66 + tok]);
    res[j] = gg*us[j] + (1.f-gg)*xgv;
  }
  __syncthreads();   // all xg reads done before f32 reuse of HH
  #pragma unroll
  for (int j = 0; j < 16; j++) HH.o[(c0+j)*66 + tok] = res[j];
  __syncthreads();
  #pragma unroll
  for (int it = 0; it < 4; it++){
    int idx = tid + 256*it;
    int tk = idx >> 4, c4 = (idx & 15) * 4;
    int gtok = token0 + tk;
    float4 v = make_float4(HH.o[(c4+0)*66+tk], HH.o[(c4+1)*66+tk],
                           HH.o[(c4+2)*66+tk], HH.o[(c4+3)*66+tk]);
    *(float4*)(out + (size_t)gtok*C_ + c4) = v;
  }
}

extern "C" void kernel_launch(void* const* d_in, const int* in_sizes, int n_in,
                              void* d_out, int out_size, void* d_ws, size_t ws_size,
                              hipStream_t stream)
{
  (void)in_sizes; (void)n_in; (void)out_size; (void)ws_size;
  const float* query = (const float*)d_in[0];
  const float* key   = (const float*)d_in[1];
  const float* value = (const float*)d_in[2];
  const float* DSm   = (const float*)d_in[4];
  const float* Wemb  = (const float*)d_in[5];
  const float* bemb  = (const float*)d_in[6];
  const float* Wq    = (const float*)d_in[7];
  const float* Wk    = (const float*)d_in[8];
  const float* Wv    = (const float*)d_in[9];
  const float* Wfc   = (const float*)d_in[10];
  const float* bfc   = (const float*)d_in[11];
  const float* ln1g  = (const float*)d_in[12];
  const float* ln1b  = (const float*)d_in[13];
  const float* ln2g  = (const float*)d_in[14];
  const float* ln2b  = (const float*)d_in[15];
  const float* Wff1  = (const float*)d_in[16];
  const float* bff1  = (const float*)d_in[17];
  const float* Wff2  = (const float*)d_in[18];
  const float* bff2  = (const float*)d_in[19];
  const float* g1W   = (const float*)d_in[20];
  const float* g1as  = (const float*)d_in[21];
  const float* g1ad  = (const float*)d_in[22];
  const float* g1b   = (const float*)d_in[23];
  const float* g2W   = (const float*)d_in[24];
  const float* g2as  = (const float*)d_in[25];
  const float* g2ad  = (const float*)d_in[26];
  const float* g2b   = (const float*)d_in[27];
  const float* jkW   = (const float*)d_in[28];
  const float* jkb   = (const float*)d_in[29];
  const float* Wfs   = (const float*)d_in[30];
  const float* bfs   = (const float*)d_in[31];
  const float* Wfg   = (const float*)d_in[32];
  const float* bfg   = (const float*)d_in[33];
  const int* ei      = (const int*)d_in[34];
  float* out = (float*)d_out;

  float* wf     = (float*)d_ws;
  float* dsb    = wf + DS_OFF;
  float* xg_ws  = wf + XG_OFF;
  u16*   hA     = (u16*)(wf + HA_OFF);
  u16*   hB     = (u16*)(wf + HB_OFF);
  float* o_ws   = wf + HA_OFF;             // aliases hA (dead before k_av)
  float* hs_ws  = wf + HS_OFF;
  float* hd_ws  = wf + HD_OFF;
  int*   indptr = (int*)(wf + INT_OFF);
  int*   srcs   = indptr + 260;
  float* mS     = wf + MS_OFF;

  k_pre  <<<dim3(641),  dim3(256), 0, stream>>>(query, g1W, g1as, g1ad, hA, hs_ws, hd_ws,
                                                DSm, Wemb, bemb, dsb, ei, indptr, srcs);
  k_agg1 <<<dim3(576),  dim3(256), 0, stream>>>(hA, hs_ws, hd_ws, indptr, srcs, g1b, hB);
  k_lin2 <<<dim3(576),  dim3(256), 0, stream>>>(hB, g2W, g2as, g2ad, hA, hs_ws, hd_ws);
  k_aggjk<<<dim3(1152), dim3(256), 0, stream>>>(hA, hs_ws, hd_ws, indptr, srcs, g2b, hB,
                                                jkW, jkb, xg_ws,
                                                query, key, Wq, Wk, dsb, mS);
  k_av   <<<dim3(576),  dim3(256), 0, stream>>>(query, key, value, Wq, Wk, Wv, dsb, mS, o_ws);
  k_final<<<dim3(576),  dim3(256), 0, stream>>>(query, dsb, o_ws, xg_ws,
      Wfc, bfc, ln1g, ln1b, ln2g, ln2b,
      Wff1, bff1, Wff2, bff2,
      Wfs, bfs, Wfg, bfg, out);
}

// Round 11
// 279.835 us; speedup vs baseline: 1.5545x; 1.0884x over previous
//
#include <hip/hip_runtime.h>

typedef unsigned short u16;
typedef unsigned int u32;

#define B_ 4
#define N_ 256
#define T_ 36
#define C_ 64
#define H_ 4
#define D_ 16
#define CH_ 128
#define E_ 4096
#define EQ_ 1408   // per-quarter edge cap (mean 1024, sigma ~28 -> +14 sigma)
#define G_ (B_*T_)
#define TOK_ (B_*N_*T_)

// workspace layout (float offsets)
#define DS_OFF  0
#define XG_OFF  (DS_OFF + N_*C_)
#define HA_OFF  (XG_OFF + TOK_*C_)          // bf16 h buffer A (conv outs)
#define HB_OFF  (HA_OFF + G_*N_*CH_/2)      // bf16 buffer B (h1)
#define HS_OFF  (HB_OFF + G_*N_*CH_/2)
#define HD_OFF  (HS_OFF + G_*N_)
#define INT_OFF (HD_OFF + G_*N_)
#define MS_OFF  (INT_OFF + 4608)            // (m, 1/S) pairs: 576 * 512 floats
#define O_SEP_OFF (MS_OFF + 576*512)        // separate o_ws region (if ws permits)

__device__ __forceinline__ float bf2f(u16 u){
  u32 x = ((u32)u) << 16;
  return __builtin_bit_cast(float, x);
}
__device__ __forceinline__ u16 f2bf(float f){
  u32 x = __builtin_bit_cast(u32, f);
  x += 0x7fffu + ((x >> 16) & 1u);
  return (u16)(x >> 16);
}
__device__ __forceinline__ void unpack8(uint4 u, float* f){
  f[0]=bf2f((u16)(u.x & 0xffffu)); f[1]=bf2f((u16)(u.x >> 16));
  f[2]=bf2f((u16)(u.y & 0xffffu)); f[3]=bf2f((u16)(u.y >> 16));
  f[4]=bf2f((u16)(u.z & 0xffffu)); f[5]=bf2f((u16)(u.z >> 16));
  f[6]=bf2f((u16)(u.w & 0xffffu)); f[7]=bf2f((u16)(u.w >> 16));
}
__device__ __forceinline__ uint4 pack8f(const float* f){
  uint4 u;
  u.x = (u32)f2bf(f[0]) | ((u32)f2bf(f[1]) << 16);
  u.y = (u32)f2bf(f[2]) | ((u32)f2bf(f[3]) << 16);
  u.z = (u32)f2bf(f[4]) | ((u32)f2bf(f[5]) << 16);
  u.w = (u32)f2bf(f[6]) | ((u32)f2bf(f[7]) << 16);
  return u;
}
__device__ __forceinline__ int rfl(int v){ return __builtin_amdgcn_readfirstlane(v); }

// XCD swizzle: all 4 quarter-blocks of graph g share bid%8 == g%8 (same XCD L2)
__device__ __forceinline__ void gq_from_bid(int bid, int& g, int& q){
  int xc = bid & 7, slot = bid >> 3;
  q = slot & 3;
  g = xc + ((slot >> 2) << 3);
}

#define SP_ 20   // f32 attn row pitch (80B, 16B-aligned)

// parallel per-dst edge softmax: 4 threads per dst (slices mod 4), shfl-combined.
__device__ __forceinline__ void edge_softmax_par(int tid, int n0,
    const int* __restrict__ indptr, int p00,
    const int* srcs_l, const float* hs_l, const float* __restrict__ hd_ws,
    int g, float* alpha_l)
{
  const int ld = tid >> 2;
  const int sl = tid & 3;
  const int dst = n0 + ld;
  const int p0 = indptr[dst] - p00, p1 = indptr[dst+1] - p00;
  const float hdn = hd_ws[g*N_ + dst];
  float m = -1e30f;
  for (int j = p0 + sl; j < p1; j += 4){
    float e = hs_l[srcs_l[j]] + hdn;
    e = e > 0.f ? e : 0.2f * e;
    alpha_l[j] = e;
    m = fmaxf(m, e);
  }
  m = fmaxf(m, __shfl_xor(m, 1, 64));
  m = fmaxf(m, __shfl_xor(m, 2, 64));
  float s = 0.f;
  for (int j = p0 + sl; j < p1; j += 4){
    float w = __expf(alpha_l[j] - m);
    alpha_l[j] = w; s += w;
  }
  s += __shfl_xor(s, 1, 64);
  s += __shfl_xor(s, 2, 64);
  float inv = 1.f / (s + 1e-16f);
  for (int j = p0 + sl; j < p1; j += 4) alpha_l[j] *= inv;
}

// ---------------- fused pre: lin1 (576) + ds (64) + csr (1) ----------------
__global__ __launch_bounds__(256)
void k_pre(const float* __restrict__ query, const float* __restrict__ W1,
           const float* __restrict__ as1, const float* __restrict__ ad1,
           u16* __restrict__ h, float* __restrict__ hs_ws, float* __restrict__ hd_ws,
           const float* __restrict__ DSm, const float* __restrict__ Wemb,
           const float* __restrict__ bemb, float* __restrict__ dsb,
           const int* __restrict__ ei, int* __restrict__ indptr, int* __restrict__ srcs)
{
  __shared__ union UP {
    struct { float xs[64][65]; float red[2][4][64]; } lin;
    struct { int srcL[E_]; int dstL[E_]; int tmp[E_]; int cnt[N_]; int base[N_+1]; } c;
  } S;
  const int bid = blockIdx.x;
  const int tid = threadIdx.x;

  if (bid < 576){
    int g, q; gq_from_bid(bid, g, q);
    const int n0 = q * 64;
    const int b = g / T_, t = g % T_;
    {
      const size_t gb = (((size_t)b*N_ + n0)*T_ + t)*C_;
      #pragma unroll
      for (int it = 0; it < 4; it++){
        int idx = tid + 256*it;
        int row = idx >> 4, c4 = (idx & 15) * 4;
        float4 v = *(const float4*)(query + gb + (size_t)row*(T_*C_) + c4);
        S.lin.xs[row][c4+0] = v.x; S.lin.xs[row][c4+1] = v.y;
        S.lin.xs[row][c4+2] = v.z; S.lin.xs[row][c4+3] = v.w;
      }
    }
    __syncthreads();

    const int r = tid & 63;
    const int cb = rfl(tid >> 6);
    const int ch0 = cb * 32;

    float acc[32];
    #pragma unroll
    for (int j = 0; j < 32; j++) acc[j] = 0.f;
    for (int k = 0; k < 64; k++){
      float xv = S.lin.xs[r][k];
      const float* wrow = W1 + k*CH_ + ch0;   // wave-uniform -> scalar loads
      #pragma unroll
      for (int j = 0; j < 32; j++) acc[j] += xv * wrow[j];
    }
    float hs = 0.f, hd = 0.f;
    #pragma unroll
    for (int j = 0; j < 32; j++){ hs += acc[j]*as1[ch0+j]; hd += acc[j]*ad1[ch0+j]; }
    S.lin.red[0][cb][r] = hs; S.lin.red[1][cb][r] = hd;

    u16* hp = h + ((size_t)(g*N_ + n0 + r))*CH_ + ch0;
    #pragma unroll
    for (int j8 = 0; j8 < 32; j8 += 8)
      *(uint4*)(hp + j8) = pack8f(&acc[j8]);

    __syncthreads();
    if (tid < 64){
      float a = S.lin.red[0][0][tid]+S.lin.red[0][1][tid]+S.lin.red[0][2][tid]+S.lin.red[0][3][tid];
      float d = S.lin.red[1][0][tid]+S.lin.red[1][1][tid]+S.lin.red[1][2][tid]+S.lin.red[1][3][tid];
      hs_ws[g*N_ + n0 + tid] = a;
      hd_ws[g*N_ + n0 + tid] = d;
    }
  } else if (bid < 640){
    const int n = (bid - 576) * 4 + (tid >> 6);   // wave-uniform
    const int c = tid & 63;
    float acc = bemb[c];
    for (int m = 0; m < N_; m++) acc += DSm[n*N_ + m] * Wemb[m*C_ + c];
    dsb[n*C_ + c] = acc;
  } else {
    for (int e = tid; e < E_; e += 256){ S.c.srcL[e] = ei[e]; S.c.dstL[e] = ei[E_ + e]; }
    S.c.cnt[tid] = 0;
    __syncthreads();
    for (int e = tid; e < E_; e += 256) atomicAdd(&S.c.cnt[S.c.dstL[e]], 1);
    __syncthreads();
    if (tid == 0){
      int run = 0;
      for (int i = 0; i < N_; i++){ S.c.base[i] = run; run += S.c.cnt[i]; }
      S.c.base[N_] = run;
    }
    __syncthreads();
    S.c.cnt[tid] = 0;
    __syncthreads();
    for (int e = tid; e < E_; e += 256){
      int d = S.c.dstL[e];
      int p = atomicAdd(&S.c.cnt[d], 1);
      S.c.tmp[S.c.base[d] + p] = e;
    }
    __syncthreads();
    {
      const int p0 = S.c.base[tid], p1 = S.c.base[tid] + S.c.cnt[tid];
      for (int i = p0 + 1; i < p1; i++){      // insertion sort by edge id -> deterministic
        int v = S.c.tmp[i]; int j = i - 1;
        while (j >= p0 && S.c.tmp[j] > v){ S.c.tmp[j+1] = S.c.tmp[j]; j--; }
        S.c.tmp[j+1] = v;
      }
      for (int j = p0; j < p1; j++) srcs[j] = S.c.srcL[S.c.tmp[j]];
    }
    indptr[tid] = S.c.base[tid];
    if (tid == 0) indptr[N_] = S.c.base[N_];
  }
}

// ---------------- K2: agg1 (blocks 0..575) ∥ attn stats (576..1151) ----------------
__global__ __launch_bounds__(256)
void k_agg1stat(const u16* __restrict__ hin, const float* __restrict__ hs_ws, const float* __restrict__ hd_ws,
                const int* __restrict__ indptr, const int* __restrict__ srcs,
                const float* __restrict__ bias, u16* __restrict__ hout,
                const float* __restrict__ query, const float* __restrict__ key,
                const float* __restrict__ Wq, const float* __restrict__ Wk,
                const float* __restrict__ dsb, float* __restrict__ mS)
{
  __shared__ union UA {
    struct { int srcs_l[EQ_]; float alpha_l[EQ_]; float hs_l[N_]; } a;
    struct { float qs[N_][SP_]; float wq[16][16]; float wk[16][16]; } s;
  } U;
  const int bid = blockIdx.x;
  const int tid = threadIdx.x;

  if (bid < 576){
    int g, q; gq_from_bid(bid, g, q);
    const int n0 = q * 64;

    const int p00 = indptr[n0];
    const int pend = indptr[n0 + 64];
    const int cntE = pend - p00;
    for (int i = tid; i < cntE; i += 256) U.a.srcs_l[i] = srcs[p00 + i];
    U.a.hs_l[tid] = hs_ws[g*N_ + tid];
    __syncthreads();

    edge_softmax_par(tid, n0, indptr, p00, U.a.srcs_l, U.a.hs_l, hd_ws, g, U.a.alpha_l);
    __syncthreads();

    const int r = tid & 63;
    const int cb = rfl(tid >> 6);
    const int ch0 = cb * 32;
    const int dst = n0 + r;
    const int p0 = indptr[dst] - p00, p1 = indptr[dst+1] - p00;

    float acc[32];
    #pragma unroll
    for (int j = 0; j < 32; j++) acc[j] = 0.f;
    for (int j = p0; j < p1; j++){
      float a = U.a.alpha_l[j];
      int s = U.a.srcs_l[j];
      const uint4* hp = (const uint4*)(hin + ((size_t)(g*N_ + s))*CH_ + ch0);
      #pragma unroll
      for (int qq = 0; qq < 4; qq++){
        float hv[8]; unpack8(hp[qq], hv);
        #pragma unroll
        for (int i = 0; i < 8; i++) acc[qq*8+i] += a * hv[i];
      }
    }
    float o[32];
    #pragma unroll
    for (int j = 0; j < 32; j++){
      float v = acc[j] + bias[ch0+j];
      o[j] = v > 0.f ? v : 0.f;
    }
    u16* op = hout + ((size_t)(g*N_ + dst))*CH_ + ch0;
    #pragma unroll
    for (int j8 = 0; j8 < 32; j8 += 8)
      *(uint4*)(op + j8) = pack8f(&o[j8]);
  } else {
    // attn stats: per (b,t,h), thread = column k; (m, 1/S) over q axis
    const int sb = bid - 576;
    const int b = sb / (T_*H_);
    const int rem = sb % (T_*H_);
    const int t = rem / H_;
    const int h = rem % H_;
    const int n = tid;

    U.s.wq[n>>4][n&15] = Wq[n];
    U.s.wk[n>>4][n&15] = Wk[n];

    const size_t base = ((((size_t)b*N_ + n)*T_) + t)*C_ + h*D_;
    const float* dsp = dsb + n*C_ + h*D_;

    float x[16];
    #pragma unroll
    for (int j4 = 0; j4 < 16; j4 += 4){
      float4 a = *(const float4*)(query + base + j4);
      float4 d = *(const float4*)(dsp + j4);
      x[j4]=a.x+d.x; x[j4+1]=a.y+d.y; x[j4+2]=a.z+d.z; x[j4+3]=a.w+d.w;
    }
    __syncthreads();   // weights staged
    #pragma unroll
    for (int j = 0; j < 16; j++){
      float a = 0.f;
      #pragma unroll
      for (int i = 0; i < 16; i++) a += x[i]*U.s.wq[i][j];
      U.s.qs[n][j] = a;
    }
    float khr[16];
    #pragma unroll
    for (int j4 = 0; j4 < 16; j4 += 4){
      float4 a = *(const float4*)(key + base + j4);
      float4 d = *(const float4*)(dsp + j4);
      x[j4]=a.x+d.x; x[j4+1]=a.y+d.y; x[j4+2]=a.z+d.z; x[j4+3]=a.w+d.w;
    }
    #pragma unroll
    for (int j = 0; j < 16; j++){
      float a = 0.f;
      #pragma unroll
      for (int i = 0; i < 16; i++) a += x[i]*U.s.wk[i][j];
      khr[j] = a;
    }
    __syncthreads();   // qs complete

    float m[4], s[4];
    #pragma unroll
    for (int c = 0; c < 4; c++){ m[c] = -1e30f; s[c] = 0.f; }
    for (int qq = 0; qq < 64; qq++){
      #pragma unroll
      for (int c = 0; c < 4; c++){
        const float* qrow = &U.s.qs[qq + 64*c][0];
        float4 a0 = *(const float4*)(qrow);
        float4 a1 = *(const float4*)(qrow+4);
        float4 a2 = *(const float4*)(qrow+8);
        float4 a3 = *(const float4*)(qrow+12);
        float d = a0.x*khr[0]+a0.y*khr[1]+a0.z*khr[2]+a0.w*khr[3]
                + a1.x*khr[4]+a1.y*khr[5]+a1.z*khr[6]+a1.w*khr[7]
                + a2.x*khr[8]+a2.y*khr[9]+a2.z*khr[10]+a2.w*khr[11]
                + a3.x*khr[12]+a3.y*khr[13]+a3.z*khr[14]+a3.w*khr[15];
        d *= 0.125f;
        float mn = fmaxf(m[c], d);
        s[c] = s[c]*__expf(m[c]-mn) + __expf(d-mn);
        m[c] = mn;
      }
    }
    float M = fmaxf(fmaxf(m[0],m[1]), fmaxf(m[2],m[3]));
    float S = s[0]*__expf(m[0]-M) + s[1]*__expf(m[1]-M)
            + s[2]*__expf(m[2]-M) + s[3]*__expf(m[3]-M);
    mS[(size_t)sb*512 + n*2]     = M;
    mS[(size_t)sb*512 + n*2 + 1] = 1.f / S;
  }
}

// ---------------- lin2: h2 = bf16(h1 @ W2), fused hs2/hd2 ----------------
__global__ __launch_bounds__(256)
void k_lin2(const u16* __restrict__ h1, const float* __restrict__ W2,
            const float* __restrict__ as2, const float* __restrict__ ad2,
            u16* __restrict__ h2, float* __restrict__ hs_ws, float* __restrict__ hd_ws)
{
  __shared__ float xs[64][129];
  __shared__ float red[2][4][64];
  const int bid = blockIdx.x;
  int g, q; gq_from_bid(bid, g, q);
  const int n0 = q * 64;
  const int tid = threadIdx.x;

  {
    #pragma unroll
    for (int it = 0; it < 4; it++){
      int idx = tid + 256*it;
      int row = idx >> 4, c8 = (idx & 15) * 8;
      uint4 u = *(const uint4*)(h1 + ((size_t)(g*N_ + n0 + row))*CH_ + c8);
      float v[8]; unpack8(u, v);
      #pragma unroll
      for (int i = 0; i < 8; i++) xs[row][c8+i] = v[i];
    }
  }
  __syncthreads();

  const int r = tid & 63;
  const int cb = rfl(tid >> 6);
  const int ch0 = cb * 32;

  float acc[32];
  #pragma unroll
  for (int j = 0; j < 32; j++) acc[j] = 0.f;
  for (int k = 0; k < 128; k++){
    float xv = xs[r][k];
    const float* wrow = W2 + k*CH_ + ch0;
    #pragma unroll
    for (int j = 0; j < 32; j++) acc[j] += xv * wrow[j];
  }
  float hs = 0.f, hd = 0.f;
  #pragma unroll
  for (int j = 0; j < 32; j++){ hs += acc[j]*as2[ch0+j]; hd += acc[j]*ad2[ch0+j]; }
  red[0][cb][r] = hs; red[1][cb][r] = hd;

  u16* hp = h2 + ((size_t)(g*N_ + n0 + r))*CH_ + ch0;
  #pragma unroll
  for (int j8 = 0; j8 < 32; j8 += 8)
    *(uint4*)(hp + j8) = pack8f(&acc[j8]);

  __syncthreads();
  if (tid < 64){
    float a = red[0][0][tid]+red[0][1][tid]+red[0][2][tid]+red[0][3][tid];
    float d = red[1][0][tid]+red[1][1][tid]+red[1][2][tid]+red[1][3][tid];
    hs_ws[g*N_ + n0 + tid] = a;
    hd_ws[g*N_ + n0 + tid] = d;
  }
}

// ---------------- K4: agg2+jk (eff 0..575) ∥ attn AV (eff 576..1151) ----------------
__global__ __launch_bounds__(256)
void k_agg2av(const u16* __restrict__ h2, const float* __restrict__ hs_ws, const float* __restrict__ hd_ws,
              const int* __restrict__ indptr, const int* __restrict__ srcs,
              const float* __restrict__ b2, const u16* __restrict__ h1,
              const float* __restrict__ jkW, const float* __restrict__ jkb, float* __restrict__ xg,
              const float* __restrict__ query, const float* __restrict__ key, const float* __restrict__ value,
              const float* __restrict__ Wq, const float* __restrict__ Wk, const float* __restrict__ Wv,
              const float* __restrict__ dsb, const float* __restrict__ mS, float* __restrict__ o_ws,
              int bid_base)
{
  __shared__ union UJ {
    struct { int srcs_l[EQ_]; float alpha_l[EQ_]; float hs_l[N_]; } a;
    struct { u16 xs[64][136]; } l;
    struct { float ks[N_][SP_]; float vs[N_][SP_]; float2 msl[N_];
             float wq[16][16]; float wk[16][16]; float wv[16][16]; } v;
  } U;
  const int bid = blockIdx.x + bid_base;
  const int tid = threadIdx.x;

  if (bid < 576){
    int g, q; gq_from_bid(bid, g, q);
    const int n0 = q * 64;
    const int b = g / T_, t = g % T_;

    // ---- agg2 (output stays in regs) ----
    const int p00 = indptr[n0];
    const int pend = indptr[n0 + 64];
    const int cntE = pend - p00;
    for (int i = tid; i < cntE; i += 256) U.a.srcs_l[i] = srcs[p00 + i];
    U.a.hs_l[tid] = hs_ws[g*N_ + tid];
    __syncthreads();

    edge_softmax_par(tid, n0, indptr, p00, U.a.srcs_l, U.a.hs_l, hd_ws, g, U.a.alpha_l);
    __syncthreads();

    const int r = tid & 63;
    const int cb = rfl(tid >> 6);
    const int ch0 = cb * 32;
    const int dst = n0 + r;
    const int p0 = indptr[dst] - p00, p1 = indptr[dst+1] - p00;

    float acc[32];
    #pragma unroll
    for (int j = 0; j < 32; j++) acc[j] = 0.f;
    for (int j = p0; j < p1; j++){
      float a = U.a.alpha_l[j];
      int s = U.a.srcs_l[j];
      const uint4* hp = (const uint4*)(h2 + ((size_t)(g*N_ + s))*CH_ + ch0);
      #pragma unroll
      for (int qq = 0; qq < 4; qq++){
        float hv[8]; unpack8(hp[qq], hv);
        #pragma unroll
        for (int i = 0; i < 8; i++) acc[qq*8+i] += a * hv[i];
      }
    }
    float o[32];
    {
      const uint4* h1p = (const uint4*)(h1 + ((size_t)(g*N_ + dst))*CH_ + ch0);
      #pragma unroll
      for (int j8 = 0; j8 < 32; j8 += 8){
        float h1v[8]; unpack8(h1p[j8>>3], h1v);
        #pragma unroll
        for (int i = 0; i < 8; i++){
          float v = acc[j8+i] + b2[ch0+j8+i];
          v = v > 0.f ? v : 0.f;
          o[j8+i] = fmaxf(h1v[i], v);
        }
      }
    }
    __syncthreads();   // all agg reads of U.a done

    // regs -> xs (bf16)
    #pragma unroll
    for (int j8 = 0; j8 < 32; j8 += 8)
      *(uint4*)&U.l.xs[r][ch0 + j8] = pack8f(&o[j8]);
    __syncthreads();

    // jk linear: xg(time-reversed) = xs @ jkW + jkb
    const int o0 = cb * 16;
    float acc2[16];
    #pragma unroll
    for (int j = 0; j < 16; j++) acc2[j] = 0.f;
    for (int k8 = 0; k8 < 16; k8++){
      uint4 u = *(const uint4*)&U.l.xs[r][k8*8];
      float hv[8]; unpack8(u, hv);
      #pragma unroll
      for (int kk = 0; kk < 8; kk++){
        const float* wrow = jkW + (k8*8+kk)*C_ + o0;
        #pragma unroll
        for (int j = 0; j < 16; j++) acc2[j] += hv[kk] * wrow[j];
      }
    }
    float* op = xg + ((((size_t)b*N_ + n0 + r)*T_) + (T_-1-t))*C_ + o0;
    #pragma unroll
    for (int j4 = 0; j4 < 16; j4 += 4){
      float4 v = make_float4(acc2[j4]+jkb[o0+j4], acc2[j4+1]+jkb[o0+j4+1],
                             acc2[j4+2]+jkb[o0+j4+2], acc2[j4+3]+jkb[o0+j4+3]);
      *(float4*)(op + j4) = v;
    }
  } else {
    // ---- attn AV: per (b,t,h), thread = row q; stats precomputed ----
    const int sb = bid - 576;
    const int b = sb / (T_*H_);
    const int rem = sb % (T_*H_);
    const int t = rem / H_;
    const int h = rem % H_;
    const int n = tid;

    U.v.wq[n>>4][n&15] = Wq[n];
    U.v.wk[n>>4][n&15] = Wk[n];
    U.v.wv[n>>4][n&15] = Wv[n];
    U.v.msl[n] = *(const float2*)(mS + (size_t)sb*512 + n*2);

    const size_t base = ((((size_t)b*N_ + n)*T_) + t)*C_ + h*D_;
    const float* dsp = dsb + n*C_ + h*D_;

    float ds16[16];
    #pragma unroll
    for (int j4 = 0; j4 < 16; j4 += 4){
      float4 d = *(const float4*)(dsp + j4);
      ds16[j4]=d.x; ds16[j4+1]=d.y; ds16[j4+2]=d.z; ds16[j4+3]=d.w;
    }
    __syncthreads();   // weights staged

    float x[16];
    #pragma unroll
    for (int j4 = 0; j4 < 16; j4 += 4){
      float4 a = *(const float4*)(key + base + j4);
      x[j4]=a.x+ds16[j4]; x[j4+1]=a.y+ds16[j4+1]; x[j4+2]=a.z+ds16[j4+2]; x[j4+3]=a.w+ds16[j4+3];
    }
    #pragma unroll
    for (int j = 0; j < 16; j++){
      float a = 0.f;
      #pragma unroll
      for (int i = 0; i < 16; i++) a += x[i]*U.v.wk[i][j];
      U.v.ks[n][j] = a;
    }
    #pragma unroll
    for (int j4 = 0; j4 < 16; j4 += 4){
      float4 a = *(const float4*)(value + base + j4);
      x[j4]=a.x+ds16[j4]; x[j4+1]=a.y+ds16[j4+1]; x[j4+2]=a.z+ds16[j4+2]; x[j4+3]=a.w+ds16[j4+3];
    }
    #pragma unroll
    for (int j = 0; j < 16; j++){
      float a = 0.f;
      #pragma unroll
      for (int i = 0; i < 16; i++) a += x[i]*U.v.wv[i][j];
      U.v.vs[n][j] = a;
    }
    float qhr[16];
    #pragma unroll
    for (int j4 = 0; j4 < 16; j4 += 4){
      float4 a = *(const float4*)(query + base + j4);
      x[j4]=a.x+ds16[j4]; x[j4+1]=a.y+ds16[j4+1]; x[j4+2]=a.z+ds16[j4+2]; x[j4+3]=a.w+ds16[j4+3];
    }
    #pragma unroll
    for (int j = 0; j < 16; j++){
      float a = 0.f;
      #pragma unroll
      for (int i = 0; i < 16; i++) a += x[i]*U.v.wq[i][j];
      qhr[j] = a;
    }
    __syncthreads();   // ks/vs/msl complete

    float o0[16], o1[16];
    #pragma unroll
    for (int j = 0; j < 16; j++){ o0[j] = 0.f; o1[j] = 0.f; }
    for (int k = 0; k < N_; k += 2){
      {
        const float* krow = &U.v.ks[k][0];
        float4 a0 = *(const float4*)(krow);
        float4 a1 = *(const float4*)(krow+4);
        float4 a2 = *(const float4*)(krow+8);
        float4 a3 = *(const float4*)(krow+12);
        float d = a0.x*qhr[0]+a0.y*qhr[1]+a0.z*qhr[2]+a0.w*qhr[3]
                + a1.x*qhr[4]+a1.y*qhr[5]+a1.z*qhr[6]+a1.w*qhr[7]
                + a2.x*qhr[8]+a2.y*qhr[9]+a2.z*qhr[10]+a2.w*qhr[11]
                + a3.x*qhr[12]+a3.y*qhr[13]+a3.z*qhr[14]+a3.w*qhr[15];
        float2 ms0 = U.v.msl[k];
        float p = __expf(d*0.125f - ms0.x) * ms0.y;
        const float* vrow = &U.v.vs[k][0];
        float4 v0 = *(const float4*)(vrow);
        float4 v1 = *(const float4*)(vrow+4);
        float4 v2 = *(const float4*)(vrow+8);
        float4 v3 = *(const float4*)(vrow+12);
        o0[0]+=p*v0.x; o0[1]+=p*v0.y; o0[2]+=p*v0.z; o0[3]+=p*v0.w;
        o0[4]+=p*v1.x; o0[5]+=p*v1.y; o0[6]+=p*v1.z; o0[7]+=p*v1.w;
        o0[8]+=p*v2.x; o0[9]+=p*v2.y; o0[10]+=p*v2.z; o0[11]+=p*v2.w;
        o0[12]+=p*v3.x; o0[13]+=p*v3.y; o0[14]+=p*v3.z; o0[15]+=p*v3.w;
      }
      {
        const float* krow = &U.v.ks[k+1][0];
        float4 a0 = *(const float4*)(krow);
        float4 a1 = *(const float4*)(krow+4);
        float4 a2 = *(const float4*)(krow+8);
        float4 a3 = *(const float4*)(krow+12);
        float d = a0.x*qhr[0]+a0.y*qhr[1]+a0.z*qhr[2]+a0.w*qhr[3]
                + a1.x*qhr[4]+a1.y*qhr[5]+a1.z*qhr[6]+a1.w*qhr[7]
                + a2.x*qhr[8]+a2.y*qhr[9]+a2.z*qhr[10]+a2.w*qhr[11]
                + a3.x*qhr[12]+a3.y*qhr[13]+a3.z*qhr[14]+a3.w*qhr[15];
        float2 ms1 = U.v.msl[k+1];
        float p = __expf(d*0.125f - ms1.x) * ms1.y;
        const float* vrow = &U.v.vs[k+1][0];
        float4 v0 = *(const float4*)(vrow);
        float4 v1 = *(const float4*)(vrow+4);
        float4 v2 = *(const float4*)(vrow+8);
        float4 v3 = *(const float4*)(vrow+12);
        o1[0]+=p*v0.x; o1[1]+=p*v0.y; o1[2]+=p*v0.z; o1[3]+=p*v0.w;
        o1[4]+=p*v1.x; o1[5]+=p*v1.y; o1[6]+=p*v1.z; o1[7]+=p*v1.w;
        o1[8]+=p*v2.x; o1[9]+=p*v2.y; o1[10]+=p*v2.z; o1[11]+=p*v2.w;
        o1[12]+=p*v3.x; o1[13]+=p*v3.y; o1[14]+=p*v3.z; o1[15]+=p*v3.w;
      }
    }
    float* op = o_ws + base;
    #pragma unroll
    for (int j4 = 0; j4 < 16; j4 += 4)
      *(float4*)(op + j4) = make_float4(o0[j4]+o1[j4], o0[j4+1]+o1[j4+1],
                                        o0[j4+2]+o1[j4+2], o0[j4+3]+o1[j4+3]);
  }
}

// ---------------- fused epilogue: bf16 LDS staging ----------------
__global__ __launch_bounds__(256)
void k_final(const float* __restrict__ query, const float* __restrict__ dsb,
             const float* __restrict__ o_ws, const float* __restrict__ xg_ws,
             const float* __restrict__ Wfc, const float* __restrict__ bfc,
             const float* __restrict__ ln1g, const float* __restrict__ ln1b,
             const float* __restrict__ ln2g, const float* __restrict__ ln2b,
             const float* __restrict__ Wff1, const float* __restrict__ bff1,
             const float* __restrict__ Wff2, const float* __restrict__ bff2,
             const float* __restrict__ Wfs, const float* __restrict__ bfs,
             const float* __restrict__ Wfg, const float* __restrict__ bfg,
             float* __restrict__ out)
{
  __shared__ u16 smA[64*66];                       // o_t -> us_t (bf16)
  __shared__ u16 smB[64*66];                       // qd_t -> ms_t (bf16)
  __shared__ union UH { u16 h[128*66]; float o[64*66]; } HH;  // hidden/xg (bf16) -> out_t (f32)
  __shared__ float lnxA[4][64];
  __shared__ float lnxB[4][64];

  const int tid = threadIdx.x;
  const int token0 = blockIdx.x * 64;
  const int w = rfl(tid >> 6);
  const int tok = tid & 63;
  const int c0 = w * 16;

  #pragma unroll
  for (int it = 0; it < 4; it++){
    int idx = tid + 256*it;
    int tk = idx >> 4, c4 = (idx & 15) * 4;
    int gtok = token0 + tk;
    int n = (gtok / T_) & (N_-1);
    float4 ov = *(const float4*)(o_ws + (size_t)gtok*C_ + c4);
    float4 qv = *(const float4*)(query + (size_t)gtok*C_ + c4);
    float4 dv = *(const float4*)(dsb + n*C_ + c4);
    smA[(c4+0)*66+tk] = f2bf(ov.x); smA[(c4+1)*66+tk] = f2bf(ov.y);
    smA[(c4+2)*66+tk] = f2bf(ov.z); smA[(c4+3)*66+tk] = f2bf(ov.w);
    smB[(c4+0)*66+tk] = f2bf(qv.x+dv.x); smB[(c4+1)*66+tk] = f2bf(qv.y+dv.y);
    smB[(c4+2)*66+tk] = f2bf(qv.z+dv.z); smB[(c4+3)*66+tk] = f2bf(qv.w+dv.w);
  }
  __syncthreads();

  // fc
  float x1[16];
  #pragma unroll
  for (int j = 0; j < 16; j++) x1[j] = 0.f;
  for (int i = 0; i < C_; i++){
    float ov = bf2f(smA[i*66 + tok]);
    const float* wrow = Wfc + i*C_ + c0;
    #pragma unroll
    for (int j = 0; j < 16; j++) x1[j] += ov * wrow[j];
  }
  #pragma unroll
  for (int j = 0; j < 16; j++) x1[j] += bfc[c0+j] + bf2f(smB[(c0+j)*66 + tok]);

  // LN1
  float s1 = 0.f;
  #pragma unroll
  for (int j = 0; j < 16; j++) s1 += x1[j];
  lnxA[w][tok] = s1;
  __syncthreads();
  float mu = (lnxA[0][tok]+lnxA[1][tok]+lnxA[2][tok]+lnxA[3][tok]) * (1.f/64.f);
  float v1 = 0.f;
  #pragma unroll
  for (int j = 0; j < 16; j++){ float d = x1[j]-mu; v1 += d*d; }
  lnxB[w][tok] = v1;
  __syncthreads();
  float var = (lnxB[0][tok]+lnxB[1][tok]+lnxB[2][tok]+lnxB[3][tok]) * (1.f/64.f);
  float rstd = rsqrtf(var + 1e-5f);
  float ms[16];
  #pragma unroll
  for (int j = 0; j < 16; j++) ms[j] = (x1[j]-mu)*rstd*ln1g[c0+j] + ln1b[c0+j];
  __syncthreads();
  #pragma unroll
  for (int j = 0; j < 16; j++) smB[(c0+j)*66 + tok] = f2bf(ms[j]);
  __syncthreads();

  // FFN
  float part[16];
  #pragma unroll
  for (int j = 0; j < 16; j++) part[j] = 0.f;
  #pragma unroll
  for (int ch = 0; ch < 2; ch++){
    float fch[32];
    #pragma unroll
    for (int kk = 0; kk < 32; kk++) fch[kk] = 0.f;
    const int kbase = w*64 + ch*32;
    for (int i = 0; i < C_; i++){
      float msv = bf2f(smB[i*66 + tok]);
      const float* wrow = Wff1 + i*(4*C_) + kbase;
      #pragma unroll
      for (int kk = 0; kk < 32; kk++) fch[kk] += msv * wrow[kk];
    }
    #pragma unroll
    for (int kk = 0; kk < 32; kk++){
      float v = fch[kk] + bff1[kbase+kk];
      fch[kk] = v > 0.f ? v : 0.f;
    }
    if (ch) __syncthreads();
    #pragma unroll
    for (int kk = 0; kk < 32; kk++) HH.h[(w*32+kk)*66 + tok] = f2bf(fch[kk]);
    __syncthreads();
    #pragma unroll
    for (int wq = 0; wq < 4; wq++){
      #pragma unroll 8
      for (int kk = 0; kk < 32; kk++){
        int k = wq*64 + ch*32 + kk;
        float hv = bf2f(HH.h[(wq*32+kk)*66 + tok]);
        const float* wrow = Wff2 + k*C_ + c0;
        #pragma unroll
        for (int j = 0; j < 16; j++) part[j] += hv * wrow[j];
      }
    }
  }
  float x2[16];
  #pragma unroll
  for (int j = 0; j < 16; j++) x2[j] = part[j] + bff2[c0+j] + ms[j];

  // LN2
  float s2 = 0.f;
  #pragma unroll
  for (int j = 0; j < 16; j++) s2 += x2[j];
  __syncthreads();
  lnxA[w][tok] = s2;
  __syncthreads();
  float mu2 = (lnxA[0][tok]+lnxA[1][tok]+lnxA[2][tok]+lnxA[3][tok]) * (1.f/64.f);
  float v2 = 0.f;
  #pragma unroll
  for (int j = 0; j < 16; j++){ float d = x2[j]-mu2; v2 += d*d; }
  lnxB[w][tok] = v2;
  __syncthreads();
  float var2 = (lnxB[0][tok]+lnxB[1][tok]+lnxB[2][tok]+lnxB[3][tok]) * (1.f/64.f);
  float rstd2 = rsqrtf(var2 + 1e-5f);
  float us[16];
  #pragma unroll
  for (int j = 0; j < 16; j++) us[j] = (x2[j]-mu2)*rstd2*ln2g[c0+j] + ln2b[c0+j];

  // us -> smA ; xg -> HH.h rows 0..63 (hidden dead)
  #pragma unroll
  for (int j = 0; j < 16; j++) smA[(c0+j)*66 + tok] = f2bf(us[j]);
  #pragma unroll
  for (int it = 0; it < 4; it++){
    int idx = tid + 256*it;
    int tk = idx >> 4, c4 = (idx & 15) * 4;
    int gtok = token0 + tk;
    float4 xv = *(const float4*)(xg_ws + (size_t)gtok*C_ + c4);
    HH.h[(c4+0)*66+tk] = f2bf(xv.x); HH.h[(c4+1)*66+tk] = f2bf(xv.y);
    HH.h[(c4+2)*66+tk] = f2bf(xv.z); HH.h[(c4+3)*66+tk] = f2bf(xv.w);
  }
  __syncthreads();

  // gate
  float ga[16];
  #pragma unroll
  for (int j = 0; j < 16; j++) ga[j] = 0.f;
  for (int i = 0; i < C_; i++){
    float uv = bf2f(smA[i*66 + tok]);
    float xv = bf2f(HH.h[i*66 + tok]);
    const float* wsr = Wfs + i*C_ + c0;
    const float* wgr = Wfg + i*C_ + c0;
    #pragma unroll
    for (int j = 0; j < 16; j++) ga[j] += uv*wsr[j] + xv*wgr[j];
  }
  float res[16];
  #pragma unroll
  for (int j = 0; j < 16; j++){
    float a = ga[j] + bfs[c0+j] + bfg[c0+j];
    float gg = 1.f / (1.f + __expf(-a));
    float xgv = bf2f(HH.h[(c0+j)*66 + tok]);
    res[j] = gg*us[j] + (1.f-gg)*xgv;
  }
  __syncthreads();   // all xg reads done before f32 reuse of HH
  #pragma unroll
  for (int j = 0; j < 16; j++) HH.o[(c0+j)*66 + tok] = res[j];
  __syncthreads();
  #pragma unroll
  for (int it = 0; it < 4; it++){
    int idx = tid + 256*it;
    int tk = idx >> 4, c4 = (idx & 15) * 4;
    int gtok = token0 + tk;
    float4 v = make_float4(HH.o[(c4+0)*66+tk], HH.o[(c4+1)*66+tk],
                           HH.o[(c4+2)*66+tk], HH.o[(c4+3)*66+tk]);
    *(float4*)(out + (size_t)gtok*C_ + c4) = v;
  }
}

extern "C" void kernel_launch(void* const* d_in, const int* in_sizes, int n_in,
                              void* d_out, int out_size, void* d_ws, size_t ws_size,
                              hipStream_t stream)
{
  (void)in_sizes; (void)n_in; (void)out_size;
  const float* query = (const float*)d_in[0];
  const float* key   = (const float*)d_in[1];
  const float* value = (const float*)d_in[2];
  const float* DSm   = (const float*)d_in[4];
  const float* Wemb  = (const float*)d_in[5];
  const float* bemb  = (const float*)d_in[6];
  const float* Wq    = (const float*)d_in[7];
  const float* Wk    = (const float*)d_in[8];
  const float* Wv    = (const float*)d_in[9];
  const float* Wfc   = (const float*)d_in[10];
  const float* bfc   = (const float*)d_in[11];
  const float* ln1g  = (const float*)d_in[12];
  const float* ln1b  = (const float*)d_in[13];
  const float* ln2g  = (const float*)d_in[14];
  const float* ln2b  = (const float*)d_in[15];
  const float* Wff1  = (const float*)d_in[16];
  const float* bff1  = (const float*)d_in[17];
  const float* Wff2  = (const float*)d_in[18];
  const float* bff2  = (const float*)d_in[19];
  const float* g1W   = (const float*)d_in[20];
  const float* g1as  = (const float*)d_in[21];
  const float* g1ad  = (const float*)d_in[22];
  const float* g1b   = (const float*)d_in[23];
  const float* g2W   = (const float*)d_in[24];
  const float* g2as  = (const float*)d_in[25];
  const float* g2ad  = (const float*)d_in[26];
  const float* g2b   = (const float*)d_in[27];
  const float* jkW   = (const float*)d_in[28];
  const float* jkb   = (const float*)d_in[29];
  const float* Wfs   = (const float*)d_in[30];
  const float* bfs   = (const float*)d_in[31];
  const float* Wfg   = (const float*)d_in[32];
  const float* bfg   = (const float*)d_in[33];
  const int* ei      = (const int*)d_in[34];
  float* out = (float*)d_out;

  float* wf     = (float*)d_ws;
  float* dsb    = wf + DS_OFF;
  float* xg_ws  = wf + XG_OFF;
  u16*   hA     = (u16*)(wf + HA_OFF);
  u16*   hB     = (u16*)(wf + HB_OFF);
  float* hs_ws  = wf + HS_OFF;
  float* hd_ws  = wf + HD_OFF;
  int*   indptr = (int*)(wf + INT_OFF);
  int*   srcs   = indptr + 260;
  float* mS     = wf + MS_OFF;

  const size_t need = (size_t)(O_SEP_OFF + TOK_*C_) * 4;
  const bool sep = ws_size >= need;                     // deterministic (fixed per session)
  float* o_ws = sep ? (wf + O_SEP_OFF) : (wf + HA_OFF); // fallback aliases hA

  k_pre     <<<dim3(641),  dim3(256), 0, stream>>>(query, g1W, g1as, g1ad, hA, hs_ws, hd_ws,
                                                   DSm, Wemb, bemb, dsb, ei, indptr, srcs);
  k_agg1stat<<<dim3(1152), dim3(256), 0, stream>>>(hA, hs_ws, hd_ws, indptr, srcs, g1b, hB,
                                                   query, key, Wq, Wk, dsb, mS);
  k_lin2    <<<dim3(576),  dim3(256), 0, stream>>>(hB, g2W, g2as, g2ad, hA, hs_ws, hd_ws);
  if (sep){
    // agg2+jk runs concurrently with attn-AV (o_ws is its own region)
    k_agg2av<<<dim3(1152), dim3(256), 0, stream>>>(hA, hs_ws, hd_ws, indptr, srcs, g2b, hB,
                                                   jkW, jkb, xg_ws,
                                                   query, key, value, Wq, Wk, Wv, dsb, mS, o_ws, 0);
  } else {
    // fallback: agg2+jk first (hA live), then AV (o_ws aliases now-dead hA)
    k_agg2av<<<dim3(576),  dim3(256), 0, stream>>>(hA, hs_ws, hd_ws, indptr, srcs, g2b, hB,
                                                   jkW, jkb, xg_ws,
                                                   query, key, value, Wq, Wk, Wv, dsb, mS, o_ws, 0);
    k_agg2av<<<dim3(576),  dim3(256), 0, stream>>>(hA, hs_ws, hd_ws, indptr, srcs, g2b, hB,
                                                   jkW, jkb, xg_ws,
                                                   query, key, value, Wq, Wk, Wv, dsb, mS, o_ws, 576);
  }
  k_final   <<<dim3(576),  dim3(256), 0, stream>>>(query, dsb, o_ws, xg_ws,
      Wfc, bfc, ln1g, ln1b, ln2g, ln2b,
      Wff1, bff1, Wff2, bff2,
      Wfs, bfs, Wfg, bfg, out);
}